// Round 1
// baseline (854.301 us; speedup 1.0000x reference)
//
#include <hip/hip_runtime.h>

// Transformer block on MI355X (gfx950).
// B=2, T=2048, C=1024, H=16, D=64. All GEMMs in bf16 MFMA (16x16x32),
// m97-style 128x128 tiles with global_load_lds(16B). Flash attention with
// online softmax, P transposed via padded LDS. Weights converted+transposed
// to bf16 every launch (harness re-poisons ws). Needs 96 MB workspace.

typedef unsigned short u16;
typedef unsigned int u32;
typedef __attribute__((ext_vector_type(8))) short v8s;   // 8 x bf16 (4 VGPR)
typedef __attribute__((ext_vector_type(4))) float v4f;   // MFMA acc

#define GAS __attribute__((address_space(1)))
#define LAS __attribute__((address_space(3)))

__device__ __forceinline__ u16 f2bf(float f) {
  u32 u = __float_as_uint(f);
  u = (u + 0x7FFF + ((u >> 16) & 1)) >> 16;  // RNE
  return (u16)u;
}
__device__ __forceinline__ float bf2f(u16 h) {
  return __uint_as_float(((u32)h) << 16);
}

// ---------------- weight transpose + fp32->bf16 convert ----------------
// W [K][N] f32  ->  Wt [N][K] bf16.  grid(N/32, K/32), block 256.
__global__ __launch_bounds__(256)
void wtrans(const float* __restrict__ W, u16* __restrict__ Wt, int K, int N) {
  __shared__ float tile[32][33];
  const int n0 = blockIdx.x << 5, k0 = blockIdx.y << 5;
  const int r = threadIdx.x >> 5, c = threadIdx.x & 31;
  for (int i = 0; i < 4; ++i)
    tile[r + 8 * i][c] = W[(size_t)(k0 + r + 8 * i) * N + n0 + c];
  __syncthreads();
  for (int i = 0; i < 4; ++i)
    Wt[(size_t)(n0 + r + 8 * i) * K + k0 + c] = f2bf(tile[c][r + 8 * i]);
}

// ---------------- LayerNorm (f32 in -> bf16 out), C=1024 ----------------
__global__ __launch_bounds__(256)
void ln_bf16(const float* __restrict__ x, const float* __restrict__ g,
             const float* __restrict__ be, u16* __restrict__ out) {
  constexpr int C = 1024;
  const int row = blockIdx.x, t = threadIdx.x;
  const float4 v = ((const float4*)(x + (size_t)row * C))[t];
  float s = v.x + v.y + v.z + v.w;
  for (int m = 32; m >= 1; m >>= 1) s += __shfl_xor(s, m);
  __shared__ float red[4], red2[4];
  if ((t & 63) == 0) red[t >> 6] = s;
  __syncthreads();
  const float mu = (red[0] + red[1] + red[2] + red[3]) * (1.f / C);
  const float dx = v.x - mu, dy = v.y - mu, dz = v.z - mu, dw = v.w - mu;
  float s2 = dx * dx + dy * dy + dz * dz + dw * dw;
  for (int m = 32; m >= 1; m >>= 1) s2 += __shfl_xor(s2, m);
  if ((t & 63) == 0) red2[t >> 6] = s2;
  __syncthreads();
  const float var = (red2[0] + red2[1] + red2[2] + red2[3]) * (1.f / C);
  const float rs = rsqrtf(var + 1e-5f);
  const int c = t << 2;
  u16 o0 = f2bf(dx * rs * g[c + 0] + be[c + 0]);
  u16 o1 = f2bf(dy * rs * g[c + 1] + be[c + 1]);
  u16 o2 = f2bf(dz * rs * g[c + 2] + be[c + 2]);
  u16 o3 = f2bf(dw * rs * g[c + 3] + be[c + 3]);
  uint2 pk;
  pk.x = (u32)o0 | ((u32)o1 << 16);
  pk.y = (u32)o2 | ((u32)o3 << 16);
  *(uint2*)(out + (size_t)row * C + c) = pk;
}

// ---------------- GEMM: C = A[M,K](bf16) * Bt[N,K]^T(bf16) + epilogue ----
// EPI 0: +bias -> bf16 out
// EPI 1: +bias, gelu(tanh) -> bf16 out
// EPI 2: +bias, +res(f32) -> f32 out
template <int EPI>
__global__ __launch_bounds__(256)
void gemm_bt(const u16* __restrict__ A, const u16* __restrict__ Bt,
             const float* __restrict__ bias, const float* __restrict__ res,
             void* __restrict__ outp, int M, int N, int K) {
  __shared__ u16 As[128 * 32];
  __shared__ u16 Bs[128 * 32];
  const int tid = threadIdx.x;
  const int wave = tid >> 6, lane = tid & 63;
  const int m0 = blockIdx.y << 7, n0 = blockIdx.x << 7;

  v4f acc[4][4];
  const v4f vz = {0.f, 0.f, 0.f, 0.f};
  for (int i = 0; i < 4; ++i)
    for (int j = 0; j < 4; ++j) acc[i][j] = vz;

  const int wm = (wave >> 1) << 6, wn = (wave & 1) << 6;
  const int sr = lane >> 2;         // row within 16-row staging chunk
  const int sc = (lane & 3) << 3;   // col (elements)
  const int fr = lane & 15;
  const int fk = (lane >> 4) << 3;
  const int c0 = wave << 1;

  u16* lA0 = As + (c0 + 0) * 512;
  u16* lA1 = As + (c0 + 1) * 512;
  u16* lB0 = Bs + (c0 + 0) * 512;
  u16* lB1 = Bs + (c0 + 1) * 512;
  const u16* gA0 = A + (size_t)(m0 + c0 * 16 + sr) * K + sc;
  const u16* gA1 = A + (size_t)(m0 + c0 * 16 + 16 + sr) * K + sc;
  const u16* gB0 = Bt + (size_t)(n0 + c0 * 16 + sr) * K + sc;
  const u16* gB1 = Bt + (size_t)(n0 + c0 * 16 + 16 + sr) * K + sc;

  for (int k0 = 0; k0 < K; k0 += 32) {
    __builtin_amdgcn_global_load_lds((GAS const u32*)(gA0 + k0), (LAS u32*)lA0, 16, 0, 0);
    __builtin_amdgcn_global_load_lds((GAS const u32*)(gA1 + k0), (LAS u32*)lA1, 16, 0, 0);
    __builtin_amdgcn_global_load_lds((GAS const u32*)(gB0 + k0), (LAS u32*)lB0, 16, 0, 0);
    __builtin_amdgcn_global_load_lds((GAS const u32*)(gB1 + k0), (LAS u32*)lB1, 16, 0, 0);
    __syncthreads();
    v8s af[4], bfr[4];
    for (int mi = 0; mi < 4; ++mi)
      af[mi] = *(const v8s*)&As[(wm + mi * 16 + fr) * 32 + fk];
    for (int ni = 0; ni < 4; ++ni)
      bfr[ni] = *(const v8s*)&Bs[(wn + ni * 16 + fr) * 32 + fk];
    for (int mi = 0; mi < 4; ++mi)
      for (int ni = 0; ni < 4; ++ni)
        acc[mi][ni] = __builtin_amdgcn_mfma_f32_16x16x32_bf16(af[mi], bfr[ni], acc[mi][ni], 0, 0, 0);
    __syncthreads();
  }

  const int er = (lane >> 4) << 2;  // C-layout: row = er+r, col = fr (m89-verified)
  for (int mi = 0; mi < 4; ++mi) {
    for (int ni = 0; ni < 4; ++ni) {
      const int col = n0 + wn + ni * 16 + fr;
      const float bcol = bias[col];
      for (int r = 0; r < 4; ++r) {
        const int row = m0 + wm + mi * 16 + er + r;
        float v = acc[mi][ni][r] + bcol;
        if constexpr (EPI == 1) {
          const float t = tanhf(0.7978845608028654f * (v + 0.044715f * v * v * v));
          v = 0.5f * v * (1.f + t);
        }
        if constexpr (EPI == 2) {
          v += res[(size_t)row * N + col];
          ((float*)outp)[(size_t)row * N + col] = v;
        } else {
          ((u16*)outp)[(size_t)row * N + col] = f2bf(v);
        }
      }
    }
  }
}

// ---------------- qkv [B*T, 3C] bf16 -> Q,K [B,H,T,D] (Q pre-scaled 1/8) --
__global__ __launch_bounds__(256)
void reshape_qk(const u16* __restrict__ qkv, u16* __restrict__ Q,
                u16* __restrict__ Ko) {
  const int idx = blockIdx.x * 256 + threadIdx.x;  // over B*H*T*D = 4M
  const int d = idx & 63;
  const int t = (idx >> 6) & 2047;
  const int bh = idx >> 17;
  const int b = bh >> 4, h = bh & 15;
  const size_t src = (size_t)(b * 2048 + t) * 3072 + h * 64 + d;
  Q[idx] = f2bf(bf2f(qkv[src]) * 0.125f);  // fold 1/sqrt(64); exact pow2
  Ko[idx] = qkv[src + 1024];
}

// ---------------- V -> Vt [B,H,D,T] bf16 (transpose via LDS) -------------
__global__ __launch_bounds__(256)
void transpose_v(const u16* __restrict__ qkv, u16* __restrict__ Vt) {
  __shared__ u16 tile[64][65];
  const int t0 = blockIdx.x << 6;
  const int bh = blockIdx.y;
  const int b = bh >> 4, h = bh & 15;
  const int r4 = threadIdx.x >> 6, c = threadIdx.x & 63;
  for (int i = 0; i < 16; ++i) {
    const int r = r4 * 16 + i;
    tile[r][c] = qkv[(size_t)(b * 2048 + t0 + r) * 3072 + 2048 + h * 64 + c];
  }
  __syncthreads();
  for (int i = 0; i < 16; ++i) {
    const int d = r4 * 16 + i;
    Vt[(size_t)bh * 64 * 2048 + (size_t)d * 2048 + t0 + c] = tile[c][d];
  }
}

// ---------------- flash attention (causal), one wave = 16 q rows ---------
// grid(T/64, B*H), block 256 (4 waves). 32-key tiles.
__global__ __launch_bounds__(256)
void attn_kernel(const u16* __restrict__ Q, const u16* __restrict__ K,
                 const u16* __restrict__ Vt, u16* __restrict__ y) {
  constexpr int T = 2048, D = 64, C = 1024;
  const int tid = threadIdx.x, wave = tid >> 6, lane = tid & 63;
  const int bh = blockIdx.y, b = bh >> 4, h = bh & 15;
  const int q0 = blockIdx.x * 64 + wave * 16;
  const u16* Qh = Q + (size_t)bh * T * D;
  const u16* Kh = K + (size_t)bh * T * D;
  const u16* Vh = Vt + (size_t)bh * D * T;

  __shared__ u16 P[4][16 * 40];  // stride 40: conflict-free, 16B-aligned b128
  u16* pw = &P[wave][0];

  const int fr = lane & 15, fg = lane >> 4;

  v8s qf0 = *(const v8s*)&Qh[(q0 + fr) * D + fg * 8];
  v8s qf1 = *(const v8s*)&Qh[(q0 + fr) * D + 32 + fg * 8];

  const v4f vz = {0.f, 0.f, 0.f, 0.f};
  v4f o[4];
  for (int ni = 0; ni < 4; ++ni) o[ni] = vz;
  float m_i[4], l_i[4];
  for (int r = 0; r < 4; ++r) { m_i[r] = -1e30f; l_i[r] = 0.f; }

  const int ktb = (blockIdx.x * 64 + 63) >> 5;  // uniform per block
  for (int kt = 0; kt <= ktb; ++kt) {
    const int kb = kt << 5;
    const v8s kf0a = *(const v8s*)&Kh[(kb + fr) * D + fg * 8];
    const v8s kf0b = *(const v8s*)&Kh[(kb + fr) * D + 32 + fg * 8];
    const v8s kf1a = *(const v8s*)&Kh[(kb + 16 + fr) * D + fg * 8];
    const v8s kf1b = *(const v8s*)&Kh[(kb + 16 + fr) * D + 32 + fg * 8];
    v4f s0 = vz, s1 = vz;
    s0 = __builtin_amdgcn_mfma_f32_16x16x32_bf16(qf0, kf0a, s0, 0, 0, 0);
    s0 = __builtin_amdgcn_mfma_f32_16x16x32_bf16(qf1, kf0b, s0, 0, 0, 0);
    s1 = __builtin_amdgcn_mfma_f32_16x16x32_bf16(qf0, kf1a, s1, 0, 0, 0);
    s1 = __builtin_amdgcn_mfma_f32_16x16x32_bf16(qf1, kf1b, s1, 0, 0, 0);

    for (int r = 0; r < 4; ++r) {
      const int q = q0 + fg * 4 + r;
      float v0 = (kb + fr <= q) ? s0[r] : -1e30f;
      float v1 = (kb + 16 + fr <= q) ? s1[r] : -1e30f;
      float mt = fmaxf(v0, v1);
      for (int m = 1; m <= 8; m <<= 1) mt = fmaxf(mt, __shfl_xor(mt, m));
      const float m_new = fmaxf(m_i[r], mt);
      const float alpha = __expf(m_i[r] - m_new);
      const float e0 = __expf(v0 - m_new);
      const float e1 = __expf(v1 - m_new);
      float sum = e0 + e1;
      for (int m = 1; m <= 8; m <<= 1) sum += __shfl_xor(sum, m);
      l_i[r] = l_i[r] * alpha + sum;
      m_i[r] = m_new;
      for (int ni = 0; ni < 4; ++ni) o[ni][r] *= alpha;
      pw[(fg * 4 + r) * 40 + fr] = f2bf(e0);
      pw[(fg * 4 + r) * 40 + 16 + fr] = f2bf(e1);
    }
    __syncthreads();  // uniform count; drains LDS writes before A-frag reads
    const v8s pf = *(const v8s*)&pw[fr * 40 + fg * 8];
    for (int ni = 0; ni < 4; ++ni) {
      const v8s vf = *(const v8s*)&Vh[(size_t)(ni * 16 + fr) * T + kb + fg * 8];
      o[ni] = __builtin_amdgcn_mfma_f32_16x16x32_bf16(pf, vf, o[ni], 0, 0, 0);
    }
    __syncthreads();
  }

  for (int ni = 0; ni < 4; ++ni)
    for (int r = 0; r < 4; ++r) {
      const int q = q0 + fg * 4 + r;
      y[(size_t)(b * T + q) * C + h * D + ni * 16 + fr] = f2bf(o[ni][r] / l_i[r]);
    }
}

// ------------------------------- launch ----------------------------------
extern "C" void kernel_launch(void* const* d_in, const int* in_sizes, int n_in,
                              void* d_out, int out_size, void* d_ws, size_t ws_size,
                              hipStream_t stream) {
  const float* x      = (const float*)d_in[0];
  const float* ln1_g  = (const float*)d_in[1];
  const float* ln1_b  = (const float*)d_in[2];
  const float* W_attn = (const float*)d_in[3];
  const float* b_attn = (const float*)d_in[4];
  const float* W_o    = (const float*)d_in[5];
  const float* b_o    = (const float*)d_in[6];
  const float* ln2_g  = (const float*)d_in[7];
  const float* ln2_b  = (const float*)d_in[8];
  const float* W_fc   = (const float*)d_in[9];
  const float* b_fc   = (const float*)d_in[10];
  const float* W_fc2  = (const float*)d_in[11];
  const float* b_fc2  = (const float*)d_in[12];
  float* out = (float*)d_out;
  char* ws = (char*)d_ws;

  const size_t MB = 1u << 20;
  u16* Wattn_t = (u16*)(ws + 0 * MB);   // [3072][1024] 6MB
  u16* Wo_t    = (u16*)(ws + 6 * MB);   // [1024][1024] 2MB
  u16* Wfc_t   = (u16*)(ws + 8 * MB);   // [4096][1024] 8MB
  u16* Wfc2_t  = (u16*)(ws + 16 * MB);  // [1024][4096] 8MB
  float* x1    = (float*)(ws + 24 * MB); // [4096][1024] f32 16MB (persistent)
  u16* h1      = (u16*)(ws + 40 * MB);  // 8MB
  u16* qkv     = (u16*)(ws + 48 * MB);  // 24MB
  u16* Qb      = (u16*)(ws + 72 * MB);  // 8MB
  u16* Kb      = (u16*)(ws + 80 * MB);  // 8MB
  u16* Vt      = (u16*)(ws + 88 * MB);  // 8MB   (total 96MB)
  u16* yb      = (u16*)(ws + 40 * MB);  // reuse h1 (dead after qkv GEMM)
  u16* h2      = (u16*)(ws + 48 * MB);  // reuse qkv (dead after reshape)
  u16* ab      = (u16*)(ws + 56 * MB);  // 32MB, reuses Q/K/Vt region (dead)

  // weights -> bf16 transposed
  wtrans<<<dim3(3072 / 32, 1024 / 32), 256, 0, stream>>>(W_attn, Wattn_t, 1024, 3072);
  wtrans<<<dim3(1024 / 32, 1024 / 32), 256, 0, stream>>>(W_o, Wo_t, 1024, 1024);
  wtrans<<<dim3(4096 / 32, 1024 / 32), 256, 0, stream>>>(W_fc, Wfc_t, 1024, 4096);
  wtrans<<<dim3(1024 / 32, 4096 / 32), 256, 0, stream>>>(W_fc2, Wfc2_t, 4096, 1024);

  // ln1 -> h1
  ln_bf16<<<4096, 256, 0, stream>>>(x, ln1_g, ln1_b, h1);
  // qkv = h1 @ W_attn + b_attn  (bf16 out)
  gemm_bt<0><<<dim3(3072 / 128, 4096 / 128), 256, 0, stream>>>(
      h1, Wattn_t, b_attn, nullptr, qkv, 4096, 3072, 1024);
  // split/reshape
  reshape_qk<<<(2 * 16 * 2048 * 64) / 256, 256, 0, stream>>>(qkv, Qb, Kb);
  transpose_v<<<dim3(2048 / 64, 32), 256, 0, stream>>>(qkv, Vt);
  // attention -> yb [B*T, C] bf16
  attn_kernel<<<dim3(2048 / 64, 32), 256, 0, stream>>>(Qb, Kb, Vt, yb);
  // x1 = x + yb @ W_o + b_o   (f32 out)
  gemm_bt<2><<<dim3(1024 / 128, 4096 / 128), 256, 0, stream>>>(
      yb, Wo_t, b_o, x, x1, 4096, 1024, 1024);
  // ln2 -> h2
  ln_bf16<<<4096, 256, 0, stream>>>(x1, ln2_g, ln2_b, h2);
  // ab = gelu(h2 @ W_fc + b_fc)  (bf16 out)
  gemm_bt<1><<<dim3(4096 / 128, 4096 / 128), 256, 0, stream>>>(
      h2, Wfc_t, b_fc, nullptr, ab, 4096, 4096, 1024);
  // out = x1 + ab @ W_fc2 + b_fc2  (f32 out)
  gemm_bt<2><<<dim3(1024 / 128, 4096 / 128), 256, 0, stream>>>(
      ab, Wfc2_t, b_fc2, x1, out, 4096, 1024, 4096);
}

// Round 2
// 594.170 us; speedup vs baseline: 1.4378x; 1.4378x over previous
//
#include <hip/hip_runtime.h>

// Transformer block on MI355X (gfx950).
// B=2, T=2048, C=1024, H=16, D=64. All GEMMs in bf16 MFMA (16x16x32),
// m97-style 128x128 tiles with global_load_lds(16B). Flash attention with
// online softmax, P transposed via padded LDS. Weights converted+transposed
// to bf16 every launch (harness re-poisons ws). Needs 96 MB workspace.
//
// R1 fix: round-0 kernel kept the 4x4 v4f accumulator in SCRATCH (VGPR=60,
// WRITE_SIZE=1.9GB/dispatch) because the epilogue's tanhf call blocked loop
// unrolling -> dynamic vector indexing -> SROA defeated. All register-array
// loops are now #pragma unroll'd and tanh is inlined via __expf.

typedef unsigned short u16;
typedef unsigned int u32;
typedef __attribute__((ext_vector_type(8))) short v8s;   // 8 x bf16 (4 VGPR)
typedef __attribute__((ext_vector_type(4))) float v4f;   // MFMA acc

#define GAS __attribute__((address_space(1)))
#define LAS __attribute__((address_space(3)))

__device__ __forceinline__ u16 f2bf(float f) {
  u32 u = __float_as_uint(f);
  u = (u + 0x7FFF + ((u >> 16) & 1)) >> 16;  // RNE
  return (u16)u;
}
__device__ __forceinline__ float bf2f(u16 h) {
  return __uint_as_float(((u32)h) << 16);
}
__device__ __forceinline__ float fast_tanh(float x) {
  // tanh(x) = 1 - 2/(1+e^{2x}); |x| here is O(1), __expf is plenty accurate
  return 1.f - 2.f / (1.f + __expf(2.f * x));
}

// ---------------- weight transpose + fp32->bf16 convert ----------------
// W [K][N] f32  ->  Wt [N][K] bf16.  grid(N/32, K/32), block 256.
__global__ __launch_bounds__(256)
void wtrans(const float* __restrict__ W, u16* __restrict__ Wt, int K, int N) {
  __shared__ float tile[32][33];
  const int n0 = blockIdx.x << 5, k0 = blockIdx.y << 5;
  const int r = threadIdx.x >> 5, c = threadIdx.x & 31;
#pragma unroll
  for (int i = 0; i < 4; ++i)
    tile[r + 8 * i][c] = W[(size_t)(k0 + r + 8 * i) * N + n0 + c];
  __syncthreads();
#pragma unroll
  for (int i = 0; i < 4; ++i)
    Wt[(size_t)(n0 + r + 8 * i) * K + k0 + c] = f2bf(tile[c][r + 8 * i]);
}

// ---------------- LayerNorm (f32 in -> bf16 out), C=1024 ----------------
__global__ __launch_bounds__(256)
void ln_bf16(const float* __restrict__ x, const float* __restrict__ g,
             const float* __restrict__ be, u16* __restrict__ out) {
  constexpr int C = 1024;
  const int row = blockIdx.x, t = threadIdx.x;
  const float4 v = ((const float4*)(x + (size_t)row * C))[t];
  float s = v.x + v.y + v.z + v.w;
#pragma unroll
  for (int m = 32; m >= 1; m >>= 1) s += __shfl_xor(s, m);
  __shared__ float red[4], red2[4];
  if ((t & 63) == 0) red[t >> 6] = s;
  __syncthreads();
  const float mu = (red[0] + red[1] + red[2] + red[3]) * (1.f / C);
  const float dx = v.x - mu, dy = v.y - mu, dz = v.z - mu, dw = v.w - mu;
  float s2 = dx * dx + dy * dy + dz * dz + dw * dw;
#pragma unroll
  for (int m = 32; m >= 1; m >>= 1) s2 += __shfl_xor(s2, m);
  if ((t & 63) == 0) red2[t >> 6] = s2;
  __syncthreads();
  const float var = (red2[0] + red2[1] + red2[2] + red2[3]) * (1.f / C);
  const float rs = rsqrtf(var + 1e-5f);
  const int c = t << 2;
  u16 o0 = f2bf(dx * rs * g[c + 0] + be[c + 0]);
  u16 o1 = f2bf(dy * rs * g[c + 1] + be[c + 1]);
  u16 o2 = f2bf(dz * rs * g[c + 2] + be[c + 2]);
  u16 o3 = f2bf(dw * rs * g[c + 3] + be[c + 3]);
  uint2 pk;
  pk.x = (u32)o0 | ((u32)o1 << 16);
  pk.y = (u32)o2 | ((u32)o3 << 16);
  *(uint2*)(out + (size_t)row * C + c) = pk;
}

// ---------------- GEMM: C = A[M,K](bf16) * Bt[N,K]^T(bf16) + epilogue ----
// EPI 0: +bias -> bf16 out
// EPI 1: +bias, gelu(tanh) -> bf16 out
// EPI 2: +bias, +res(f32) -> f32 out
template <int EPI>
__global__ __launch_bounds__(256)
void gemm_bt(const u16* __restrict__ A, const u16* __restrict__ Bt,
             const float* __restrict__ bias, const float* __restrict__ res,
             void* __restrict__ outp, int M, int N, int K) {
  __shared__ u16 As[128 * 32];
  __shared__ u16 Bs[128 * 32];
  const int tid = threadIdx.x;
  const int wave = tid >> 6, lane = tid & 63;
  const int m0 = blockIdx.y << 7, n0 = blockIdx.x << 7;

  v4f acc[4][4];
  const v4f vz = {0.f, 0.f, 0.f, 0.f};
#pragma unroll
  for (int i = 0; i < 4; ++i)
#pragma unroll
    for (int j = 0; j < 4; ++j) acc[i][j] = vz;

  const int wm = (wave >> 1) << 6, wn = (wave & 1) << 6;
  const int sr = lane >> 2;         // row within 16-row staging chunk
  const int sc = (lane & 3) << 3;   // col (elements)
  const int fr = lane & 15;
  const int fk = (lane >> 4) << 3;
  const int c0 = wave << 1;

  u16* lA0 = As + (c0 + 0) * 512;
  u16* lA1 = As + (c0 + 1) * 512;
  u16* lB0 = Bs + (c0 + 0) * 512;
  u16* lB1 = Bs + (c0 + 1) * 512;
  const u16* gA0 = A + (size_t)(m0 + c0 * 16 + sr) * K + sc;
  const u16* gA1 = A + (size_t)(m0 + c0 * 16 + 16 + sr) * K + sc;
  const u16* gB0 = Bt + (size_t)(n0 + c0 * 16 + sr) * K + sc;
  const u16* gB1 = Bt + (size_t)(n0 + c0 * 16 + 16 + sr) * K + sc;

  for (int k0 = 0; k0 < K; k0 += 32) {
    __builtin_amdgcn_global_load_lds((GAS const u32*)(gA0 + k0), (LAS u32*)lA0, 16, 0, 0);
    __builtin_amdgcn_global_load_lds((GAS const u32*)(gA1 + k0), (LAS u32*)lA1, 16, 0, 0);
    __builtin_amdgcn_global_load_lds((GAS const u32*)(gB0 + k0), (LAS u32*)lB0, 16, 0, 0);
    __builtin_amdgcn_global_load_lds((GAS const u32*)(gB1 + k0), (LAS u32*)lB1, 16, 0, 0);
    __syncthreads();
    v8s af[4], bfr[4];
#pragma unroll
    for (int mi = 0; mi < 4; ++mi)
      af[mi] = *(const v8s*)&As[(wm + mi * 16 + fr) * 32 + fk];
#pragma unroll
    for (int ni = 0; ni < 4; ++ni)
      bfr[ni] = *(const v8s*)&Bs[(wn + ni * 16 + fr) * 32 + fk];
#pragma unroll
    for (int mi = 0; mi < 4; ++mi)
#pragma unroll
      for (int ni = 0; ni < 4; ++ni)
        acc[mi][ni] = __builtin_amdgcn_mfma_f32_16x16x32_bf16(af[mi], bfr[ni], acc[mi][ni], 0, 0, 0);
    __syncthreads();
  }

  const int er = (lane >> 4) << 2;  // C-layout: row = er+r, col = fr (m89-verified)
#pragma unroll
  for (int mi = 0; mi < 4; ++mi) {
#pragma unroll
    for (int ni = 0; ni < 4; ++ni) {
      const int col = n0 + wn + ni * 16 + fr;
      const float bcol = bias[col];
#pragma unroll
      for (int r = 0; r < 4; ++r) {
        const int row = m0 + wm + mi * 16 + er + r;
        float v = acc[mi][ni][r] + bcol;
        if constexpr (EPI == 1) {
          const float t = fast_tanh(0.7978845608028654f * (v + 0.044715f * v * v * v));
          v = 0.5f * v * (1.f + t);
        }
        if constexpr (EPI == 2) {
          v += res[(size_t)row * N + col];
          ((float*)outp)[(size_t)row * N + col] = v;
        } else {
          ((u16*)outp)[(size_t)row * N + col] = f2bf(v);
        }
      }
    }
  }
}

// ---------------- qkv [B*T, 3C] bf16 -> Q,K [B,H,T,D] (Q pre-scaled 1/8) --
__global__ __launch_bounds__(256)
void reshape_qk(const u16* __restrict__ qkv, u16* __restrict__ Q,
                u16* __restrict__ Ko) {
  const int idx = blockIdx.x * 256 + threadIdx.x;  // over B*H*T*D = 4M
  const int d = idx & 63;
  const int t = (idx >> 6) & 2047;
  const int bh = idx >> 17;
  const int b = bh >> 4, h = bh & 15;
  const size_t src = (size_t)(b * 2048 + t) * 3072 + h * 64 + d;
  Q[idx] = f2bf(bf2f(qkv[src]) * 0.125f);  // fold 1/sqrt(64); exact pow2
  Ko[idx] = qkv[src + 1024];
}

// ---------------- V -> Vt [B,H,D,T] bf16 (transpose via LDS) -------------
__global__ __launch_bounds__(256)
void transpose_v(const u16* __restrict__ qkv, u16* __restrict__ Vt) {
  __shared__ u16 tile[64][65];
  const int t0 = blockIdx.x << 6;
  const int bh = blockIdx.y;
  const int b = bh >> 4, h = bh & 15;
  const int r4 = threadIdx.x >> 6, c = threadIdx.x & 63;
#pragma unroll
  for (int i = 0; i < 16; ++i) {
    const int r = r4 * 16 + i;
    tile[r][c] = qkv[(size_t)(b * 2048 + t0 + r) * 3072 + 2048 + h * 64 + c];
  }
  __syncthreads();
#pragma unroll
  for (int i = 0; i < 16; ++i) {
    const int d = r4 * 16 + i;
    Vt[(size_t)bh * 64 * 2048 + (size_t)d * 2048 + t0 + c] = tile[c][d];
  }
}

// ---------------- flash attention (causal), one wave = 16 q rows ---------
// grid(T/64, B*H), block 256 (4 waves). 32-key tiles.
__global__ __launch_bounds__(256)
void attn_kernel(const u16* __restrict__ Q, const u16* __restrict__ K,
                 const u16* __restrict__ Vt, u16* __restrict__ y) {
  constexpr int T = 2048, D = 64, C = 1024;
  const int tid = threadIdx.x, wave = tid >> 6, lane = tid & 63;
  const int bh = blockIdx.y, b = bh >> 4, h = bh & 15;
  const int q0 = blockIdx.x * 64 + wave * 16;
  const u16* Qh = Q + (size_t)bh * T * D;
  const u16* Kh = K + (size_t)bh * T * D;
  const u16* Vh = Vt + (size_t)bh * D * T;

  __shared__ u16 P[4][16 * 40];  // stride 40: conflict-free, 16B-aligned b128
  u16* pw = &P[wave][0];

  const int fr = lane & 15, fg = lane >> 4;

  v8s qf0 = *(const v8s*)&Qh[(q0 + fr) * D + fg * 8];
  v8s qf1 = *(const v8s*)&Qh[(q0 + fr) * D + 32 + fg * 8];

  const v4f vz = {0.f, 0.f, 0.f, 0.f};
  v4f o[4];
#pragma unroll
  for (int ni = 0; ni < 4; ++ni) o[ni] = vz;
  float m_i[4], l_i[4];
#pragma unroll
  for (int r = 0; r < 4; ++r) { m_i[r] = -1e30f; l_i[r] = 0.f; }

  const int ktb = (blockIdx.x * 64 + 63) >> 5;  // uniform per block
  for (int kt = 0; kt <= ktb; ++kt) {
    const int kb = kt << 5;
    const v8s kf0a = *(const v8s*)&Kh[(kb + fr) * D + fg * 8];
    const v8s kf0b = *(const v8s*)&Kh[(kb + fr) * D + 32 + fg * 8];
    const v8s kf1a = *(const v8s*)&Kh[(kb + 16 + fr) * D + fg * 8];
    const v8s kf1b = *(const v8s*)&Kh[(kb + 16 + fr) * D + 32 + fg * 8];
    v4f s0 = vz, s1 = vz;
    s0 = __builtin_amdgcn_mfma_f32_16x16x32_bf16(qf0, kf0a, s0, 0, 0, 0);
    s0 = __builtin_amdgcn_mfma_f32_16x16x32_bf16(qf1, kf0b, s0, 0, 0, 0);
    s1 = __builtin_amdgcn_mfma_f32_16x16x32_bf16(qf0, kf1a, s1, 0, 0, 0);
    s1 = __builtin_amdgcn_mfma_f32_16x16x32_bf16(qf1, kf1b, s1, 0, 0, 0);

#pragma unroll
    for (int r = 0; r < 4; ++r) {
      const int q = q0 + fg * 4 + r;
      float v0 = (kb + fr <= q) ? s0[r] : -1e30f;
      float v1 = (kb + 16 + fr <= q) ? s1[r] : -1e30f;
      float mt = fmaxf(v0, v1);
#pragma unroll
      for (int m = 1; m <= 8; m <<= 1) mt = fmaxf(mt, __shfl_xor(mt, m));
      const float m_new = fmaxf(m_i[r], mt);
      const float alpha = __expf(m_i[r] - m_new);
      const float e0 = __expf(v0 - m_new);
      const float e1 = __expf(v1 - m_new);
      float sum = e0 + e1;
#pragma unroll
      for (int m = 1; m <= 8; m <<= 1) sum += __shfl_xor(sum, m);
      l_i[r] = l_i[r] * alpha + sum;
      m_i[r] = m_new;
#pragma unroll
      for (int ni = 0; ni < 4; ++ni) o[ni][r] *= alpha;
      pw[(fg * 4 + r) * 40 + fr] = f2bf(e0);
      pw[(fg * 4 + r) * 40 + 16 + fr] = f2bf(e1);
    }
    __syncthreads();  // uniform count; drains LDS writes before A-frag reads
    const v8s pf = *(const v8s*)&pw[fr * 40 + fg * 8];
#pragma unroll
    for (int ni = 0; ni < 4; ++ni) {
      const v8s vf = *(const v8s*)&Vh[(size_t)(ni * 16 + fr) * T + kb + fg * 8];
      o[ni] = __builtin_amdgcn_mfma_f32_16x16x32_bf16(pf, vf, o[ni], 0, 0, 0);
    }
    __syncthreads();
  }

#pragma unroll
  for (int ni = 0; ni < 4; ++ni)
#pragma unroll
    for (int r = 0; r < 4; ++r) {
      const int q = q0 + fg * 4 + r;
      y[(size_t)(b * T + q) * C + h * D + ni * 16 + fr] = f2bf(o[ni][r] / l_i[r]);
    }
}

// ------------------------------- launch ----------------------------------
extern "C" void kernel_launch(void* const* d_in, const int* in_sizes, int n_in,
                              void* d_out, int out_size, void* d_ws, size_t ws_size,
                              hipStream_t stream) {
  const float* x      = (const float*)d_in[0];
  const float* ln1_g  = (const float*)d_in[1];
  const float* ln1_b  = (const float*)d_in[2];
  const float* W_attn = (const float*)d_in[3];
  const float* b_attn = (const float*)d_in[4];
  const float* W_o    = (const float*)d_in[5];
  const float* b_o    = (const float*)d_in[6];
  const float* ln2_g  = (const float*)d_in[7];
  const float* ln2_b  = (const float*)d_in[8];
  const float* W_fc   = (const float*)d_in[9];
  const float* b_fc   = (const float*)d_in[10];
  const float* W_fc2  = (const float*)d_in[11];
  const float* b_fc2  = (const float*)d_in[12];
  float* out = (float*)d_out;
  char* ws = (char*)d_ws;

  const size_t MB = 1u << 20;
  u16* Wattn_t = (u16*)(ws + 0 * MB);   // [3072][1024] 6MB
  u16* Wo_t    = (u16*)(ws + 6 * MB);   // [1024][1024] 2MB
  u16* Wfc_t   = (u16*)(ws + 8 * MB);   // [4096][1024] 8MB
  u16* Wfc2_t  = (u16*)(ws + 16 * MB);  // [1024][4096] 8MB
  float* x1    = (float*)(ws + 24 * MB); // [4096][1024] f32 16MB (persistent)
  u16* h1      = (u16*)(ws + 40 * MB);  // 8MB
  u16* qkv     = (u16*)(ws + 48 * MB);  // 24MB
  u16* Qb      = (u16*)(ws + 72 * MB);  // 8MB
  u16* Kb      = (u16*)(ws + 80 * MB);  // 8MB
  u16* Vt      = (u16*)(ws + 88 * MB);  // 8MB   (total 96MB)
  u16* yb      = (u16*)(ws + 40 * MB);  // reuse h1 (dead after qkv GEMM)
  u16* h2      = (u16*)(ws + 48 * MB);  // reuse qkv (dead after reshape)
  u16* ab      = (u16*)(ws + 56 * MB);  // 32MB, reuses Q/K/Vt region (dead)

  // weights -> bf16 transposed
  wtrans<<<dim3(3072 / 32, 1024 / 32), 256, 0, stream>>>(W_attn, Wattn_t, 1024, 3072);
  wtrans<<<dim3(1024 / 32, 1024 / 32), 256, 0, stream>>>(W_o, Wo_t, 1024, 1024);
  wtrans<<<dim3(4096 / 32, 1024 / 32), 256, 0, stream>>>(W_fc, Wfc_t, 1024, 4096);
  wtrans<<<dim3(1024 / 32, 4096 / 32), 256, 0, stream>>>(W_fc2, Wfc2_t, 4096, 1024);

  // ln1 -> h1
  ln_bf16<<<4096, 256, 0, stream>>>(x, ln1_g, ln1_b, h1);
  // qkv = h1 @ W_attn + b_attn  (bf16 out)
  gemm_bt<0><<<dim3(3072 / 128, 4096 / 128), 256, 0, stream>>>(
      h1, Wattn_t, b_attn, nullptr, qkv, 4096, 3072, 1024);
  // split/reshape
  reshape_qk<<<(2 * 16 * 2048 * 64) / 256, 256, 0, stream>>>(qkv, Qb, Kb);
  transpose_v<<<dim3(2048 / 64, 32), 256, 0, stream>>>(qkv, Vt);
  // attention -> yb [B*T, C] bf16
  attn_kernel<<<dim3(2048 / 64, 32), 256, 0, stream>>>(Qb, Kb, Vt, yb);
  // x1 = x + yb @ W_o + b_o   (f32 out)
  gemm_bt<2><<<dim3(1024 / 128, 4096 / 128), 256, 0, stream>>>(
      yb, Wo_t, b_o, x, x1, 4096, 1024, 1024);
  // ln2 -> h2
  ln_bf16<<<4096, 256, 0, stream>>>(x1, ln2_g, ln2_b, h2);
  // ab = gelu(h2 @ W_fc + b_fc)  (bf16 out)
  gemm_bt<1><<<dim3(4096 / 128, 4096 / 128), 256, 0, stream>>>(
      h2, Wfc_t, b_fc, nullptr, ab, 4096, 4096, 1024);
  // out = x1 + ab @ W_fc2 + b_fc2  (f32 out)
  gemm_bt<2><<<dim3(1024 / 128, 4096 / 128), 256, 0, stream>>>(
      ab, Wfc2_t, b_fc2, x1, out, 4096, 1024, 4096);
}

// Round 3
// 449.389 us; speedup vs baseline: 1.9010x; 1.3222x over previous
//
#include <hip/hip_runtime.h>

// Transformer block on MI355X (gfx950).
// B=2, T=2048, C=1024, H=16, D=64. All GEMMs in bf16 MFMA (16x16x32),
// m97-style 128x128 tiles with global_load_lds(16B). Flash attention with
// online softmax. Weights converted+transposed to bf16 every launch.
//
// R1: acc array was in scratch (tanhf blocked unroll) -> fixed with unroll +
//     inline tanh. R2: attention was latency-bound (238us: per-wave global
//     K/V loads 4x redundant, serial shfl softmax chains).
// R3: attention rewritten: K/V staged in LDS (XOR-swizzled for conflict-free
//     b128 reads), S^T layout puts keys on the register dim (2 shfl per
//     reduction instead of 8 chains), O^T layout makes m/l/alpha lane-local.

typedef unsigned short u16;
typedef unsigned int u32;
typedef __attribute__((ext_vector_type(8))) short v8s;   // 8 x bf16 (4 VGPR)
typedef __attribute__((ext_vector_type(4))) float v4f;   // MFMA acc

#define GAS __attribute__((address_space(1)))
#define LAS __attribute__((address_space(3)))

__device__ __forceinline__ u16 f2bf(float f) {
  u32 u = __float_as_uint(f);
  u = (u + 0x7FFF + ((u >> 16) & 1)) >> 16;  // RNE
  return (u16)u;
}
__device__ __forceinline__ float bf2f(u16 h) {
  return __uint_as_float(((u32)h) << 16);
}
__device__ __forceinline__ float fast_tanh(float x) {
  return 1.f - 2.f / (1.f + __expf(2.f * x));
}

// ---------------- weight transpose + fp32->bf16 convert ----------------
__global__ __launch_bounds__(256)
void wtrans(const float* __restrict__ W, u16* __restrict__ Wt, int K, int N) {
  __shared__ float tile[32][33];
  const int n0 = blockIdx.x << 5, k0 = blockIdx.y << 5;
  const int r = threadIdx.x >> 5, c = threadIdx.x & 31;
#pragma unroll
  for (int i = 0; i < 4; ++i)
    tile[r + 8 * i][c] = W[(size_t)(k0 + r + 8 * i) * N + n0 + c];
  __syncthreads();
#pragma unroll
  for (int i = 0; i < 4; ++i)
    Wt[(size_t)(n0 + r + 8 * i) * K + k0 + c] = f2bf(tile[c][r + 8 * i]);
}

// ---------------- LayerNorm (f32 in -> bf16 out), C=1024 ----------------
__global__ __launch_bounds__(256)
void ln_bf16(const float* __restrict__ x, const float* __restrict__ g,
             const float* __restrict__ be, u16* __restrict__ out) {
  constexpr int C = 1024;
  const int row = blockIdx.x, t = threadIdx.x;
  const float4 v = ((const float4*)(x + (size_t)row * C))[t];
  float s = v.x + v.y + v.z + v.w;
#pragma unroll
  for (int m = 32; m >= 1; m >>= 1) s += __shfl_xor(s, m);
  __shared__ float red[4], red2[4];
  if ((t & 63) == 0) red[t >> 6] = s;
  __syncthreads();
  const float mu = (red[0] + red[1] + red[2] + red[3]) * (1.f / C);
  const float dx = v.x - mu, dy = v.y - mu, dz = v.z - mu, dw = v.w - mu;
  float s2 = dx * dx + dy * dy + dz * dz + dw * dw;
#pragma unroll
  for (int m = 32; m >= 1; m >>= 1) s2 += __shfl_xor(s2, m);
  if ((t & 63) == 0) red2[t >> 6] = s2;
  __syncthreads();
  const float var = (red2[0] + red2[1] + red2[2] + red2[3]) * (1.f / C);
  const float rs = rsqrtf(var + 1e-5f);
  const int c = t << 2;
  u16 o0 = f2bf(dx * rs * g[c + 0] + be[c + 0]);
  u16 o1 = f2bf(dy * rs * g[c + 1] + be[c + 1]);
  u16 o2 = f2bf(dz * rs * g[c + 2] + be[c + 2]);
  u16 o3 = f2bf(dw * rs * g[c + 3] + be[c + 3]);
  uint2 pk;
  pk.x = (u32)o0 | ((u32)o1 << 16);
  pk.y = (u32)o2 | ((u32)o3 << 16);
  *(uint2*)(out + (size_t)row * C + c) = pk;
}

// ---------------- GEMM: C = A[M,K](bf16) * Bt[N,K]^T(bf16) + epilogue ----
template <int EPI>
__global__ __launch_bounds__(256)
void gemm_bt(const u16* __restrict__ A, const u16* __restrict__ Bt,
             const float* __restrict__ bias, const float* __restrict__ res,
             void* __restrict__ outp, int M, int N, int K) {
  __shared__ u16 As[128 * 32];
  __shared__ u16 Bs[128 * 32];
  const int tid = threadIdx.x;
  const int wave = tid >> 6, lane = tid & 63;
  const int m0 = blockIdx.y << 7, n0 = blockIdx.x << 7;

  v4f acc[4][4];
  const v4f vz = {0.f, 0.f, 0.f, 0.f};
#pragma unroll
  for (int i = 0; i < 4; ++i)
#pragma unroll
    for (int j = 0; j < 4; ++j) acc[i][j] = vz;

  const int wm = (wave >> 1) << 6, wn = (wave & 1) << 6;
  const int sr = lane >> 2;
  const int sc = (lane & 3) << 3;
  const int fr = lane & 15;
  const int fk = (lane >> 4) << 3;
  const int c0 = wave << 1;

  u16* lA0 = As + (c0 + 0) * 512;
  u16* lA1 = As + (c0 + 1) * 512;
  u16* lB0 = Bs + (c0 + 0) * 512;
  u16* lB1 = Bs + (c0 + 1) * 512;
  const u16* gA0 = A + (size_t)(m0 + c0 * 16 + sr) * K + sc;
  const u16* gA1 = A + (size_t)(m0 + c0 * 16 + 16 + sr) * K + sc;
  const u16* gB0 = Bt + (size_t)(n0 + c0 * 16 + sr) * K + sc;
  const u16* gB1 = Bt + (size_t)(n0 + c0 * 16 + 16 + sr) * K + sc;

  for (int k0 = 0; k0 < K; k0 += 32) {
    __builtin_amdgcn_global_load_lds((GAS const u32*)(gA0 + k0), (LAS u32*)lA0, 16, 0, 0);
    __builtin_amdgcn_global_load_lds((GAS const u32*)(gA1 + k0), (LAS u32*)lA1, 16, 0, 0);
    __builtin_amdgcn_global_load_lds((GAS const u32*)(gB0 + k0), (LAS u32*)lB0, 16, 0, 0);
    __builtin_amdgcn_global_load_lds((GAS const u32*)(gB1 + k0), (LAS u32*)lB1, 16, 0, 0);
    __syncthreads();
    v8s af[4], bfr[4];
#pragma unroll
    for (int mi = 0; mi < 4; ++mi)
      af[mi] = *(const v8s*)&As[(wm + mi * 16 + fr) * 32 + fk];
#pragma unroll
    for (int ni = 0; ni < 4; ++ni)
      bfr[ni] = *(const v8s*)&Bs[(wn + ni * 16 + fr) * 32 + fk];
#pragma unroll
    for (int mi = 0; mi < 4; ++mi)
#pragma unroll
      for (int ni = 0; ni < 4; ++ni)
        acc[mi][ni] = __builtin_amdgcn_mfma_f32_16x16x32_bf16(af[mi], bfr[ni], acc[mi][ni], 0, 0, 0);
    __syncthreads();
  }

  const int er = (lane >> 4) << 2;
#pragma unroll
  for (int mi = 0; mi < 4; ++mi) {
#pragma unroll
    for (int ni = 0; ni < 4; ++ni) {
      const int col = n0 + wn + ni * 16 + fr;
      const float bcol = bias[col];
#pragma unroll
      for (int r = 0; r < 4; ++r) {
        const int row = m0 + wm + mi * 16 + er + r;
        float v = acc[mi][ni][r] + bcol;
        if constexpr (EPI == 1) {
          const float t = fast_tanh(0.7978845608028654f * (v + 0.044715f * v * v * v));
          v = 0.5f * v * (1.f + t);
        }
        if constexpr (EPI == 2) {
          v += res[(size_t)row * N + col];
          ((float*)outp)[(size_t)row * N + col] = v;
        } else {
          ((u16*)outp)[(size_t)row * N + col] = f2bf(v);
        }
      }
    }
  }
}

// ---------------- qkv [B*T, 3C] bf16 -> Q,K [B,H,T,D] (Q pre-scaled 1/8) --
__global__ __launch_bounds__(256)
void reshape_qk(const u16* __restrict__ qkv, u16* __restrict__ Q,
                u16* __restrict__ Ko) {
  const int idx = blockIdx.x * 256 + threadIdx.x;
  const int d = idx & 63;
  const int t = (idx >> 6) & 2047;
  const int bh = idx >> 17;
  const int b = bh >> 4, h = bh & 15;
  const size_t src = (size_t)(b * 2048 + t) * 3072 + h * 64 + d;
  Q[idx] = f2bf(bf2f(qkv[src]) * 0.125f);
  Ko[idx] = qkv[src + 1024];
}

// ---------------- V -> Vt [B,H,D,T] bf16 (transpose via LDS) -------------
__global__ __launch_bounds__(256)
void transpose_v(const u16* __restrict__ qkv, u16* __restrict__ Vt) {
  __shared__ u16 tile[64][65];
  const int t0 = blockIdx.x << 6;
  const int bh = blockIdx.y;
  const int b = bh >> 4, h = bh & 15;
  const int r4 = threadIdx.x >> 6, c = threadIdx.x & 63;
#pragma unroll
  for (int i = 0; i < 16; ++i) {
    const int r = r4 * 16 + i;
    tile[r][c] = qkv[(size_t)(b * 2048 + t0 + r) * 3072 + 2048 + h * 64 + c];
  }
  __syncthreads();
#pragma unroll
  for (int i = 0; i < 16; ++i) {
    const int d = r4 * 16 + i;
    Vt[(size_t)bh * 64 * 2048 + (size_t)d * 2048 + t0 + c] = tile[c][d];
  }
}

// ---------------- flash attention (causal) -------------------------------
// grid(T/128, B*H), block 256 (4 waves). Wave w: q rows [128*bx+32w, +32).
// 64-key tiles staged in LDS (K[64][64], Vt[64][64], XOR-swizzled col-groups).
// S^T = mfma(Kfrag, Qfrag): keys on reg dim -> in-lane reductions + 2 shfl.
// O^T = mfma(Vfrag, Pfrag): m/l/alpha indexed by q = lane&15, lane-local.
constexpr int PSTR = 88;  // P row stride (u16): 176B = 16B-mult, 2-way banks

template <bool MASKED>
__device__ __forceinline__ void attn_tile(
    const u16* __restrict__ Kt, const u16* __restrict__ Vti,
    u16* __restrict__ pw, const v8s (&qf)[2][2], v4f (&ot)[4][2],
    float (&m_i)[2], float (&l_i)[2], const int fr, const int fg,
    const int kb, const int qw) {
  const v4f vz = {0.f, 0.f, 0.f, 0.f};
  const int swz = fr & 7;
  // --- S^T[key][q] ---
  v4f st[4][2];
#pragma unroll
  for (int ks = 0; ks < 4; ++ks) {
#pragma unroll
    for (int qs = 0; qs < 2; ++qs) st[ks][qs] = vz;
    const int rr = ks * 16 + fr;
    const v8s kf0 = *(const v8s*)&Kt[rr * 64 + ((0 + fg) ^ swz) * 8];
    const v8s kf1 = *(const v8s*)&Kt[rr * 64 + ((4 + fg) ^ swz) * 8];
#pragma unroll
    for (int qs = 0; qs < 2; ++qs) {
      st[ks][qs] = __builtin_amdgcn_mfma_f32_16x16x32_bf16(kf0, qf[qs][0], st[ks][qs], 0, 0, 0);
      st[ks][qs] = __builtin_amdgcn_mfma_f32_16x16x32_bf16(kf1, qf[qs][1], st[ks][qs], 0, 0, 0);
    }
  }
  // --- online softmax (per q-subtile; q = lane&15) ---
#pragma unroll
  for (int qs = 0; qs < 2; ++qs) {
    const int q = qw + qs * 16 + fr;
    float e[4][4];
    float mt = -1e30f;
#pragma unroll
    for (int ks = 0; ks < 4; ++ks)
#pragma unroll
      for (int r = 0; r < 4; ++r) {
        float v = st[ks][qs][r];
        if (MASKED) v = (kb + ks * 16 + fg * 4 + r <= q) ? v : -1e30f;
        e[ks][r] = v;
        mt = fmaxf(mt, v);
      }
    mt = fmaxf(mt, __shfl_xor(mt, 16));
    mt = fmaxf(mt, __shfl_xor(mt, 32));
    const float m_new = fmaxf(m_i[qs], mt);
    const float alpha = __expf(m_i[qs] - m_new);
    m_i[qs] = m_new;
    float ls = 0.f;
#pragma unroll
    for (int ks = 0; ks < 4; ++ks)
#pragma unroll
      for (int r = 0; r < 4; ++r) {
        e[ks][r] = __expf(e[ks][r] - m_new);
        ls += e[ks][r];
      }
    ls += __shfl_xor(ls, 16);
    ls += __shfl_xor(ls, 32);
    l_i[qs] = l_i[qs] * alpha + ls;
#pragma unroll
    for (int ds = 0; ds < 4; ++ds) ot[ds][qs] *= alpha;
#pragma unroll
    for (int ks = 0; ks < 4; ++ks) {
      ushort4 pk4;
      pk4.x = f2bf(e[ks][0]);
      pk4.y = f2bf(e[ks][1]);
      pk4.z = f2bf(e[ks][2]);
      pk4.w = f2bf(e[ks][3]);
      *(ushort4*)&pw[(qs * 16 + fr) * PSTR + ks * 16 + fg * 4] = pk4;
    }
  }
  // --- O^T += V^T P^T  (P read back in B-frag layout, same wave: lgkmcnt) ---
  v8s vfr[4][2];
#pragma unroll
  for (int ds = 0; ds < 4; ++ds) {
    const int rr = ds * 16 + fr;
    vfr[ds][0] = *(const v8s*)&Vti[rr * 64 + ((0 + fg) ^ swz) * 8];
    vfr[ds][1] = *(const v8s*)&Vti[rr * 64 + ((4 + fg) ^ swz) * 8];
  }
#pragma unroll
  for (int qs = 0; qs < 2; ++qs) {
    const v8s pf0 = *(const v8s*)&pw[(qs * 16 + fr) * PSTR + 0 * 32 + fg * 8];
    const v8s pf1 = *(const v8s*)&pw[(qs * 16 + fr) * PSTR + 1 * 32 + fg * 8];
#pragma unroll
    for (int ds = 0; ds < 4; ++ds) {
      ot[ds][qs] = __builtin_amdgcn_mfma_f32_16x16x32_bf16(vfr[ds][0], pf0, ot[ds][qs], 0, 0, 0);
      ot[ds][qs] = __builtin_amdgcn_mfma_f32_16x16x32_bf16(vfr[ds][1], pf1, ot[ds][qs], 0, 0, 0);
    }
  }
}

__global__ __launch_bounds__(256)
void attn_kernel(const u16* __restrict__ Q, const u16* __restrict__ K,
                 const u16* __restrict__ Vt, u16* __restrict__ y) {
  constexpr int T = 2048, D = 64, C = 1024;
  __shared__ alignas(16) u16 Ktile[64 * 64];
  __shared__ alignas(16) u16 Vtile[64 * 64];
  __shared__ alignas(16) u16 Pw[4][32 * PSTR];

  const int tid = threadIdx.x, wave = tid >> 6, lane = tid & 63;
  const int fr = lane & 15, fg = lane >> 4;
  const int bh = blockIdx.y, b = bh >> 4, h = bh & 15;
  const int qw = blockIdx.x * 128 + wave * 32;
  const u16* Qh = Q + (size_t)bh * T * D;
  const u16* Kh = K + (size_t)bh * T * D;
  const u16* Vh = Vt + (size_t)bh * D * T;
  u16* pw = &Pw[wave][0];

  // Q fragments (B-operand: lane&15 = q, k = d)
  v8s qf[2][2];
#pragma unroll
  for (int qs = 0; qs < 2; ++qs)
#pragma unroll
    for (int dh = 0; dh < 2; ++dh)
      qf[qs][dh] = *(const v8s*)&Qh[(size_t)(qw + qs * 16 + fr) * D + dh * 32 + fg * 8];

  const v4f vz = {0.f, 0.f, 0.f, 0.f};
  v4f ot[4][2];
#pragma unroll
  for (int ds = 0; ds < 4; ++ds)
#pragma unroll
    for (int qs = 0; qs < 2; ++qs) ot[ds][qs] = vz;
  float m_i[2] = {-1e30f, -1e30f}, l_i[2] = {0.f, 0.f};

  const int n_blk = 2 * blockIdx.x + 2;
  for (int kt = 0; kt < n_blk; ++kt) {
    const int kb = kt << 6;
    __syncthreads();  // previous tile's LDS reads done before overwrite
    // stage K rows [wave*16, +16) and Vt rows [wave*16, +16), 8 rows/call
#pragma unroll
    for (int cc = 0; cc < 2; ++cc) {
      const int r0 = wave * 16 + cc * 8;
      const int rr = r0 + (lane >> 3);
      const int gg = (lane & 7) ^ (rr & 7);
      __builtin_amdgcn_global_load_lds(
          (GAS const u32*)(Kh + (size_t)(kb + rr) * D + gg * 8),
          (LAS u32*)(Ktile + r0 * 64), 16, 0, 0);
      __builtin_amdgcn_global_load_lds(
          (GAS const u32*)(Vh + (size_t)rr * T + kb + gg * 8),
          (LAS u32*)(Vtile + r0 * 64), 16, 0, 0);
    }
    __syncthreads();  // staging complete (syncthreads drains vmcnt)
    if (kb <= qw + 31) {  // wave-uniform causal skip
      if (kb + 63 > qw)
        attn_tile<true>(Ktile, Vtile, pw, qf, ot, m_i, l_i, fr, fg, kb, qw);
      else
        attn_tile<false>(Ktile, Vtile, pw, qf, ot, m_i, l_i, fr, fg, kb, qw);
    }
  }

  const float inv_l[2] = {1.f / l_i[0], 1.f / l_i[1]};
#pragma unroll
  for (int qs = 0; qs < 2; ++qs)
#pragma unroll
    for (int ds = 0; ds < 4; ++ds) {
      ushort4 o4;
      o4.x = f2bf(ot[ds][qs][0] * inv_l[qs]);
      o4.y = f2bf(ot[ds][qs][1] * inv_l[qs]);
      o4.z = f2bf(ot[ds][qs][2] * inv_l[qs]);
      o4.w = f2bf(ot[ds][qs][3] * inv_l[qs]);
      *(ushort4*)&y[(size_t)(b * T + qw + qs * 16 + fr) * C + h * D + ds * 16 + fg * 4] = o4;
    }
}

// ------------------------------- launch ----------------------------------
extern "C" void kernel_launch(void* const* d_in, const int* in_sizes, int n_in,
                              void* d_out, int out_size, void* d_ws, size_t ws_size,
                              hipStream_t stream) {
  const float* x      = (const float*)d_in[0];
  const float* ln1_g  = (const float*)d_in[1];
  const float* ln1_b  = (const float*)d_in[2];
  const float* W_attn = (const float*)d_in[3];
  const float* b_attn = (const float*)d_in[4];
  const float* W_o    = (const float*)d_in[5];
  const float* b_o    = (const float*)d_in[6];
  const float* ln2_g  = (const float*)d_in[7];
  const float* ln2_b  = (const float*)d_in[8];
  const float* W_fc   = (const float*)d_in[9];
  const float* b_fc   = (const float*)d_in[10];
  const float* W_fc2  = (const float*)d_in[11];
  const float* b_fc2  = (const float*)d_in[12];
  float* out = (float*)d_out;
  char* ws = (char*)d_ws;

  const size_t MB = 1u << 20;
  u16* Wattn_t = (u16*)(ws + 0 * MB);
  u16* Wo_t    = (u16*)(ws + 6 * MB);
  u16* Wfc_t   = (u16*)(ws + 8 * MB);
  u16* Wfc2_t  = (u16*)(ws + 16 * MB);
  float* x1    = (float*)(ws + 24 * MB);
  u16* h1      = (u16*)(ws + 40 * MB);
  u16* qkv     = (u16*)(ws + 48 * MB);
  u16* Qb      = (u16*)(ws + 72 * MB);
  u16* Kb      = (u16*)(ws + 80 * MB);
  u16* Vt      = (u16*)(ws + 88 * MB);
  u16* yb      = (u16*)(ws + 40 * MB);
  u16* h2      = (u16*)(ws + 48 * MB);
  u16* ab      = (u16*)(ws + 56 * MB);

  wtrans<<<dim3(3072 / 32, 1024 / 32), 256, 0, stream>>>(W_attn, Wattn_t, 1024, 3072);
  wtrans<<<dim3(1024 / 32, 1024 / 32), 256, 0, stream>>>(W_o, Wo_t, 1024, 1024);
  wtrans<<<dim3(4096 / 32, 1024 / 32), 256, 0, stream>>>(W_fc, Wfc_t, 1024, 4096);
  wtrans<<<dim3(1024 / 32, 4096 / 32), 256, 0, stream>>>(W_fc2, Wfc2_t, 4096, 1024);

  ln_bf16<<<4096, 256, 0, stream>>>(x, ln1_g, ln1_b, h1);
  gemm_bt<0><<<dim3(3072 / 128, 4096 / 128), 256, 0, stream>>>(
      h1, Wattn_t, b_attn, nullptr, qkv, 4096, 3072, 1024);
  reshape_qk<<<(2 * 16 * 2048 * 64) / 256, 256, 0, stream>>>(qkv, Qb, Kb);
  transpose_v<<<dim3(2048 / 64, 32), 256, 0, stream>>>(qkv, Vt);
  attn_kernel<<<dim3(2048 / 128, 32), 256, 0, stream>>>(Qb, Kb, Vt, yb);
  gemm_bt<2><<<dim3(1024 / 128, 4096 / 128), 256, 0, stream>>>(
      yb, Wo_t, b_o, x, x1, 4096, 1024, 1024);
  ln_bf16<<<4096, 256, 0, stream>>>(x1, ln2_g, ln2_b, h2);
  gemm_bt<1><<<dim3(4096 / 128, 4096 / 128), 256, 0, stream>>>(
      h2, Wfc_t, b_fc, nullptr, ab, 4096, 4096, 1024);
  gemm_bt<2><<<dim3(1024 / 128, 4096 / 128), 256, 0, stream>>>(
      ab, Wfc2_t, b_fc2, x1, out, 4096, 1024, 4096);
}

// Round 4
// 418.184 us; speedup vs baseline: 2.0429x; 1.0746x over previous
//
#include <hip/hip_runtime.h>

// Transformer block on MI355X (gfx950).
// B=2, T=2048, C=1024, H=16, D=64. All GEMMs in bf16 MFMA (16x16x32).
// R1: acc array in scratch (tanhf blocked unroll) -> unroll + inline tanh.
// R2: attention latency-bound -> LDS-staged K/V, S^T/O^T register layouts.
// R3: N=1024 GEMMs (proj, fc2) were occupancy-bound: grid 256 = 1 block/CU
//     (Occupancy 10%, MfmaUtil 13%). R4: dedicated BN=64 kernel (grid 512,
//     2 blocks/CU) with explicit LDS double-buffering (no in-loop vmcnt(0)
//     drain of the *current* tile; prefetch has a full compute phase).

typedef unsigned short u16;
typedef unsigned int u32;
typedef __attribute__((ext_vector_type(8))) short v8s;   // 8 x bf16 (4 VGPR)
typedef __attribute__((ext_vector_type(4))) float v4f;   // MFMA acc

#define GAS __attribute__((address_space(1)))
#define LAS __attribute__((address_space(3)))

__device__ __forceinline__ u16 f2bf(float f) {
  u32 u = __float_as_uint(f);
  u = (u + 0x7FFF + ((u >> 16) & 1)) >> 16;  // RNE
  return (u16)u;
}
__device__ __forceinline__ float bf2f(u16 h) {
  return __uint_as_float(((u32)h) << 16);
}
__device__ __forceinline__ float fast_tanh(float x) {
  return 1.f - 2.f / (1.f + __expf(2.f * x));
}

// ---------------- weight transpose + fp32->bf16 convert ----------------
__global__ __launch_bounds__(256)
void wtrans(const float* __restrict__ W, u16* __restrict__ Wt, int K, int N) {
  __shared__ float tile[32][33];
  const int n0 = blockIdx.x << 5, k0 = blockIdx.y << 5;
  const int r = threadIdx.x >> 5, c = threadIdx.x & 31;
#pragma unroll
  for (int i = 0; i < 4; ++i)
    tile[r + 8 * i][c] = W[(size_t)(k0 + r + 8 * i) * N + n0 + c];
  __syncthreads();
#pragma unroll
  for (int i = 0; i < 4; ++i)
    Wt[(size_t)(n0 + r + 8 * i) * K + k0 + c] = f2bf(tile[c][r + 8 * i]);
}

// ---------------- LayerNorm (f32 in -> bf16 out), C=1024 ----------------
__global__ __launch_bounds__(256)
void ln_bf16(const float* __restrict__ x, const float* __restrict__ g,
             const float* __restrict__ be, u16* __restrict__ out) {
  constexpr int C = 1024;
  const int row = blockIdx.x, t = threadIdx.x;
  const float4 v = ((const float4*)(x + (size_t)row * C))[t];
  float s = v.x + v.y + v.z + v.w;
#pragma unroll
  for (int m = 32; m >= 1; m >>= 1) s += __shfl_xor(s, m);
  __shared__ float red[4], red2[4];
  if ((t & 63) == 0) red[t >> 6] = s;
  __syncthreads();
  const float mu = (red[0] + red[1] + red[2] + red[3]) * (1.f / C);
  const float dx = v.x - mu, dy = v.y - mu, dz = v.z - mu, dw = v.w - mu;
  float s2 = dx * dx + dy * dy + dz * dz + dw * dw;
#pragma unroll
  for (int m = 32; m >= 1; m >>= 1) s2 += __shfl_xor(s2, m);
  if ((t & 63) == 0) red2[t >> 6] = s2;
  __syncthreads();
  const float var = (red2[0] + red2[1] + red2[2] + red2[3]) * (1.f / C);
  const float rs = rsqrtf(var + 1e-5f);
  const int c = t << 2;
  u16 o0 = f2bf(dx * rs * g[c + 0] + be[c + 0]);
  u16 o1 = f2bf(dy * rs * g[c + 1] + be[c + 1]);
  u16 o2 = f2bf(dz * rs * g[c + 2] + be[c + 2]);
  u16 o3 = f2bf(dw * rs * g[c + 3] + be[c + 3]);
  uint2 pk;
  pk.x = (u32)o0 | ((u32)o1 << 16);
  pk.y = (u32)o2 | ((u32)o3 << 16);
  *(uint2*)(out + (size_t)row * C + c) = pk;
}

// ------- GEMM 128x128: C = A[M,K] * Bt[N,K]^T + epilogue (qkv, fc1) -----
// EPI 0: +bias -> bf16 | EPI 1: +bias,gelu -> bf16 | EPI 2: +bias,+res -> f32
template <int EPI>
__global__ __launch_bounds__(256)
void gemm_bt(const u16* __restrict__ A, const u16* __restrict__ Bt,
             const float* __restrict__ bias, const float* __restrict__ res,
             void* __restrict__ outp, int M, int N, int K) {
  __shared__ u16 As[128 * 32];
  __shared__ u16 Bs[128 * 32];
  const int tid = threadIdx.x;
  const int wave = tid >> 6, lane = tid & 63;
  const int m0 = blockIdx.y << 7, n0 = blockIdx.x << 7;

  v4f acc[4][4];
  const v4f vz = {0.f, 0.f, 0.f, 0.f};
#pragma unroll
  for (int i = 0; i < 4; ++i)
#pragma unroll
    for (int j = 0; j < 4; ++j) acc[i][j] = vz;

  const int wm = (wave >> 1) << 6, wn = (wave & 1) << 6;
  const int sr = lane >> 2;
  const int sc = (lane & 3) << 3;
  const int fr = lane & 15;
  const int fk = (lane >> 4) << 3;
  const int c0 = wave << 1;

  u16* lA0 = As + (c0 + 0) * 512;
  u16* lA1 = As + (c0 + 1) * 512;
  u16* lB0 = Bs + (c0 + 0) * 512;
  u16* lB1 = Bs + (c0 + 1) * 512;
  const u16* gA0 = A + (size_t)(m0 + c0 * 16 + sr) * K + sc;
  const u16* gA1 = A + (size_t)(m0 + c0 * 16 + 16 + sr) * K + sc;
  const u16* gB0 = Bt + (size_t)(n0 + c0 * 16 + sr) * K + sc;
  const u16* gB1 = Bt + (size_t)(n0 + c0 * 16 + 16 + sr) * K + sc;

  for (int k0 = 0; k0 < K; k0 += 32) {
    __builtin_amdgcn_global_load_lds((GAS const u32*)(gA0 + k0), (LAS u32*)lA0, 16, 0, 0);
    __builtin_amdgcn_global_load_lds((GAS const u32*)(gA1 + k0), (LAS u32*)lA1, 16, 0, 0);
    __builtin_amdgcn_global_load_lds((GAS const u32*)(gB0 + k0), (LAS u32*)lB0, 16, 0, 0);
    __builtin_amdgcn_global_load_lds((GAS const u32*)(gB1 + k0), (LAS u32*)lB1, 16, 0, 0);
    __syncthreads();
    v8s af[4], bfr[4];
#pragma unroll
    for (int mi = 0; mi < 4; ++mi)
      af[mi] = *(const v8s*)&As[(wm + mi * 16 + fr) * 32 + fk];
#pragma unroll
    for (int ni = 0; ni < 4; ++ni)
      bfr[ni] = *(const v8s*)&Bs[(wn + ni * 16 + fr) * 32 + fk];
#pragma unroll
    for (int mi = 0; mi < 4; ++mi)
#pragma unroll
      for (int ni = 0; ni < 4; ++ni)
        acc[mi][ni] = __builtin_amdgcn_mfma_f32_16x16x32_bf16(af[mi], bfr[ni], acc[mi][ni], 0, 0, 0);
    __syncthreads();
  }

  const int er = (lane >> 4) << 2;
#pragma unroll
  for (int mi = 0; mi < 4; ++mi) {
#pragma unroll
    for (int ni = 0; ni < 4; ++ni) {
      const int col = n0 + wn + ni * 16 + fr;
      const float bcol = bias[col];
#pragma unroll
      for (int r = 0; r < 4; ++r) {
        const int row = m0 + wm + mi * 16 + er + r;
        float v = acc[mi][ni][r] + bcol;
        if constexpr (EPI == 1) {
          const float t = fast_tanh(0.7978845608028654f * (v + 0.044715f * v * v * v));
          v = 0.5f * v * (1.f + t);
        }
        if constexpr (EPI == 2) {
          v += res[(size_t)row * N + col];
          ((float*)outp)[(size_t)row * N + col] = v;
        } else {
          ((u16*)outp)[(size_t)row * N + col] = f2bf(v);
        }
      }
    }
  }
}

// ------- GEMM 128x64 double-buffered: for N=1024 outputs (proj, fc2) -----
// grid(N/64, M/128) = 512 blocks -> 2 blocks/CU. Explicit LDS dbuf so the
// barrier only drains loads issued a full compute-phase earlier.
template <int EPI>
__global__ __launch_bounds__(256)
void gemm_bt_n64(const u16* __restrict__ A, const u16* __restrict__ Bt,
                 const float* __restrict__ bias, const float* __restrict__ res,
                 void* __restrict__ outp, int M, int N, int K) {
  __shared__ u16 As[2][128 * 32];
  __shared__ u16 Bs[2][64 * 32];
  const int tid = threadIdx.x;
  const int wave = tid >> 6, lane = tid & 63;
  const int m0 = blockIdx.y << 7, n0 = blockIdx.x << 6;

  v4f acc[4][2];
  const v4f vz = {0.f, 0.f, 0.f, 0.f};
#pragma unroll
  for (int i = 0; i < 4; ++i)
#pragma unroll
    for (int j = 0; j < 2; ++j) acc[i][j] = vz;

  const int wm = (wave >> 1) << 6, wn = (wave & 1) << 5;
  const int sr = lane >> 2;
  const int sc = (lane & 3) << 3;
  const int fr = lane & 15;
  const int fk = (lane >> 4) << 3;

  // staging: wave stages A rows [32w,32w+32) (2 issues) and B rows [16w,16w+16)
  const u16* gA0 = A + (size_t)(m0 + wave * 32 + sr) * K + sc;
  const u16* gA1 = A + (size_t)(m0 + wave * 32 + 16 + sr) * K + sc;
  const u16* gB0 = Bt + (size_t)(n0 + wave * 16 + sr) * K + sc;
  const int aoff = wave * 1024;  // (wave*32 rows)*32 cols
  const int boff = wave * 512;   // (wave*16 rows)*32 cols

  const int nk = K >> 5;
  {
    __builtin_amdgcn_global_load_lds((GAS const u32*)gA0, (LAS u32*)(As[0] + aoff), 16, 0, 0);
    __builtin_amdgcn_global_load_lds((GAS const u32*)gA1, (LAS u32*)(As[0] + aoff + 512), 16, 0, 0);
    __builtin_amdgcn_global_load_lds((GAS const u32*)gB0, (LAS u32*)(Bs[0] + boff), 16, 0, 0);
  }
  for (int kt = 0; kt < nk; ++kt) {
    __syncthreads();  // tile kt staged (issued one iter ago) + prior reads done
    if (kt + 1 < nk) {
      const int k0 = (kt + 1) << 5;
      const int nb = (kt + 1) & 1;
      __builtin_amdgcn_global_load_lds((GAS const u32*)(gA0 + k0), (LAS u32*)(As[nb] + aoff), 16, 0, 0);
      __builtin_amdgcn_global_load_lds((GAS const u32*)(gA1 + k0), (LAS u32*)(As[nb] + aoff + 512), 16, 0, 0);
      __builtin_amdgcn_global_load_lds((GAS const u32*)(gB0 + k0), (LAS u32*)(Bs[nb] + boff), 16, 0, 0);
    }
    const u16* Ab = As[kt & 1];
    const u16* Bb = Bs[kt & 1];
    v8s af[4], bfr[2];
#pragma unroll
    for (int mi = 0; mi < 4; ++mi)
      af[mi] = *(const v8s*)&Ab[(wm + mi * 16 + fr) * 32 + fk];
#pragma unroll
    for (int ni = 0; ni < 2; ++ni)
      bfr[ni] = *(const v8s*)&Bb[(wn + ni * 16 + fr) * 32 + fk];
#pragma unroll
    for (int mi = 0; mi < 4; ++mi)
#pragma unroll
      for (int ni = 0; ni < 2; ++ni)
        acc[mi][ni] = __builtin_amdgcn_mfma_f32_16x16x32_bf16(af[mi], bfr[ni], acc[mi][ni], 0, 0, 0);
  }

  const int er = (lane >> 4) << 2;
#pragma unroll
  for (int mi = 0; mi < 4; ++mi) {
#pragma unroll
    for (int ni = 0; ni < 2; ++ni) {
      const int col = n0 + wn + ni * 16 + fr;
      const float bcol = bias[col];
#pragma unroll
      for (int r = 0; r < 4; ++r) {
        const int row = m0 + wm + mi * 16 + er + r;
        float v = acc[mi][ni][r] + bcol;
        if constexpr (EPI == 1) {
          const float t = fast_tanh(0.7978845608028654f * (v + 0.044715f * v * v * v));
          v = 0.5f * v * (1.f + t);
        }
        if constexpr (EPI == 2) {
          v += res[(size_t)row * N + col];
          ((float*)outp)[(size_t)row * N + col] = v;
        } else {
          ((u16*)outp)[(size_t)row * N + col] = f2bf(v);
        }
      }
    }
  }
}

// ---------------- qkv [B*T, 3C] bf16 -> Q,K [B,H,T,D] (Q pre-scaled 1/8) --
__global__ __launch_bounds__(256)
void reshape_qk(const u16* __restrict__ qkv, u16* __restrict__ Q,
                u16* __restrict__ Ko) {
  const int idx = blockIdx.x * 256 + threadIdx.x;
  const int d = idx & 63;
  const int t = (idx >> 6) & 2047;
  const int bh = idx >> 17;
  const int b = bh >> 4, h = bh & 15;
  const size_t src = (size_t)(b * 2048 + t) * 3072 + h * 64 + d;
  Q[idx] = f2bf(bf2f(qkv[src]) * 0.125f);
  Ko[idx] = qkv[src + 1024];
}

// ---------------- V -> Vt [B,H,D,T] bf16 (transpose via LDS) -------------
__global__ __launch_bounds__(256)
void transpose_v(const u16* __restrict__ qkv, u16* __restrict__ Vt) {
  __shared__ u16 tile[64][65];
  const int t0 = blockIdx.x << 6;
  const int bh = blockIdx.y;
  const int b = bh >> 4, h = bh & 15;
  const int r4 = threadIdx.x >> 6, c = threadIdx.x & 63;
#pragma unroll
  for (int i = 0; i < 16; ++i) {
    const int r = r4 * 16 + i;
    tile[r][c] = qkv[(size_t)(b * 2048 + t0 + r) * 3072 + 2048 + h * 64 + c];
  }
  __syncthreads();
#pragma unroll
  for (int i = 0; i < 16; ++i) {
    const int d = r4 * 16 + i;
    Vt[(size_t)bh * 64 * 2048 + (size_t)d * 2048 + t0 + c] = tile[c][d];
  }
}

// ---------------- flash attention (causal) -------------------------------
constexpr int PSTR = 88;  // P row stride (u16): 176B = 16B-mult, 2-way banks

template <bool MASKED>
__device__ __forceinline__ void attn_tile(
    const u16* __restrict__ Kt, const u16* __restrict__ Vti,
    u16* __restrict__ pw, const v8s (&qf)[2][2], v4f (&ot)[4][2],
    float (&m_i)[2], float (&l_i)[2], const int fr, const int fg,
    const int kb, const int qw) {
  const v4f vz = {0.f, 0.f, 0.f, 0.f};
  const int swz = fr & 7;
  v4f st[4][2];
#pragma unroll
  for (int ks = 0; ks < 4; ++ks) {
#pragma unroll
    for (int qs = 0; qs < 2; ++qs) st[ks][qs] = vz;
    const int rr = ks * 16 + fr;
    const v8s kf0 = *(const v8s*)&Kt[rr * 64 + ((0 + fg) ^ swz) * 8];
    const v8s kf1 = *(const v8s*)&Kt[rr * 64 + ((4 + fg) ^ swz) * 8];
#pragma unroll
    for (int qs = 0; qs < 2; ++qs) {
      st[ks][qs] = __builtin_amdgcn_mfma_f32_16x16x32_bf16(kf0, qf[qs][0], st[ks][qs], 0, 0, 0);
      st[ks][qs] = __builtin_amdgcn_mfma_f32_16x16x32_bf16(kf1, qf[qs][1], st[ks][qs], 0, 0, 0);
    }
  }
#pragma unroll
  for (int qs = 0; qs < 2; ++qs) {
    const int q = qw + qs * 16 + fr;
    float e[4][4];
    float mt = -1e30f;
#pragma unroll
    for (int ks = 0; ks < 4; ++ks)
#pragma unroll
      for (int r = 0; r < 4; ++r) {
        float v = st[ks][qs][r];
        if (MASKED) v = (kb + ks * 16 + fg * 4 + r <= q) ? v : -1e30f;
        e[ks][r] = v;
        mt = fmaxf(mt, v);
      }
    mt = fmaxf(mt, __shfl_xor(mt, 16));
    mt = fmaxf(mt, __shfl_xor(mt, 32));
    const float m_new = fmaxf(m_i[qs], mt);
    const float alpha = __expf(m_i[qs] - m_new);
    m_i[qs] = m_new;
    float ls = 0.f;
#pragma unroll
    for (int ks = 0; ks < 4; ++ks)
#pragma unroll
      for (int r = 0; r < 4; ++r) {
        e[ks][r] = __expf(e[ks][r] - m_new);
        ls += e[ks][r];
      }
    ls += __shfl_xor(ls, 16);
    ls += __shfl_xor(ls, 32);
    l_i[qs] = l_i[qs] * alpha + ls;
#pragma unroll
    for (int ds = 0; ds < 4; ++ds) ot[ds][qs] *= alpha;
#pragma unroll
    for (int ks = 0; ks < 4; ++ks) {
      ushort4 pk4;
      pk4.x = f2bf(e[ks][0]);
      pk4.y = f2bf(e[ks][1]);
      pk4.z = f2bf(e[ks][2]);
      pk4.w = f2bf(e[ks][3]);
      *(ushort4*)&pw[(qs * 16 + fr) * PSTR + ks * 16 + fg * 4] = pk4;
    }
  }
  v8s vfr[4][2];
#pragma unroll
  for (int ds = 0; ds < 4; ++ds) {
    const int rr = ds * 16 + fr;
    vfr[ds][0] = *(const v8s*)&Vti[rr * 64 + ((0 + fg) ^ swz) * 8];
    vfr[ds][1] = *(const v8s*)&Vti[rr * 64 + ((4 + fg) ^ swz) * 8];
  }
#pragma unroll
  for (int qs = 0; qs < 2; ++qs) {
    const v8s pf0 = *(const v8s*)&pw[(qs * 16 + fr) * PSTR + 0 * 32 + fg * 8];
    const v8s pf1 = *(const v8s*)&pw[(qs * 16 + fr) * PSTR + 1 * 32 + fg * 8];
#pragma unroll
    for (int ds = 0; ds < 4; ++ds) {
      ot[ds][qs] = __builtin_amdgcn_mfma_f32_16x16x32_bf16(vfr[ds][0], pf0, ot[ds][qs], 0, 0, 0);
      ot[ds][qs] = __builtin_amdgcn_mfma_f32_16x16x32_bf16(vfr[ds][1], pf1, ot[ds][qs], 0, 0, 0);
    }
  }
}

__global__ __launch_bounds__(256)
void attn_kernel(const u16* __restrict__ Q, const u16* __restrict__ K,
                 const u16* __restrict__ Vt, u16* __restrict__ y) {
  constexpr int T = 2048, D = 64, C = 1024;
  __shared__ alignas(16) u16 Ktile[64 * 64];
  __shared__ alignas(16) u16 Vtile[64 * 64];
  __shared__ alignas(16) u16 Pw[4][32 * PSTR];

  const int tid = threadIdx.x, wave = tid >> 6, lane = tid & 63;
  const int fr = lane & 15, fg = lane >> 4;
  const int bh = blockIdx.y, b = bh >> 4, h = bh & 15;
  const int qw = blockIdx.x * 128 + wave * 32;
  const u16* Qh = Q + (size_t)bh * T * D;
  const u16* Kh = K + (size_t)bh * T * D;
  const u16* Vh = Vt + (size_t)bh * D * T;
  u16* pw = &Pw[wave][0];

  v8s qf[2][2];
#pragma unroll
  for (int qs = 0; qs < 2; ++qs)
#pragma unroll
    for (int dh = 0; dh < 2; ++dh)
      qf[qs][dh] = *(const v8s*)&Qh[(size_t)(qw + qs * 16 + fr) * D + dh * 32 + fg * 8];

  const v4f vz = {0.f, 0.f, 0.f, 0.f};
  v4f ot[4][2];
#pragma unroll
  for (int ds = 0; ds < 4; ++ds)
#pragma unroll
    for (int qs = 0; qs < 2; ++qs) ot[ds][qs] = vz;
  float m_i[2] = {-1e30f, -1e30f}, l_i[2] = {0.f, 0.f};

  const int n_blk = 2 * blockIdx.x + 2;
  for (int kt = 0; kt < n_blk; ++kt) {
    const int kb = kt << 6;
    __syncthreads();
#pragma unroll
    for (int cc = 0; cc < 2; ++cc) {
      const int r0 = wave * 16 + cc * 8;
      const int rr = r0 + (lane >> 3);
      const int gg = (lane & 7) ^ (rr & 7);
      __builtin_amdgcn_global_load_lds(
          (GAS const u32*)(Kh + (size_t)(kb + rr) * D + gg * 8),
          (LAS u32*)(Ktile + r0 * 64), 16, 0, 0);
      __builtin_amdgcn_global_load_lds(
          (GAS const u32*)(Vh + (size_t)rr * T + kb + gg * 8),
          (LAS u32*)(Vtile + r0 * 64), 16, 0, 0);
    }
    __syncthreads();
    if (kb <= qw + 31) {
      if (kb + 63 > qw)
        attn_tile<true>(Ktile, Vtile, pw, qf, ot, m_i, l_i, fr, fg, kb, qw);
      else
        attn_tile<false>(Ktile, Vtile, pw, qf, ot, m_i, l_i, fr, fg, kb, qw);
    }
  }

  const float inv_l[2] = {1.f / l_i[0], 1.f / l_i[1]};
#pragma unroll
  for (int qs = 0; qs < 2; ++qs)
#pragma unroll
    for (int ds = 0; ds < 4; ++ds) {
      ushort4 o4;
      o4.x = f2bf(ot[ds][qs][0] * inv_l[qs]);
      o4.y = f2bf(ot[ds][qs][1] * inv_l[qs]);
      o4.z = f2bf(ot[ds][qs][2] * inv_l[qs]);
      o4.w = f2bf(ot[ds][qs][3] * inv_l[qs]);
      *(ushort4*)&y[(size_t)(b * T + qw + qs * 16 + fr) * C + h * D + ds * 16 + fg * 4] = o4;
    }
}

// ------------------------------- launch ----------------------------------
extern "C" void kernel_launch(void* const* d_in, const int* in_sizes, int n_in,
                              void* d_out, int out_size, void* d_ws, size_t ws_size,
                              hipStream_t stream) {
  const float* x      = (const float*)d_in[0];
  const float* ln1_g  = (const float*)d_in[1];
  const float* ln1_b  = (const float*)d_in[2];
  const float* W_attn = (const float*)d_in[3];
  const float* b_attn = (const float*)d_in[4];
  const float* W_o    = (const float*)d_in[5];
  const float* b_o    = (const float*)d_in[6];
  const float* ln2_g  = (const float*)d_in[7];
  const float* ln2_b  = (const float*)d_in[8];
  const float* W_fc   = (const float*)d_in[9];
  const float* b_fc   = (const float*)d_in[10];
  const float* W_fc2  = (const float*)d_in[11];
  const float* b_fc2  = (const float*)d_in[12];
  float* out = (float*)d_out;
  char* ws = (char*)d_ws;

  const size_t MB = 1u << 20;
  u16* Wattn_t = (u16*)(ws + 0 * MB);
  u16* Wo_t    = (u16*)(ws + 6 * MB);
  u16* Wfc_t   = (u16*)(ws + 8 * MB);
  u16* Wfc2_t  = (u16*)(ws + 16 * MB);
  float* x1    = (float*)(ws + 24 * MB);
  u16* h1      = (u16*)(ws + 40 * MB);
  u16* qkv     = (u16*)(ws + 48 * MB);
  u16* Qb      = (u16*)(ws + 72 * MB);
  u16* Kb      = (u16*)(ws + 80 * MB);
  u16* Vt      = (u16*)(ws + 88 * MB);
  u16* yb      = (u16*)(ws + 40 * MB);
  u16* h2      = (u16*)(ws + 48 * MB);
  u16* ab      = (u16*)(ws + 56 * MB);

  wtrans<<<dim3(3072 / 32, 1024 / 32), 256, 0, stream>>>(W_attn, Wattn_t, 1024, 3072);
  wtrans<<<dim3(1024 / 32, 1024 / 32), 256, 0, stream>>>(W_o, Wo_t, 1024, 1024);
  wtrans<<<dim3(4096 / 32, 1024 / 32), 256, 0, stream>>>(W_fc, Wfc_t, 1024, 4096);
  wtrans<<<dim3(1024 / 32, 4096 / 32), 256, 0, stream>>>(W_fc2, Wfc2_t, 4096, 1024);

  ln_bf16<<<4096, 256, 0, stream>>>(x, ln1_g, ln1_b, h1);
  gemm_bt<0><<<dim3(3072 / 128, 4096 / 128), 256, 0, stream>>>(
      h1, Wattn_t, b_attn, nullptr, qkv, 4096, 3072, 1024);
  reshape_qk<<<(2 * 16 * 2048 * 64) / 256, 256, 0, stream>>>(qkv, Qb, Kb);
  transpose_v<<<dim3(2048 / 64, 32), 256, 0, stream>>>(qkv, Vt);
  attn_kernel<<<dim3(2048 / 128, 32), 256, 0, stream>>>(Qb, Kb, Vt, yb);
  gemm_bt_n64<2><<<dim3(1024 / 64, 4096 / 128), 256, 0, stream>>>(
      yb, Wo_t, b_o, x, x1, 4096, 1024, 1024);
  ln_bf16<<<4096, 256, 0, stream>>>(x1, ln2_g, ln2_b, h2);
  gemm_bt<1><<<dim3(4096 / 128, 4096 / 128), 256, 0, stream>>>(
      h2, Wfc_t, b_fc, nullptr, ab, 4096, 4096, 1024);
  gemm_bt_n64<2><<<dim3(1024 / 64, 4096 / 128), 256, 0, stream>>>(
      ab, Wfc2_t, b_fc2, x1, out, 4096, 1024, 4096);
}

// Round 5
// 390.041 us; speedup vs baseline: 2.1903x; 1.0722x over previous
//
#include <hip/hip_runtime.h>

// Transformer block on MI355X (gfx950).
// B=2, T=2048, C=1024, H=16, D=64. All GEMMs in bf16 MFMA (16x16x32).
// R1: acc array in scratch (tanhf blocked unroll) -> unroll + inline tanh.
// R2: attention latency-bound -> LDS-staged K/V, S^T/O^T register layouts.
// R3/R4: N=1024 GEMMs occupancy-bound -> BN=64 dbuf kernel (2 blocks/CU).
// R5: attention causal work-balance: block j handles q-tiles j AND 31-j
//     concurrently over one staged key-tile stream (33 tile-updates per
//     block, uniform across CUs), K/V double-buffered (1 barrier/tile),
//     Q/K read directly from qkv (reshape_qk fused away; S scaled 1/8).

typedef unsigned short u16;
typedef unsigned int u32;
typedef __attribute__((ext_vector_type(8))) short v8s;   // 8 x bf16 (4 VGPR)
typedef __attribute__((ext_vector_type(4))) float v4f;   // MFMA acc

#define GAS __attribute__((address_space(1)))
#define LAS __attribute__((address_space(3)))

__device__ __forceinline__ u16 f2bf(float f) {
  u32 u = __float_as_uint(f);
  u = (u + 0x7FFF + ((u >> 16) & 1)) >> 16;  // RNE
  return (u16)u;
}
__device__ __forceinline__ float bf2f(u16 h) {
  return __uint_as_float(((u32)h) << 16);
}
__device__ __forceinline__ float fast_tanh(float x) {
  return 1.f - 2.f / (1.f + __expf(2.f * x));
}

// ---------------- weight transpose + fp32->bf16 convert ----------------
__global__ __launch_bounds__(256)
void wtrans(const float* __restrict__ W, u16* __restrict__ Wt, int K, int N) {
  __shared__ float tile[32][33];
  const int n0 = blockIdx.x << 5, k0 = blockIdx.y << 5;
  const int r = threadIdx.x >> 5, c = threadIdx.x & 31;
#pragma unroll
  for (int i = 0; i < 4; ++i)
    tile[r + 8 * i][c] = W[(size_t)(k0 + r + 8 * i) * N + n0 + c];
  __syncthreads();
#pragma unroll
  for (int i = 0; i < 4; ++i)
    Wt[(size_t)(n0 + r + 8 * i) * K + k0 + c] = f2bf(tile[c][r + 8 * i]);
}

// ---------------- LayerNorm (f32 in -> bf16 out), C=1024 ----------------
__global__ __launch_bounds__(256)
void ln_bf16(const float* __restrict__ x, const float* __restrict__ g,
             const float* __restrict__ be, u16* __restrict__ out) {
  constexpr int C = 1024;
  const int row = blockIdx.x, t = threadIdx.x;
  const float4 v = ((const float4*)(x + (size_t)row * C))[t];
  float s = v.x + v.y + v.z + v.w;
#pragma unroll
  for (int m = 32; m >= 1; m >>= 1) s += __shfl_xor(s, m);
  __shared__ float red[4], red2[4];
  if ((t & 63) == 0) red[t >> 6] = s;
  __syncthreads();
  const float mu = (red[0] + red[1] + red[2] + red[3]) * (1.f / C);
  const float dx = v.x - mu, dy = v.y - mu, dz = v.z - mu, dw = v.w - mu;
  float s2 = dx * dx + dy * dy + dz * dz + dw * dw;
#pragma unroll
  for (int m = 32; m >= 1; m >>= 1) s2 += __shfl_xor(s2, m);
  if ((t & 63) == 0) red2[t >> 6] = s2;
  __syncthreads();
  const float var = (red2[0] + red2[1] + red2[2] + red2[3]) * (1.f / C);
  const float rs = rsqrtf(var + 1e-5f);
  const int c = t << 2;
  u16 o0 = f2bf(dx * rs * g[c + 0] + be[c + 0]);
  u16 o1 = f2bf(dy * rs * g[c + 1] + be[c + 1]);
  u16 o2 = f2bf(dz * rs * g[c + 2] + be[c + 2]);
  u16 o3 = f2bf(dw * rs * g[c + 3] + be[c + 3]);
  uint2 pk;
  pk.x = (u32)o0 | ((u32)o1 << 16);
  pk.y = (u32)o2 | ((u32)o3 << 16);
  *(uint2*)(out + (size_t)row * C + c) = pk;
}

// ------- GEMM 128x128: C = A[M,K] * Bt[N,K]^T + epilogue (qkv, fc1) -----
template <int EPI>
__global__ __launch_bounds__(256)
void gemm_bt(const u16* __restrict__ A, const u16* __restrict__ Bt,
             const float* __restrict__ bias, const float* __restrict__ res,
             void* __restrict__ outp, int M, int N, int K) {
  __shared__ u16 As[128 * 32];
  __shared__ u16 Bs[128 * 32];
  const int tid = threadIdx.x;
  const int wave = tid >> 6, lane = tid & 63;
  const int m0 = blockIdx.y << 7, n0 = blockIdx.x << 7;

  v4f acc[4][4];
  const v4f vz = {0.f, 0.f, 0.f, 0.f};
#pragma unroll
  for (int i = 0; i < 4; ++i)
#pragma unroll
    for (int j = 0; j < 4; ++j) acc[i][j] = vz;

  const int wm = (wave >> 1) << 6, wn = (wave & 1) << 6;
  const int sr = lane >> 2;
  const int sc = (lane & 3) << 3;
  const int fr = lane & 15;
  const int fk = (lane >> 4) << 3;
  const int c0 = wave << 1;

  u16* lA0 = As + (c0 + 0) * 512;
  u16* lA1 = As + (c0 + 1) * 512;
  u16* lB0 = Bs + (c0 + 0) * 512;
  u16* lB1 = Bs + (c0 + 1) * 512;
  const u16* gA0 = A + (size_t)(m0 + c0 * 16 + sr) * K + sc;
  const u16* gA1 = A + (size_t)(m0 + c0 * 16 + 16 + sr) * K + sc;
  const u16* gB0 = Bt + (size_t)(n0 + c0 * 16 + sr) * K + sc;
  const u16* gB1 = Bt + (size_t)(n0 + c0 * 16 + 16 + sr) * K + sc;

  for (int k0 = 0; k0 < K; k0 += 32) {
    __builtin_amdgcn_global_load_lds((GAS const u32*)(gA0 + k0), (LAS u32*)lA0, 16, 0, 0);
    __builtin_amdgcn_global_load_lds((GAS const u32*)(gA1 + k0), (LAS u32*)lA1, 16, 0, 0);
    __builtin_amdgcn_global_load_lds((GAS const u32*)(gB0 + k0), (LAS u32*)lB0, 16, 0, 0);
    __builtin_amdgcn_global_load_lds((GAS const u32*)(gB1 + k0), (LAS u32*)lB1, 16, 0, 0);
    __syncthreads();
    v8s af[4], bfr[4];
#pragma unroll
    for (int mi = 0; mi < 4; ++mi)
      af[mi] = *(const v8s*)&As[(wm + mi * 16 + fr) * 32 + fk];
#pragma unroll
    for (int ni = 0; ni < 4; ++ni)
      bfr[ni] = *(const v8s*)&Bs[(wn + ni * 16 + fr) * 32 + fk];
#pragma unroll
    for (int mi = 0; mi < 4; ++mi)
#pragma unroll
      for (int ni = 0; ni < 4; ++ni)
        acc[mi][ni] = __builtin_amdgcn_mfma_f32_16x16x32_bf16(af[mi], bfr[ni], acc[mi][ni], 0, 0, 0);
    __syncthreads();
  }

  const int er = (lane >> 4) << 2;
#pragma unroll
  for (int mi = 0; mi < 4; ++mi) {
#pragma unroll
    for (int ni = 0; ni < 4; ++ni) {
      const int col = n0 + wn + ni * 16 + fr;
      const float bcol = bias[col];
#pragma unroll
      for (int r = 0; r < 4; ++r) {
        const int row = m0 + wm + mi * 16 + er + r;
        float v = acc[mi][ni][r] + bcol;
        if constexpr (EPI == 1) {
          const float t = fast_tanh(0.7978845608028654f * (v + 0.044715f * v * v * v));
          v = 0.5f * v * (1.f + t);
        }
        if constexpr (EPI == 2) {
          v += res[(size_t)row * N + col];
          ((float*)outp)[(size_t)row * N + col] = v;
        } else {
          ((u16*)outp)[(size_t)row * N + col] = f2bf(v);
        }
      }
    }
  }
}

// ------- GEMM 128x64 double-buffered: for N=1024 outputs (proj, fc2) -----
template <int EPI>
__global__ __launch_bounds__(256)
void gemm_bt_n64(const u16* __restrict__ A, const u16* __restrict__ Bt,
                 const float* __restrict__ bias, const float* __restrict__ res,
                 void* __restrict__ outp, int M, int N, int K) {
  __shared__ u16 As[2][128 * 32];
  __shared__ u16 Bs[2][64 * 32];
  const int tid = threadIdx.x;
  const int wave = tid >> 6, lane = tid & 63;
  const int m0 = blockIdx.y << 7, n0 = blockIdx.x << 6;

  v4f acc[4][2];
  const v4f vz = {0.f, 0.f, 0.f, 0.f};
#pragma unroll
  for (int i = 0; i < 4; ++i)
#pragma unroll
    for (int j = 0; j < 2; ++j) acc[i][j] = vz;

  const int wm = (wave >> 1) << 6, wn = (wave & 1) << 5;
  const int sr = lane >> 2;
  const int sc = (lane & 3) << 3;
  const int fr = lane & 15;
  const int fk = (lane >> 4) << 3;

  const u16* gA0 = A + (size_t)(m0 + wave * 32 + sr) * K + sc;
  const u16* gA1 = A + (size_t)(m0 + wave * 32 + 16 + sr) * K + sc;
  const u16* gB0 = Bt + (size_t)(n0 + wave * 16 + sr) * K + sc;
  const int aoff = wave * 1024;
  const int boff = wave * 512;

  const int nk = K >> 5;
  {
    __builtin_amdgcn_global_load_lds((GAS const u32*)gA0, (LAS u32*)(As[0] + aoff), 16, 0, 0);
    __builtin_amdgcn_global_load_lds((GAS const u32*)gA1, (LAS u32*)(As[0] + aoff + 512), 16, 0, 0);
    __builtin_amdgcn_global_load_lds((GAS const u32*)gB0, (LAS u32*)(Bs[0] + boff), 16, 0, 0);
  }
  for (int kt = 0; kt < nk; ++kt) {
    __syncthreads();
    if (kt + 1 < nk) {
      const int k0 = (kt + 1) << 5;
      const int nb = (kt + 1) & 1;
      __builtin_amdgcn_global_load_lds((GAS const u32*)(gA0 + k0), (LAS u32*)(As[nb] + aoff), 16, 0, 0);
      __builtin_amdgcn_global_load_lds((GAS const u32*)(gA1 + k0), (LAS u32*)(As[nb] + aoff + 512), 16, 0, 0);
      __builtin_amdgcn_global_load_lds((GAS const u32*)(gB0 + k0), (LAS u32*)(Bs[nb] + boff), 16, 0, 0);
    }
    const u16* Ab = As[kt & 1];
    const u16* Bb = Bs[kt & 1];
    v8s af[4], bfr[2];
#pragma unroll
    for (int mi = 0; mi < 4; ++mi)
      af[mi] = *(const v8s*)&Ab[(wm + mi * 16 + fr) * 32 + fk];
#pragma unroll
    for (int ni = 0; ni < 2; ++ni)
      bfr[ni] = *(const v8s*)&Bb[(wn + ni * 16 + fr) * 32 + fk];
#pragma unroll
    for (int mi = 0; mi < 4; ++mi)
#pragma unroll
      for (int ni = 0; ni < 2; ++ni)
        acc[mi][ni] = __builtin_amdgcn_mfma_f32_16x16x32_bf16(af[mi], bfr[ni], acc[mi][ni], 0, 0, 0);
  }

  const int er = (lane >> 4) << 2;
#pragma unroll
  for (int mi = 0; mi < 4; ++mi) {
#pragma unroll
    for (int ni = 0; ni < 2; ++ni) {
      const int col = n0 + wn + ni * 16 + fr;
      const float bcol = bias[col];
#pragma unroll
      for (int r = 0; r < 4; ++r) {
        const int row = m0 + wm + mi * 16 + er + r;
        float v = acc[mi][ni][r] + bcol;
        if constexpr (EPI == 1) {
          const float t = fast_tanh(0.7978845608028654f * (v + 0.044715f * v * v * v));
          v = 0.5f * v * (1.f + t);
        }
        if constexpr (EPI == 2) {
          v += res[(size_t)row * N + col];
          ((float*)outp)[(size_t)row * N + col] = v;
        } else {
          ((u16*)outp)[(size_t)row * N + col] = f2bf(v);
        }
      }
    }
  }
}

// ---------------- V -> Vt [B,H,D,T] bf16 (transpose via LDS) -------------
__global__ __launch_bounds__(256)
void transpose_v(const u16* __restrict__ qkv, u16* __restrict__ Vt) {
  __shared__ u16 tile[64][65];
  const int t0 = blockIdx.x << 6;
  const int bh = blockIdx.y;
  const int b = bh >> 4, h = bh & 15;
  const int r4 = threadIdx.x >> 6, c = threadIdx.x & 63;
#pragma unroll
  for (int i = 0; i < 16; ++i) {
    const int r = r4 * 16 + i;
    tile[r][c] = qkv[(size_t)(b * 2048 + t0 + r) * 3072 + 2048 + h * 64 + c];
  }
  __syncthreads();
#pragma unroll
  for (int i = 0; i < 16; ++i) {
    const int d = r4 * 16 + i;
    Vt[(size_t)bh * 64 * 2048 + (size_t)d * 2048 + t0 + c] = tile[c][d];
  }
}

// ---------------- flash attention (causal, balanced pairing) -------------
// grid(16, B*H). Block j handles q-tiles ta=j and tb=31-j (64 rows each)
// concurrently over one key-tile stream 0..tb (A's range ⊆ B's range).
// Every block: exactly 33 tile-updates. K/V 64x64 tiles double-buffered.
// Wave w owns q rows [64*t + 16w, +16) of each q-tile.
// S^T = mfma(Kfrag, Qfrag) (keys on reg dim); O^T = mfma(Vfrag, Pfrag).
constexpr int PSTR = 88;  // P row stride (u16): 176B = 16B-mult, 2-way banks

template <bool MASKED>
__device__ __forceinline__ void attn_sub(
    const v8s (&kf)[4][2], const v8s (&vfr)[4][2], const v8s (&qf)[2],
    v4f (&ot)[4], float& m_i, float& l_i, u16* __restrict__ pw,
    const int kb, const int qrow, const int fr, const int fg) {
  const v4f vz = {0.f, 0.f, 0.f, 0.f};
  v4f st[4];
#pragma unroll
  for (int ks = 0; ks < 4; ++ks) {
    st[ks] = vz;
    st[ks] = __builtin_amdgcn_mfma_f32_16x16x32_bf16(kf[ks][0], qf[0], st[ks], 0, 0, 0);
    st[ks] = __builtin_amdgcn_mfma_f32_16x16x32_bf16(kf[ks][1], qf[1], st[ks], 0, 0, 0);
  }
  const int q = qrow + fr;
  float e[4][4];
  float mt = -1e30f;
#pragma unroll
  for (int ks = 0; ks < 4; ++ks)
#pragma unroll
    for (int r = 0; r < 4; ++r) {
      float v = st[ks][r] * 0.125f;  // fold 1/sqrt(64)
      if (MASKED) v = (kb + ks * 16 + fg * 4 + r <= q) ? v : -1e30f;
      e[ks][r] = v;
      mt = fmaxf(mt, v);
    }
  mt = fmaxf(mt, __shfl_xor(mt, 16));
  mt = fmaxf(mt, __shfl_xor(mt, 32));
  const float m_new = fmaxf(m_i, mt);
  const float alpha = __expf(m_i - m_new);
  m_i = m_new;
  float ls = 0.f;
#pragma unroll
  for (int ks = 0; ks < 4; ++ks)
#pragma unroll
    for (int r = 0; r < 4; ++r) {
      e[ks][r] = __expf(e[ks][r] - m_new);
      ls += e[ks][r];
    }
  ls += __shfl_xor(ls, 16);
  ls += __shfl_xor(ls, 32);
  l_i = l_i * alpha + ls;
#pragma unroll
  for (int ds = 0; ds < 4; ++ds) ot[ds] *= alpha;
#pragma unroll
  for (int ks = 0; ks < 4; ++ks) {
    ushort4 pk4;
    pk4.x = f2bf(e[ks][0]);
    pk4.y = f2bf(e[ks][1]);
    pk4.z = f2bf(e[ks][2]);
    pk4.w = f2bf(e[ks][3]);
    *(ushort4*)&pw[fr * PSTR + ks * 16 + fg * 4] = pk4;
  }
  const v8s pf0 = *(const v8s*)&pw[fr * PSTR + fg * 8];
  const v8s pf1 = *(const v8s*)&pw[fr * PSTR + 32 + fg * 8];
#pragma unroll
  for (int ds = 0; ds < 4; ++ds) {
    ot[ds] = __builtin_amdgcn_mfma_f32_16x16x32_bf16(vfr[ds][0], pf0, ot[ds], 0, 0, 0);
    ot[ds] = __builtin_amdgcn_mfma_f32_16x16x32_bf16(vfr[ds][1], pf1, ot[ds], 0, 0, 0);
  }
}

__global__ __launch_bounds__(256)
void attn_kernel(const u16* __restrict__ qkv, const u16* __restrict__ Vt,
                 u16* __restrict__ y) {
  constexpr int T = 2048, D = 64, C = 1024, QS = 3072;
  __shared__ alignas(16) u16 Ktile[2][64 * 64];
  __shared__ alignas(16) u16 Vtile[2][64 * 64];
  __shared__ alignas(16) u16 Pw[4][16 * PSTR];

  const int tid = threadIdx.x, wave = tid >> 6, lane = tid & 63;
  const int fr = lane & 15, fg = lane >> 4;
  const int bh = blockIdx.y, b = bh >> 4, h = bh & 15;
  const int ta = blockIdx.x, tb = 31 - ta;
  const u16* qkvb = qkv + (size_t)b * T * QS + h * 64;  // Q base
  const u16* Kg = qkvb + 1024;                          // K base
  const u16* Vh = Vt + (size_t)bh * D * T;
  u16* pw = &Pw[wave][0];

  const int rowA = ta * 64 + wave * 16;
  const int rowB = tb * 64 + wave * 16;

  v8s qfA[2], qfB[2];
#pragma unroll
  for (int dh = 0; dh < 2; ++dh) {
    qfA[dh] = *(const v8s*)&qkvb[(size_t)(rowA + fr) * QS + dh * 32 + fg * 8];
    qfB[dh] = *(const v8s*)&qkvb[(size_t)(rowB + fr) * QS + dh * 32 + fg * 8];
  }

  const v4f vz = {0.f, 0.f, 0.f, 0.f};
  v4f otA[4], otB[4];
#pragma unroll
  for (int ds = 0; ds < 4; ++ds) { otA[ds] = vz; otB[ds] = vz; }
  float mA = -1e30f, lA = 0.f, mB = -1e30f, lB = 0.f;

  const int srow = lane >> 3;            // staging row within 8-row chunk
  const int sg0 = lane & 7;              // staging col-group before swizzle

  const int nt = tb + 1;
  // prologue: stage tile 0 into buf 0
  {
#pragma unroll
    for (int cc = 0; cc < 2; ++cc) {
      const int r0 = wave * 16 + cc * 8;
      const int rr = r0 + srow;
      const int gg = sg0 ^ (rr & 7);
      __builtin_amdgcn_global_load_lds(
          (GAS const u32*)(Kg + (size_t)rr * QS + gg * 8),
          (LAS u32*)(Ktile[0] + r0 * 64), 16, 0, 0);
      __builtin_amdgcn_global_load_lds(
          (GAS const u32*)(Vh + (size_t)rr * T + gg * 8),
          (LAS u32*)(Vtile[0] + r0 * 64), 16, 0, 0);
    }
  }
  for (int kt = 0; kt < nt; ++kt) {
    __syncthreads();  // drains staging of kt; prior buf reads complete
    if (kt + 1 < nt) {
      const int kb1 = (kt + 1) << 6;
      const int nb = (kt + 1) & 1;
#pragma unroll
      for (int cc = 0; cc < 2; ++cc) {
        const int r0 = wave * 16 + cc * 8;
        const int rr = r0 + srow;
        const int gg = sg0 ^ (rr & 7);
        __builtin_amdgcn_global_load_lds(
            (GAS const u32*)(Kg + (size_t)(kb1 + rr) * QS + gg * 8),
            (LAS u32*)(Ktile[nb] + r0 * 64), 16, 0, 0);
        __builtin_amdgcn_global_load_lds(
            (GAS const u32*)(Vh + (size_t)rr * T + kb1 + gg * 8),
            (LAS u32*)(Vtile[nb] + r0 * 64), 16, 0, 0);
      }
    }
    const u16* Kt = Ktile[kt & 1];
    const u16* Vi = Vtile[kt & 1];
    const int kb = kt << 6;
    const int swz = fr & 7;
    v8s kf[4][2], vfr[4][2];
#pragma unroll
    for (int ks = 0; ks < 4; ++ks) {
      const int rr = ks * 16 + fr;
      kf[ks][0] = *(const v8s*)&Kt[rr * 64 + ((0 + fg) ^ swz) * 8];
      kf[ks][1] = *(const v8s*)&Kt[rr * 64 + ((4 + fg) ^ swz) * 8];
      vfr[ks][0] = *(const v8s*)&Vi[rr * 64 + ((0 + fg) ^ swz) * 8];
      vfr[ks][1] = *(const v8s*)&Vi[rr * 64 + ((4 + fg) ^ swz) * 8];
    }
    if (kt < ta) {
      attn_sub<false>(kf, vfr, qfA, otA, mA, lA, pw, kb, rowA, fr, fg);
      attn_sub<false>(kf, vfr, qfB, otB, mB, lB, pw, kb, rowB, fr, fg);
    } else if (kt == ta) {
      attn_sub<true>(kf, vfr, qfA, otA, mA, lA, pw, kb, rowA, fr, fg);
      attn_sub<false>(kf, vfr, qfB, otB, mB, lB, pw, kb, rowB, fr, fg);
    } else if (kt < tb) {
      attn_sub<false>(kf, vfr, qfB, otB, mB, lB, pw, kb, rowB, fr, fg);
    } else {
      attn_sub<true>(kf, vfr, qfB, otB, mB, lB, pw, kb, rowB, fr, fg);
    }
  }

  const float invA = 1.f / lA, invB = 1.f / lB;
#pragma unroll
  for (int ds = 0; ds < 4; ++ds) {
    ushort4 a4, b4;
    a4.x = f2bf(otA[ds][0] * invA);
    a4.y = f2bf(otA[ds][1] * invA);
    a4.z = f2bf(otA[ds][2] * invA);
    a4.w = f2bf(otA[ds][3] * invA);
    b4.x = f2bf(otB[ds][0] * invB);
    b4.y = f2bf(otB[ds][1] * invB);
    b4.z = f2bf(otB[ds][2] * invB);
    b4.w = f2bf(otB[ds][3] * invB);
    *(ushort4*)&y[(size_t)(b * T + rowA + fr) * C + h * D + ds * 16 + fg * 4] = a4;
    *(ushort4*)&y[(size_t)(b * T + rowB + fr) * C + h * D + ds * 16 + fg * 4] = b4;
  }
}

// ------------------------------- launch ----------------------------------
extern "C" void kernel_launch(void* const* d_in, const int* in_sizes, int n_in,
                              void* d_out, int out_size, void* d_ws, size_t ws_size,
                              hipStream_t stream) {
  const float* x      = (const float*)d_in[0];
  const float* ln1_g  = (const float*)d_in[1];
  const float* ln1_b  = (const float*)d_in[2];
  const float* W_attn = (const float*)d_in[3];
  const float* b_attn = (const float*)d_in[4];
  const float* W_o    = (const float*)d_in[5];
  const float* b_o    = (const float*)d_in[6];
  const float* ln2_g  = (const float*)d_in[7];
  const float* ln2_b  = (const float*)d_in[8];
  const float* W_fc   = (const float*)d_in[9];
  const float* b_fc   = (const float*)d_in[10];
  const float* W_fc2  = (const float*)d_in[11];
  const float* b_fc2  = (const float*)d_in[12];
  float* out = (float*)d_out;
  char* ws = (char*)d_ws;

  const size_t MB = 1u << 20;
  u16* Wattn_t = (u16*)(ws + 0 * MB);   // 6MB
  u16* Wo_t    = (u16*)(ws + 6 * MB);   // 2MB
  u16* Wfc_t   = (u16*)(ws + 8 * MB);   // 8MB
  u16* Wfc2_t  = (u16*)(ws + 16 * MB);  // 8MB
  float* x1    = (float*)(ws + 24 * MB); // 16MB
  u16* h1      = (u16*)(ws + 40 * MB);  // 8MB
  u16* qkv     = (u16*)(ws + 48 * MB);  // 24MB (alive through attn)
  u16* Vt      = (u16*)(ws + 88 * MB);  // 8MB
  u16* yb      = (u16*)(ws + 40 * MB);  // reuse h1 (dead after qkv GEMM)
  u16* h2      = (u16*)(ws + 48 * MB);  // reuse qkv (dead after attn)
  u16* ab      = (u16*)(ws + 56 * MB);  // 32MB (56..88)

  wtrans<<<dim3(3072 / 32, 1024 / 32), 256, 0, stream>>>(W_attn, Wattn_t, 1024, 3072);
  wtrans<<<dim3(1024 / 32, 1024 / 32), 256, 0, stream>>>(W_o, Wo_t, 1024, 1024);
  wtrans<<<dim3(4096 / 32, 1024 / 32), 256, 0, stream>>>(W_fc, Wfc_t, 1024, 4096);
  wtrans<<<dim3(1024 / 32, 4096 / 32), 256, 0, stream>>>(W_fc2, Wfc2_t, 4096, 1024);

  ln_bf16<<<4096, 256, 0, stream>>>(x, ln1_g, ln1_b, h1);
  gemm_bt<0><<<dim3(3072 / 128, 4096 / 128), 256, 0, stream>>>(
      h1, Wattn_t, b_attn, nullptr, qkv, 4096, 3072, 1024);
  transpose_v<<<dim3(2048 / 64, 32), 256, 0, stream>>>(qkv, Vt);
  attn_kernel<<<dim3(16, 32), 256, 0, stream>>>(qkv, Vt, yb);
  gemm_bt_n64<2><<<dim3(1024 / 64, 4096 / 128), 256, 0, stream>>>(
      yb, Wo_t, b_o, x, x1, 4096, 1024, 1024);
  ln_bf16<<<4096, 256, 0, stream>>>(x1, ln2_g, ln2_b, h2);
  gemm_bt<1><<<dim3(4096 / 128, 4096 / 128), 256, 0, stream>>>(
      h2, Wfc_t, b_fc, nullptr, ab, 4096, 4096, 1024);
  gemm_bt_n64<2><<<dim3(1024 / 64, 4096 / 128), 256, 0, stream>>>(
      ab, Wfc2_t, b_fc2, x1, out, 4096, 1024, 4096);
}

// Round 6
// 385.868 us; speedup vs baseline: 2.2140x; 1.0108x over previous
//
#include <hip/hip_runtime.h>

// Transformer block on MI355X (gfx950).
// B=2, T=2048, C=1024, H=16, D=64. All GEMMs in bf16 MFMA (16x16x32).
// R1: acc array in scratch (tanhf blocked unroll) -> unroll + inline tanh.
// R2: attention latency-bound -> LDS-staged K/V, S^T/O^T register layouts.
// R3/R4: N=1024 GEMMs occupancy-bound -> BN=64 dbuf kernel (2 blocks/CU).
// R5: attention causal pairing (block j does q-tiles j and 31-j).
// R6: n64 GEMM was still latency-bound (78us for fc2: 1460 cyc/iter vs ~200
//     compute; __syncthreads drains vmcnt(0) so prefetch lead = 1 phase).
//     -> depth-3 prefetch over 4 LDS buffers with raw s_barrier + manual
//     s_waitcnt vmcnt(6/3/0) (AITER pattern: in-flight loads cross barriers).

typedef unsigned short u16;
typedef unsigned int u32;
typedef __attribute__((ext_vector_type(8))) short v8s;   // 8 x bf16 (4 VGPR)
typedef __attribute__((ext_vector_type(4))) float v4f;   // MFMA acc

#define GAS __attribute__((address_space(1)))
#define LAS __attribute__((address_space(3)))

__device__ __forceinline__ u16 f2bf(float f) {
  u32 u = __float_as_uint(f);
  u = (u + 0x7FFF + ((u >> 16) & 1)) >> 16;  // RNE
  return (u16)u;
}
__device__ __forceinline__ float bf2f(u16 h) {
  return __uint_as_float(((u32)h) << 16);
}
__device__ __forceinline__ float fast_tanh(float x) {
  return 1.f - 2.f / (1.f + __expf(2.f * x));
}

// ---------------- weight transpose + fp32->bf16 convert ----------------
__global__ __launch_bounds__(256)
void wtrans(const float* __restrict__ W, u16* __restrict__ Wt, int K, int N) {
  __shared__ float tile[32][33];
  const int n0 = blockIdx.x << 5, k0 = blockIdx.y << 5;
  const int r = threadIdx.x >> 5, c = threadIdx.x & 31;
#pragma unroll
  for (int i = 0; i < 4; ++i)
    tile[r + 8 * i][c] = W[(size_t)(k0 + r + 8 * i) * N + n0 + c];
  __syncthreads();
#pragma unroll
  for (int i = 0; i < 4; ++i)
    Wt[(size_t)(n0 + r + 8 * i) * K + k0 + c] = f2bf(tile[c][r + 8 * i]);
}

// ---------------- LayerNorm (f32 in -> bf16 out), C=1024 ----------------
__global__ __launch_bounds__(256)
void ln_bf16(const float* __restrict__ x, const float* __restrict__ g,
             const float* __restrict__ be, u16* __restrict__ out) {
  constexpr int C = 1024;
  const int row = blockIdx.x, t = threadIdx.x;
  const float4 v = ((const float4*)(x + (size_t)row * C))[t];
  float s = v.x + v.y + v.z + v.w;
#pragma unroll
  for (int m = 32; m >= 1; m >>= 1) s += __shfl_xor(s, m);
  __shared__ float red[4], red2[4];
  if ((t & 63) == 0) red[t >> 6] = s;
  __syncthreads();
  const float mu = (red[0] + red[1] + red[2] + red[3]) * (1.f / C);
  const float dx = v.x - mu, dy = v.y - mu, dz = v.z - mu, dw = v.w - mu;
  float s2 = dx * dx + dy * dy + dz * dz + dw * dw;
#pragma unroll
  for (int m = 32; m >= 1; m >>= 1) s2 += __shfl_xor(s2, m);
  if ((t & 63) == 0) red2[t >> 6] = s2;
  __syncthreads();
  const float var = (red2[0] + red2[1] + red2[2] + red2[3]) * (1.f / C);
  const float rs = rsqrtf(var + 1e-5f);
  const int c = t << 2;
  u16 o0 = f2bf(dx * rs * g[c + 0] + be[c + 0]);
  u16 o1 = f2bf(dy * rs * g[c + 1] + be[c + 1]);
  u16 o2 = f2bf(dz * rs * g[c + 2] + be[c + 2]);
  u16 o3 = f2bf(dw * rs * g[c + 3] + be[c + 3]);
  uint2 pk;
  pk.x = (u32)o0 | ((u32)o1 << 16);
  pk.y = (u32)o2 | ((u32)o3 << 16);
  *(uint2*)(out + (size_t)row * C + c) = pk;
}

// ------- GEMM 128x128: C = A[M,K] * Bt[N,K]^T + epilogue (qkv, fc1) -----
template <int EPI>
__global__ __launch_bounds__(256)
void gemm_bt(const u16* __restrict__ A, const u16* __restrict__ Bt,
             const float* __restrict__ bias, const float* __restrict__ res,
             void* __restrict__ outp, int M, int N, int K) {
  __shared__ u16 As[128 * 32];
  __shared__ u16 Bs[128 * 32];
  const int tid = threadIdx.x;
  const int wave = tid >> 6, lane = tid & 63;
  const int m0 = blockIdx.y << 7, n0 = blockIdx.x << 7;

  v4f acc[4][4];
  const v4f vz = {0.f, 0.f, 0.f, 0.f};
#pragma unroll
  for (int i = 0; i < 4; ++i)
#pragma unroll
    for (int j = 0; j < 4; ++j) acc[i][j] = vz;

  const int wm = (wave >> 1) << 6, wn = (wave & 1) << 6;
  const int sr = lane >> 2;
  const int sc = (lane & 3) << 3;
  const int fr = lane & 15;
  const int fk = (lane >> 4) << 3;
  const int c0 = wave << 1;

  u16* lA0 = As + (c0 + 0) * 512;
  u16* lA1 = As + (c0 + 1) * 512;
  u16* lB0 = Bs + (c0 + 0) * 512;
  u16* lB1 = Bs + (c0 + 1) * 512;
  const u16* gA0 = A + (size_t)(m0 + c0 * 16 + sr) * K + sc;
  const u16* gA1 = A + (size_t)(m0 + c0 * 16 + 16 + sr) * K + sc;
  const u16* gB0 = Bt + (size_t)(n0 + c0 * 16 + sr) * K + sc;
  const u16* gB1 = Bt + (size_t)(n0 + c0 * 16 + 16 + sr) * K + sc;

  for (int k0 = 0; k0 < K; k0 += 32) {
    __builtin_amdgcn_global_load_lds((GAS const u32*)(gA0 + k0), (LAS u32*)lA0, 16, 0, 0);
    __builtin_amdgcn_global_load_lds((GAS const u32*)(gA1 + k0), (LAS u32*)lA1, 16, 0, 0);
    __builtin_amdgcn_global_load_lds((GAS const u32*)(gB0 + k0), (LAS u32*)lB0, 16, 0, 0);
    __builtin_amdgcn_global_load_lds((GAS const u32*)(gB1 + k0), (LAS u32*)lB1, 16, 0, 0);
    __syncthreads();
    v8s af[4], bfr[4];
#pragma unroll
    for (int mi = 0; mi < 4; ++mi)
      af[mi] = *(const v8s*)&As[(wm + mi * 16 + fr) * 32 + fk];
#pragma unroll
    for (int ni = 0; ni < 4; ++ni)
      bfr[ni] = *(const v8s*)&Bs[(wn + ni * 16 + fr) * 32 + fk];
#pragma unroll
    for (int mi = 0; mi < 4; ++mi)
#pragma unroll
      for (int ni = 0; ni < 4; ++ni)
        acc[mi][ni] = __builtin_amdgcn_mfma_f32_16x16x32_bf16(af[mi], bfr[ni], acc[mi][ni], 0, 0, 0);
    __syncthreads();
  }

  const int er = (lane >> 4) << 2;
#pragma unroll
  for (int mi = 0; mi < 4; ++mi) {
#pragma unroll
    for (int ni = 0; ni < 4; ++ni) {
      const int col = n0 + wn + ni * 16 + fr;
      const float bcol = bias[col];
#pragma unroll
      for (int r = 0; r < 4; ++r) {
        const int row = m0 + wm + mi * 16 + er + r;
        float v = acc[mi][ni][r] + bcol;
        if constexpr (EPI == 1) {
          const float t = fast_tanh(0.7978845608028654f * (v + 0.044715f * v * v * v));
          v = 0.5f * v * (1.f + t);
        }
        if constexpr (EPI == 2) {
          v += res[(size_t)row * N + col];
          ((float*)outp)[(size_t)row * N + col] = v;
        } else {
          ((u16*)outp)[(size_t)row * N + col] = f2bf(v);
        }
      }
    }
  }
}

// ------- GEMM 128x64, depth-3 prefetch pipeline (proj, fc2: N=1024) ------
// 4 LDS buffers (48 KB). Per iter: s_waitcnt vmcnt(6) waits only the 3
// oldest loads (current tile); tiles kt+1, kt+2 stay in flight across the
// raw s_barrier. Each wave waits its own loads pre-barrier => tile complete
// post-barrier; ds_read results all consumed by MFMAs before next barrier.
template <int EPI>
__global__ __launch_bounds__(256)
void gemm_bt_n64(const u16* __restrict__ A, const u16* __restrict__ Bt,
                 const float* __restrict__ bias, const float* __restrict__ res,
                 void* __restrict__ outp, int M, int N, int K) {
  __shared__ u16 As[4][128 * 32];
  __shared__ u16 Bs[4][64 * 32];
  const int tid = threadIdx.x;
  const int wave = tid >> 6, lane = tid & 63;
  const int m0 = blockIdx.y << 7, n0 = blockIdx.x << 6;

  v4f acc[4][2];
  const v4f vz = {0.f, 0.f, 0.f, 0.f};
#pragma unroll
  for (int i = 0; i < 4; ++i)
#pragma unroll
    for (int j = 0; j < 2; ++j) acc[i][j] = vz;

  const int wm = (wave >> 1) << 6, wn = (wave & 1) << 5;
  const int sr = lane >> 2;
  const int sc = (lane & 3) << 3;
  const int fr = lane & 15;
  const int fk = (lane >> 4) << 3;

  const u16* gA0 = A + (size_t)(m0 + wave * 32 + sr) * K + sc;
  const u16* gA1 = A + (size_t)(m0 + wave * 32 + 16 + sr) * K + sc;
  const u16* gB0 = Bt + (size_t)(n0 + wave * 16 + sr) * K + sc;
  const int aoff = wave * 1024;
  const int boff = wave * 512;

  const int nk = K >> 5;  // >= 32 for all our shapes

#define N64_ISSUE(t, bf)                                                      \
  do {                                                                        \
    const int k0_ = (t) << 5;                                                 \
    __builtin_amdgcn_global_load_lds((GAS const u32*)(gA0 + k0_),             \
                                     (LAS u32*)(As[bf] + aoff), 16, 0, 0);    \
    __builtin_amdgcn_global_load_lds((GAS const u32*)(gA1 + k0_),             \
                                     (LAS u32*)(As[bf] + aoff + 512), 16, 0, 0); \
    __builtin_amdgcn_global_load_lds((GAS const u32*)(gB0 + k0_),             \
                                     (LAS u32*)(Bs[bf] + boff), 16, 0, 0);    \
  } while (0)

  N64_ISSUE(0, 0);
  N64_ISSUE(1, 1);
  N64_ISSUE(2, 2);

  auto compute = [&](int kt) __attribute__((always_inline)) {
    const u16* Ab = As[kt & 3];
    const u16* Bb = Bs[kt & 3];
    v8s af[4], bfr[2];
#pragma unroll
    for (int mi = 0; mi < 4; ++mi)
      af[mi] = *(const v8s*)&Ab[(wm + mi * 16 + fr) * 32 + fk];
#pragma unroll
    for (int ni = 0; ni < 2; ++ni)
      bfr[ni] = *(const v8s*)&Bb[(wn + ni * 16 + fr) * 32 + fk];
#pragma unroll
    for (int mi = 0; mi < 4; ++mi)
#pragma unroll
      for (int ni = 0; ni < 2; ++ni)
        acc[mi][ni] = __builtin_amdgcn_mfma_f32_16x16x32_bf16(af[mi], bfr[ni], acc[mi][ni], 0, 0, 0);
  };

  for (int kt = 0; kt < nk - 2; ++kt) {
    asm volatile("s_waitcnt vmcnt(6)" ::: "memory");
    __builtin_amdgcn_s_barrier();
    if (kt + 3 < nk) N64_ISSUE(kt + 3, (kt + 3) & 3);
    compute(kt);
  }
  asm volatile("s_waitcnt vmcnt(3)" ::: "memory");
  __builtin_amdgcn_s_barrier();
  compute(nk - 2);
  asm volatile("s_waitcnt vmcnt(0)" ::: "memory");
  __builtin_amdgcn_s_barrier();
  compute(nk - 1);
#undef N64_ISSUE

  const int er = (lane >> 4) << 2;
#pragma unroll
  for (int mi = 0; mi < 4; ++mi) {
#pragma unroll
    for (int ni = 0; ni < 2; ++ni) {
      const int col = n0 + wn + ni * 16 + fr;
      const float bcol = bias[col];
#pragma unroll
      for (int r = 0; r < 4; ++r) {
        const int row = m0 + wm + mi * 16 + er + r;
        float v = acc[mi][ni][r] + bcol;
        if constexpr (EPI == 1) {
          const float t = fast_tanh(0.7978845608028654f * (v + 0.044715f * v * v * v));
          v = 0.5f * v * (1.f + t);
        }
        if constexpr (EPI == 2) {
          v += res[(size_t)row * N + col];
          ((float*)outp)[(size_t)row * N + col] = v;
        } else {
          ((u16*)outp)[(size_t)row * N + col] = f2bf(v);
        }
      }
    }
  }
}

// ---------------- V -> Vt [B,H,D,T] bf16 (transpose via LDS) -------------
__global__ __launch_bounds__(256)
void transpose_v(const u16* __restrict__ qkv, u16* __restrict__ Vt) {
  __shared__ u16 tile[64][65];
  const int t0 = blockIdx.x << 6;
  const int bh = blockIdx.y;
  const int b = bh >> 4, h = bh & 15;
  const int r4 = threadIdx.x >> 6, c = threadIdx.x & 63;
#pragma unroll
  for (int i = 0; i < 16; ++i) {
    const int r = r4 * 16 + i;
    tile[r][c] = qkv[(size_t)(b * 2048 + t0 + r) * 3072 + 2048 + h * 64 + c];
  }
  __syncthreads();
#pragma unroll
  for (int i = 0; i < 16; ++i) {
    const int d = r4 * 16 + i;
    Vt[(size_t)bh * 64 * 2048 + (size_t)d * 2048 + t0 + c] = tile[c][d];
  }
}

// ---------------- flash attention (causal, balanced pairing) -------------
constexpr int PSTR = 88;  // P row stride (u16): 176B = 16B-mult, 2-way banks

template <bool MASKED>
__device__ __forceinline__ void attn_sub(
    const v8s (&kf)[4][2], const v8s (&vfr)[4][2], const v8s (&qf)[2],
    v4f (&ot)[4], float& m_i, float& l_i, u16* __restrict__ pw,
    const int kb, const int qrow, const int fr, const int fg) {
  const v4f vz = {0.f, 0.f, 0.f, 0.f};
  v4f st[4];
#pragma unroll
  for (int ks = 0; ks < 4; ++ks) {
    st[ks] = vz;
    st[ks] = __builtin_amdgcn_mfma_f32_16x16x32_bf16(kf[ks][0], qf[0], st[ks], 0, 0, 0);
    st[ks] = __builtin_amdgcn_mfma_f32_16x16x32_bf16(kf[ks][1], qf[1], st[ks], 0, 0, 0);
  }
  const int q = qrow + fr;
  float e[4][4];
  float mt = -1e30f;
#pragma unroll
  for (int ks = 0; ks < 4; ++ks)
#pragma unroll
    for (int r = 0; r < 4; ++r) {
      float v = st[ks][r] * 0.125f;  // fold 1/sqrt(64)
      if (MASKED) v = (kb + ks * 16 + fg * 4 + r <= q) ? v : -1e30f;
      e[ks][r] = v;
      mt = fmaxf(mt, v);
    }
  mt = fmaxf(mt, __shfl_xor(mt, 16));
  mt = fmaxf(mt, __shfl_xor(mt, 32));
  const float m_new = fmaxf(m_i, mt);
  const float alpha = __expf(m_i - m_new);
  m_i = m_new;
  float ls = 0.f;
#pragma unroll
  for (int ks = 0; ks < 4; ++ks)
#pragma unroll
    for (int r = 0; r < 4; ++r) {
      e[ks][r] = __expf(e[ks][r] - m_new);
      ls += e[ks][r];
    }
  ls += __shfl_xor(ls, 16);
  ls += __shfl_xor(ls, 32);
  l_i = l_i * alpha + ls;
#pragma unroll
  for (int ds = 0; ds < 4; ++ds) ot[ds] *= alpha;
#pragma unroll
  for (int ks = 0; ks < 4; ++ks) {
    ushort4 pk4;
    pk4.x = f2bf(e[ks][0]);
    pk4.y = f2bf(e[ks][1]);
    pk4.z = f2bf(e[ks][2]);
    pk4.w = f2bf(e[ks][3]);
    *(ushort4*)&pw[fr * PSTR + ks * 16 + fg * 4] = pk4;
  }
  const v8s pf0 = *(const v8s*)&pw[fr * PSTR + fg * 8];
  const v8s pf1 = *(const v8s*)&pw[fr * PSTR + 32 + fg * 8];
#pragma unroll
  for (int ds = 0; ds < 4; ++ds) {
    ot[ds] = __builtin_amdgcn_mfma_f32_16x16x32_bf16(vfr[ds][0], pf0, ot[ds], 0, 0, 0);
    ot[ds] = __builtin_amdgcn_mfma_f32_16x16x32_bf16(vfr[ds][1], pf1, ot[ds], 0, 0, 0);
  }
}

__global__ __launch_bounds__(256)
void attn_kernel(const u16* __restrict__ qkv, const u16* __restrict__ Vt,
                 u16* __restrict__ y) {
  constexpr int T = 2048, D = 64, C = 1024, QS = 3072;
  __shared__ alignas(16) u16 Ktile[2][64 * 64];
  __shared__ alignas(16) u16 Vtile[2][64 * 64];
  __shared__ alignas(16) u16 Pw[4][16 * PSTR];

  const int tid = threadIdx.x, wave = tid >> 6, lane = tid & 63;
  const int fr = lane & 15, fg = lane >> 4;
  const int bh = blockIdx.y, b = bh >> 4, h = bh & 15;
  const int ta = blockIdx.x, tb = 31 - ta;
  const u16* qkvb = qkv + (size_t)b * T * QS + h * 64;  // Q base
  const u16* Kg = qkvb + 1024;                          // K base
  const u16* Vh = Vt + (size_t)bh * D * T;
  u16* pw = &Pw[wave][0];

  const int rowA = ta * 64 + wave * 16;
  const int rowB = tb * 64 + wave * 16;

  v8s qfA[2], qfB[2];
#pragma unroll
  for (int dh = 0; dh < 2; ++dh) {
    qfA[dh] = *(const v8s*)&qkvb[(size_t)(rowA + fr) * QS + dh * 32 + fg * 8];
    qfB[dh] = *(const v8s*)&qkvb[(size_t)(rowB + fr) * QS + dh * 32 + fg * 8];
  }

  const v4f vz = {0.f, 0.f, 0.f, 0.f};
  v4f otA[4], otB[4];
#pragma unroll
  for (int ds = 0; ds < 4; ++ds) { otA[ds] = vz; otB[ds] = vz; }
  float mA = -1e30f, lA = 0.f, mB = -1e30f, lB = 0.f;

  const int srow = lane >> 3;
  const int sg0 = lane & 7;

  const int nt = tb + 1;
  {
#pragma unroll
    for (int cc = 0; cc < 2; ++cc) {
      const int r0 = wave * 16 + cc * 8;
      const int rr = r0 + srow;
      const int gg = sg0 ^ (rr & 7);
      __builtin_amdgcn_global_load_lds(
          (GAS const u32*)(Kg + (size_t)rr * QS + gg * 8),
          (LAS u32*)(Ktile[0] + r0 * 64), 16, 0, 0);
      __builtin_amdgcn_global_load_lds(
          (GAS const u32*)(Vh + (size_t)rr * T + gg * 8),
          (LAS u32*)(Vtile[0] + r0 * 64), 16, 0, 0);
    }
  }
  for (int kt = 0; kt < nt; ++kt) {
    __syncthreads();
    if (kt + 1 < nt) {
      const int kb1 = (kt + 1) << 6;
      const int nb = (kt + 1) & 1;
#pragma unroll
      for (int cc = 0; cc < 2; ++cc) {
        const int r0 = wave * 16 + cc * 8;
        const int rr = r0 + srow;
        const int gg = sg0 ^ (rr & 7);
        __builtin_amdgcn_global_load_lds(
            (GAS const u32*)(Kg + (size_t)(kb1 + rr) * QS + gg * 8),
            (LAS u32*)(Ktile[nb] + r0 * 64), 16, 0, 0);
        __builtin_amdgcn_global_load_lds(
            (GAS const u32*)(Vh + (size_t)rr * T + kb1 + gg * 8),
            (LAS u32*)(Vtile[nb] + r0 * 64), 16, 0, 0);
      }
    }
    const u16* Kt = Ktile[kt & 1];
    const u16* Vi = Vtile[kt & 1];
    const int kb = kt << 6;
    const int swz = fr & 7;
    v8s kf[4][2], vfr[4][2];
#pragma unroll
    for (int ks = 0; ks < 4; ++ks) {
      const int rr = ks * 16 + fr;
      kf[ks][0] = *(const v8s*)&Kt[rr * 64 + ((0 + fg) ^ swz) * 8];
      kf[ks][1] = *(const v8s*)&Kt[rr * 64 + ((4 + fg) ^ swz) * 8];
      vfr[ks][0] = *(const v8s*)&Vi[rr * 64 + ((0 + fg) ^ swz) * 8];
      vfr[ks][1] = *(const v8s*)&Vi[rr * 64 + ((4 + fg) ^ swz) * 8];
    }
    if (kt < ta) {
      attn_sub<false>(kf, vfr, qfA, otA, mA, lA, pw, kb, rowA, fr, fg);
      attn_sub<false>(kf, vfr, qfB, otB, mB, lB, pw, kb, rowB, fr, fg);
    } else if (kt == ta) {
      attn_sub<true>(kf, vfr, qfA, otA, mA, lA, pw, kb, rowA, fr, fg);
      attn_sub<false>(kf, vfr, qfB, otB, mB, lB, pw, kb, rowB, fr, fg);
    } else if (kt < tb) {
      attn_sub<false>(kf, vfr, qfB, otB, mB, lB, pw, kb, rowB, fr, fg);
    } else {
      attn_sub<true>(kf, vfr, qfB, otB, mB, lB, pw, kb, rowB, fr, fg);
    }
  }

  const float invA = 1.f / lA, invB = 1.f / lB;
#pragma unroll
  for (int ds = 0; ds < 4; ++ds) {
    ushort4 a4, b4;
    a4.x = f2bf(otA[ds][0] * invA);
    a4.y = f2bf(otA[ds][1] * invA);
    a4.z = f2bf(otA[ds][2] * invA);
    a4.w = f2bf(otA[ds][3] * invA);
    b4.x = f2bf(otB[ds][0] * invB);
    b4.y = f2bf(otB[ds][1] * invB);
    b4.z = f2bf(otB[ds][2] * invB);
    b4.w = f2bf(otB[ds][3] * invB);
    *(ushort4*)&y[(size_t)(b * T + rowA + fr) * C + h * D + ds * 16 + fg * 4] = a4;
    *(ushort4*)&y[(size_t)(b * T + rowB + fr) * C + h * D + ds * 16 + fg * 4] = b4;
  }
}

// ------------------------------- launch ----------------------------------
extern "C" void kernel_launch(void* const* d_in, const int* in_sizes, int n_in,
                              void* d_out, int out_size, void* d_ws, size_t ws_size,
                              hipStream_t stream) {
  const float* x      = (const float*)d_in[0];
  const float* ln1_g  = (const float*)d_in[1];
  const float* ln1_b  = (const float*)d_in[2];
  const float* W_attn = (const float*)d_in[3];
  const float* b_attn = (const float*)d_in[4];
  const float* W_o    = (const float*)d_in[5];
  const float* b_o    = (const float*)d_in[6];
  const float* ln2_g  = (const float*)d_in[7];
  const float* ln2_b  = (const float*)d_in[8];
  const float* W_fc   = (const float*)d_in[9];
  const float* b_fc   = (const float*)d_in[10];
  const float* W_fc2  = (const float*)d_in[11];
  const float* b_fc2  = (const float*)d_in[12];
  float* out = (float*)d_out;
  char* ws = (char*)d_ws;

  const size_t MB = 1u << 20;
  u16* Wattn_t = (u16*)(ws + 0 * MB);   // 6MB
  u16* Wo_t    = (u16*)(ws + 6 * MB);   // 2MB
  u16* Wfc_t   = (u16*)(ws + 8 * MB);   // 8MB
  u16* Wfc2_t  = (u16*)(ws + 16 * MB);  // 8MB
  float* x1    = (float*)(ws + 24 * MB); // 16MB
  u16* h1      = (u16*)(ws + 40 * MB);  // 8MB
  u16* qkv     = (u16*)(ws + 48 * MB);  // 24MB (alive through attn)
  u16* Vt      = (u16*)(ws + 88 * MB);  // 8MB
  u16* yb      = (u16*)(ws + 40 * MB);  // reuse h1 (dead after qkv GEMM)
  u16* h2      = (u16*)(ws + 48 * MB);  // reuse qkv (dead after attn)
  u16* ab      = (u16*)(ws + 56 * MB);  // 32MB (56..88)

  wtrans<<<dim3(3072 / 32, 1024 / 32), 256, 0, stream>>>(W_attn, Wattn_t, 1024, 3072);
  wtrans<<<dim3(1024 / 32, 1024 / 32), 256, 0, stream>>>(W_o, Wo_t, 1024, 1024);
  wtrans<<<dim3(4096 / 32, 1024 / 32), 256, 0, stream>>>(W_fc, Wfc_t, 1024, 4096);
  wtrans<<<dim3(1024 / 32, 4096 / 32), 256, 0, stream>>>(W_fc2, Wfc2_t, 4096, 1024);

  ln_bf16<<<4096, 256, 0, stream>>>(x, ln1_g, ln1_b, h1);
  gemm_bt<0><<<dim3(3072 / 128, 4096 / 128), 256, 0, stream>>>(
      h1, Wattn_t, b_attn, nullptr, qkv, 4096, 3072, 1024);
  transpose_v<<<dim3(2048 / 64, 32), 256, 0, stream>>>(qkv, Vt);
  attn_kernel<<<dim3(16, 32), 256, 0, stream>>>(qkv, Vt, yb);
  gemm_bt_n64<2><<<dim3(1024 / 64, 4096 / 128), 256, 0, stream>>>(
      yb, Wo_t, b_o, x, x1, 4096, 1024, 1024);
  ln_bf16<<<4096, 256, 0, stream>>>(x1, ln2_g, ln2_b, h2);
  gemm_bt<1><<<dim3(4096 / 128, 4096 / 128), 256, 0, stream>>>(
      h2, Wfc_t, b_fc, nullptr, ab, 4096, 4096, 1024);
  gemm_bt_n64<2><<<dim3(1024 / 64, 4096 / 128), 256, 0, stream>>>(
      ab, Wfc2_t, b_fc2, x1, out, 4096, 1024, 4096);
}

// Round 7
// 373.290 us; speedup vs baseline: 2.2886x; 1.0337x over previous
//
#include <hip/hip_runtime.h>

// Transformer block on MI355X (gfx950).
// B=2, T=2048, C=1024, H=16, D=64. All GEMMs in bf16 MFMA (16x16x32).
// R1: acc array in scratch (tanhf blocked unroll) -> unroll + inline tanh.
// R2: attention latency-bound -> LDS-staged K/V, S^T/O^T register layouts.
// R3/R4: N=1024 GEMMs occupancy-bound -> BN=64 kernel (2 blocks/CU).
// R5: attention causal pairing (block j does q-tiles j and 31-j).
// R6: depth-3 prefetch + manual vmcnt was NEUTRAL: compiler inserted its own
//     vmcnt(0) before the compiler-visible ds_reads (can't disambiguate LDS
//     written by global_load_lds), nullifying the prefetch lead (guide m131).
// R7: fragment loads via inline-asm ds_read_b128 (opaque to the compiler's
//     dependency tracker) + lgkmcnt(0) asm with fragments tied as "+v"
//     operands. Only my vmcnt(6) remains: tiles kt+1/kt+2 stay in flight
//     across the barrier (true AITER pattern).

typedef unsigned short u16;
typedef unsigned int u32;
typedef __attribute__((ext_vector_type(8))) short v8s;   // 8 x bf16 (4 VGPR)
typedef __attribute__((ext_vector_type(4))) float v4f;   // MFMA acc

#define GAS __attribute__((address_space(1)))
#define LAS __attribute__((address_space(3)))

__device__ __forceinline__ u16 f2bf(float f) {
  u32 u = __float_as_uint(f);
  u = (u + 0x7FFF + ((u >> 16) & 1)) >> 16;  // RNE
  return (u16)u;
}
__device__ __forceinline__ float bf2f(u16 h) {
  return __uint_as_float(((u32)h) << 16);
}
__device__ __forceinline__ float fast_tanh(float x) {
  return 1.f - 2.f / (1.f + __expf(2.f * x));
}

// ---------------- weight transpose + fp32->bf16 convert ----------------
__global__ __launch_bounds__(256)
void wtrans(const float* __restrict__ W, u16* __restrict__ Wt, int K, int N) {
  __shared__ float tile[32][33];
  const int n0 = blockIdx.x << 5, k0 = blockIdx.y << 5;
  const int r = threadIdx.x >> 5, c = threadIdx.x & 31;
#pragma unroll
  for (int i = 0; i < 4; ++i)
    tile[r + 8 * i][c] = W[(size_t)(k0 + r + 8 * i) * N + n0 + c];
  __syncthreads();
#pragma unroll
  for (int i = 0; i < 4; ++i)
    Wt[(size_t)(n0 + r + 8 * i) * K + k0 + c] = f2bf(tile[c][r + 8 * i]);
}

// ---------------- LayerNorm (f32 in -> bf16 out), C=1024 ----------------
__global__ __launch_bounds__(256)
void ln_bf16(const float* __restrict__ x, const float* __restrict__ g,
             const float* __restrict__ be, u16* __restrict__ out) {
  constexpr int C = 1024;
  const int row = blockIdx.x, t = threadIdx.x;
  const float4 v = ((const float4*)(x + (size_t)row * C))[t];
  float s = v.x + v.y + v.z + v.w;
#pragma unroll
  for (int m = 32; m >= 1; m >>= 1) s += __shfl_xor(s, m);
  __shared__ float red[4], red2[4];
  if ((t & 63) == 0) red[t >> 6] = s;
  __syncthreads();
  const float mu = (red[0] + red[1] + red[2] + red[3]) * (1.f / C);
  const float dx = v.x - mu, dy = v.y - mu, dz = v.z - mu, dw = v.w - mu;
  float s2 = dx * dx + dy * dy + dz * dz + dw * dw;
#pragma unroll
  for (int m = 32; m >= 1; m >>= 1) s2 += __shfl_xor(s2, m);
  if ((t & 63) == 0) red2[t >> 6] = s2;
  __syncthreads();
  const float var = (red2[0] + red2[1] + red2[2] + red2[3]) * (1.f / C);
  const float rs = rsqrtf(var + 1e-5f);
  const int c = t << 2;
  u16 o0 = f2bf(dx * rs * g[c + 0] + be[c + 0]);
  u16 o1 = f2bf(dy * rs * g[c + 1] + be[c + 1]);
  u16 o2 = f2bf(dz * rs * g[c + 2] + be[c + 2]);
  u16 o3 = f2bf(dw * rs * g[c + 3] + be[c + 3]);
  uint2 pk;
  pk.x = (u32)o0 | ((u32)o1 << 16);
  pk.y = (u32)o2 | ((u32)o3 << 16);
  *(uint2*)(out + (size_t)row * C + c) = pk;
}

// ------- GEMM 128x128: C = A[M,K] * Bt[N,K]^T + epilogue (qkv, fc1) -----
template <int EPI>
__global__ __launch_bounds__(256)
void gemm_bt(const u16* __restrict__ A, const u16* __restrict__ Bt,
             const float* __restrict__ bias, const float* __restrict__ res,
             void* __restrict__ outp, int M, int N, int K) {
  __shared__ u16 As[128 * 32];
  __shared__ u16 Bs[128 * 32];
  const int tid = threadIdx.x;
  const int wave = tid >> 6, lane = tid & 63;
  const int m0 = blockIdx.y << 7, n0 = blockIdx.x << 7;

  v4f acc[4][4];
  const v4f vz = {0.f, 0.f, 0.f, 0.f};
#pragma unroll
  for (int i = 0; i < 4; ++i)
#pragma unroll
    for (int j = 0; j < 4; ++j) acc[i][j] = vz;

  const int wm = (wave >> 1) << 6, wn = (wave & 1) << 6;
  const int sr = lane >> 2;
  const int sc = (lane & 3) << 3;
  const int fr = lane & 15;
  const int fk = (lane >> 4) << 3;
  const int c0 = wave << 1;

  u16* lA0 = As + (c0 + 0) * 512;
  u16* lA1 = As + (c0 + 1) * 512;
  u16* lB0 = Bs + (c0 + 0) * 512;
  u16* lB1 = Bs + (c0 + 1) * 512;
  const u16* gA0 = A + (size_t)(m0 + c0 * 16 + sr) * K + sc;
  const u16* gA1 = A + (size_t)(m0 + c0 * 16 + 16 + sr) * K + sc;
  const u16* gB0 = Bt + (size_t)(n0 + c0 * 16 + sr) * K + sc;
  const u16* gB1 = Bt + (size_t)(n0 + c0 * 16 + 16 + sr) * K + sc;

  for (int k0 = 0; k0 < K; k0 += 32) {
    __builtin_amdgcn_global_load_lds((GAS const u32*)(gA0 + k0), (LAS u32*)lA0, 16, 0, 0);
    __builtin_amdgcn_global_load_lds((GAS const u32*)(gA1 + k0), (LAS u32*)lA1, 16, 0, 0);
    __builtin_amdgcn_global_load_lds((GAS const u32*)(gB0 + k0), (LAS u32*)lB0, 16, 0, 0);
    __builtin_amdgcn_global_load_lds((GAS const u32*)(gB1 + k0), (LAS u32*)lB1, 16, 0, 0);
    __syncthreads();
    v8s af[4], bfr[4];
#pragma unroll
    for (int mi = 0; mi < 4; ++mi)
      af[mi] = *(const v8s*)&As[(wm + mi * 16 + fr) * 32 + fk];
#pragma unroll
    for (int ni = 0; ni < 4; ++ni)
      bfr[ni] = *(const v8s*)&Bs[(wn + ni * 16 + fr) * 32 + fk];
#pragma unroll
    for (int mi = 0; mi < 4; ++mi)
#pragma unroll
      for (int ni = 0; ni < 4; ++ni)
        acc[mi][ni] = __builtin_amdgcn_mfma_f32_16x16x32_bf16(af[mi], bfr[ni], acc[mi][ni], 0, 0, 0);
    __syncthreads();
  }

  const int er = (lane >> 4) << 2;
#pragma unroll
  for (int mi = 0; mi < 4; ++mi) {
#pragma unroll
    for (int ni = 0; ni < 4; ++ni) {
      const int col = n0 + wn + ni * 16 + fr;
      const float bcol = bias[col];
#pragma unroll
      for (int r = 0; r < 4; ++r) {
        const int row = m0 + wm + mi * 16 + er + r;
        float v = acc[mi][ni][r] + bcol;
        if constexpr (EPI == 1) {
          const float t = fast_tanh(0.7978845608028654f * (v + 0.044715f * v * v * v));
          v = 0.5f * v * (1.f + t);
        }
        if constexpr (EPI == 2) {
          v += res[(size_t)row * N + col];
          ((float*)outp)[(size_t)row * N + col] = v;
        } else {
          ((u16*)outp)[(size_t)row * N + col] = f2bf(v);
        }
      }
    }
  }
}

// ------- GEMM 128x64, depth-3 prefetch, asm ds_read (proj, fc2) ----------
// 4 LDS buffers. Fragment loads are inline-asm ds_read_b128 so the compiler
// cannot see an LDS dependency on global_load_lds (which would force its own
// vmcnt(0)). Manual vmcnt(6) = wait only the 3 oldest loads (tile kt); tiles
// kt+1, kt+2 remain in flight across the raw s_barrier. lgkmcnt(0) asm ties
// the fragments as "+v" so MFMAs cannot be hoisted above the wait.
template <int EPI>
__global__ __launch_bounds__(256)
void gemm_bt_n64(const u16* __restrict__ A, const u16* __restrict__ Bt,
                 const float* __restrict__ bias, const float* __restrict__ res,
                 void* __restrict__ outp, int M, int N, int K) {
  __shared__ u16 As[4][128 * 32];
  __shared__ u16 Bs[4][64 * 32];
  const int tid = threadIdx.x;
  const int wave = tid >> 6, lane = tid & 63;
  const int m0 = blockIdx.y << 7, n0 = blockIdx.x << 6;

  v4f acc[4][2];
  const v4f vz = {0.f, 0.f, 0.f, 0.f};
#pragma unroll
  for (int i = 0; i < 4; ++i)
#pragma unroll
    for (int j = 0; j < 2; ++j) acc[i][j] = vz;

  const int wm = (wave >> 1) << 6, wn = (wave & 1) << 5;
  const int sr = lane >> 2;
  const int sc = (lane & 3) << 3;
  const int fr = lane & 15;
  const int fk = (lane >> 4) << 3;

  const u16* gA0 = A + (size_t)(m0 + wave * 32 + sr) * K + sc;
  const u16* gA1 = A + (size_t)(m0 + wave * 32 + 16 + sr) * K + sc;
  const u16* gB0 = Bt + (size_t)(n0 + wave * 16 + sr) * K + sc;
  const int aoff = wave * 1024;
  const int boff = wave * 512;

  // raw LDS byte offsets for asm ds_read
  const u32 asb = (u32)(size_t)(LAS const u16*)&As[0][0];
  const u32 bsb = (u32)(size_t)(LAS const u16*)&Bs[0][0];
  const u32 afrag = (u32)(((wm + fr) << 6) + (fk << 1));  // row*64B + fk*2B
  const u32 bfrag = (u32)(((wn + fr) << 6) + (fk << 1));

  const int nk = K >> 5;

#define N64_ISSUE(t, bf)                                                      \
  do {                                                                        \
    const int k0_ = (t) << 5;                                                 \
    __builtin_amdgcn_global_load_lds((GAS const u32*)(gA0 + k0_),             \
                                     (LAS u32*)(As[bf] + aoff), 16, 0, 0);    \
    __builtin_amdgcn_global_load_lds((GAS const u32*)(gA1 + k0_),             \
                                     (LAS u32*)(As[bf] + aoff + 512), 16, 0, 0); \
    __builtin_amdgcn_global_load_lds((GAS const u32*)(gB0 + k0_),             \
                                     (LAS u32*)(Bs[bf] + boff), 16, 0, 0);    \
  } while (0)

  N64_ISSUE(0, 0);
  N64_ISSUE(1, 1);
  N64_ISSUE(2, 2);

  auto compute = [&](int kt) __attribute__((always_inline)) {
    const u32 ab = asb + ((u32)(kt & 3) << 13) + afrag;  // A buf stride 8 KB
    const u32 bb = bsb + ((u32)(kt & 3) << 12) + bfrag;  // B buf stride 4 KB
    v8s a0, a1, a2, a3, b0, b1;
    asm volatile("ds_read_b128 %0, %1 offset:0"    : "=v"(a0) : "v"(ab));
    asm volatile("ds_read_b128 %0, %1 offset:1024" : "=v"(a1) : "v"(ab));
    asm volatile("ds_read_b128 %0, %1 offset:2048" : "=v"(a2) : "v"(ab));
    asm volatile("ds_read_b128 %0, %1 offset:3072" : "=v"(a3) : "v"(ab));
    asm volatile("ds_read_b128 %0, %1 offset:0"    : "=v"(b0) : "v"(bb));
    asm volatile("ds_read_b128 %0, %1 offset:1024" : "=v"(b1) : "v"(bb));
    asm volatile("s_waitcnt lgkmcnt(0)"
                 : "+v"(a0), "+v"(a1), "+v"(a2), "+v"(a3), "+v"(b0), "+v"(b1)
                 :
                 : "memory");
    acc[0][0] = __builtin_amdgcn_mfma_f32_16x16x32_bf16(a0, b0, acc[0][0], 0, 0, 0);
    acc[0][1] = __builtin_amdgcn_mfma_f32_16x16x32_bf16(a0, b1, acc[0][1], 0, 0, 0);
    acc[1][0] = __builtin_amdgcn_mfma_f32_16x16x32_bf16(a1, b0, acc[1][0], 0, 0, 0);
    acc[1][1] = __builtin_amdgcn_mfma_f32_16x16x32_bf16(a1, b1, acc[1][1], 0, 0, 0);
    acc[2][0] = __builtin_amdgcn_mfma_f32_16x16x32_bf16(a2, b0, acc[2][0], 0, 0, 0);
    acc[2][1] = __builtin_amdgcn_mfma_f32_16x16x32_bf16(a2, b1, acc[2][1], 0, 0, 0);
    acc[3][0] = __builtin_amdgcn_mfma_f32_16x16x32_bf16(a3, b0, acc[3][0], 0, 0, 0);
    acc[3][1] = __builtin_amdgcn_mfma_f32_16x16x32_bf16(a3, b1, acc[3][1], 0, 0, 0);
  };

  for (int kt = 0; kt < nk - 2; ++kt) {
    asm volatile("s_waitcnt vmcnt(6)" ::: "memory");
    __builtin_amdgcn_s_barrier();
    if (kt + 3 < nk) N64_ISSUE(kt + 3, (kt + 3) & 3);
    compute(kt);
  }
  asm volatile("s_waitcnt vmcnt(3)" ::: "memory");
  __builtin_amdgcn_s_barrier();
  compute(nk - 2);
  asm volatile("s_waitcnt vmcnt(0)" ::: "memory");
  __builtin_amdgcn_s_barrier();
  compute(nk - 1);
#undef N64_ISSUE

  const int er = (lane >> 4) << 2;
#pragma unroll
  for (int mi = 0; mi < 4; ++mi) {
#pragma unroll
    for (int ni = 0; ni < 2; ++ni) {
      const int col = n0 + wn + ni * 16 + fr;
      const float bcol = bias[col];
#pragma unroll
      for (int r = 0; r < 4; ++r) {
        const int row = m0 + wm + mi * 16 + er + r;
        float v = acc[mi][ni][r] + bcol;
        if constexpr (EPI == 1) {
          const float t = fast_tanh(0.7978845608028654f * (v + 0.044715f * v * v * v));
          v = 0.5f * v * (1.f + t);
        }
        if constexpr (EPI == 2) {
          v += res[(size_t)row * N + col];
          ((float*)outp)[(size_t)row * N + col] = v;
        } else {
          ((u16*)outp)[(size_t)row * N + col] = f2bf(v);
        }
      }
    }
  }
}

// ---------------- V -> Vt [B,H,D,T] bf16 (transpose via LDS) -------------
__global__ __launch_bounds__(256)
void transpose_v(const u16* __restrict__ qkv, u16* __restrict__ Vt) {
  __shared__ u16 tile[64][65];
  const int t0 = blockIdx.x << 6;
  const int bh = blockIdx.y;
  const int b = bh >> 4, h = bh & 15;
  const int r4 = threadIdx.x >> 6, c = threadIdx.x & 63;
#pragma unroll
  for (int i = 0; i < 16; ++i) {
    const int r = r4 * 16 + i;
    tile[r][c] = qkv[(size_t)(b * 2048 + t0 + r) * 3072 + 2048 + h * 64 + c];
  }
  __syncthreads();
#pragma unroll
  for (int i = 0; i < 16; ++i) {
    const int d = r4 * 16 + i;
    Vt[(size_t)bh * 64 * 2048 + (size_t)d * 2048 + t0 + c] = tile[c][d];
  }
}

// ---------------- flash attention (causal, balanced pairing) -------------
constexpr int PSTR = 88;  // P row stride (u16): 176B = 16B-mult, 2-way banks

template <bool MASKED>
__device__ __forceinline__ void attn_sub(
    const v8s (&kf)[4][2], const v8s (&vfr)[4][2], const v8s (&qf)[2],
    v4f (&ot)[4], float& m_i, float& l_i, u16* __restrict__ pw,
    const int kb, const int qrow, const int fr, const int fg) {
  const v4f vz = {0.f, 0.f, 0.f, 0.f};
  v4f st[4];
#pragma unroll
  for (int ks = 0; ks < 4; ++ks) {
    st[ks] = vz;
    st[ks] = __builtin_amdgcn_mfma_f32_16x16x32_bf16(kf[ks][0], qf[0], st[ks], 0, 0, 0);
    st[ks] = __builtin_amdgcn_mfma_f32_16x16x32_bf16(kf[ks][1], qf[1], st[ks], 0, 0, 0);
  }
  const int q = qrow + fr;
  float e[4][4];
  float mt = -1e30f;
#pragma unroll
  for (int ks = 0; ks < 4; ++ks)
#pragma unroll
    for (int r = 0; r < 4; ++r) {
      float v = st[ks][r] * 0.125f;  // fold 1/sqrt(64)
      if (MASKED) v = (kb + ks * 16 + fg * 4 + r <= q) ? v : -1e30f;
      e[ks][r] = v;
      mt = fmaxf(mt, v);
    }
  mt = fmaxf(mt, __shfl_xor(mt, 16));
  mt = fmaxf(mt, __shfl_xor(mt, 32));
  const float m_new = fmaxf(m_i, mt);
  const float alpha = __expf(m_i - m_new);
  m_i = m_new;
  float ls = 0.f;
#pragma unroll
  for (int ks = 0; ks < 4; ++ks)
#pragma unroll
    for (int r = 0; r < 4; ++r) {
      e[ks][r] = __expf(e[ks][r] - m_new);
      ls += e[ks][r];
    }
  ls += __shfl_xor(ls, 16);
  ls += __shfl_xor(ls, 32);
  l_i = l_i * alpha + ls;
#pragma unroll
  for (int ds = 0; ds < 4; ++ds) ot[ds] *= alpha;
#pragma unroll
  for (int ks = 0; ks < 4; ++ks) {
    ushort4 pk4;
    pk4.x = f2bf(e[ks][0]);
    pk4.y = f2bf(e[ks][1]);
    pk4.z = f2bf(e[ks][2]);
    pk4.w = f2bf(e[ks][3]);
    *(ushort4*)&pw[fr * PSTR + ks * 16 + fg * 4] = pk4;
  }
  const v8s pf0 = *(const v8s*)&pw[fr * PSTR + fg * 8];
  const v8s pf1 = *(const v8s*)&pw[fr * PSTR + 32 + fg * 8];
#pragma unroll
  for (int ds = 0; ds < 4; ++ds) {
    ot[ds] = __builtin_amdgcn_mfma_f32_16x16x32_bf16(vfr[ds][0], pf0, ot[ds], 0, 0, 0);
    ot[ds] = __builtin_amdgcn_mfma_f32_16x16x32_bf16(vfr[ds][1], pf1, ot[ds], 0, 0, 0);
  }
}

__global__ __launch_bounds__(256)
void attn_kernel(const u16* __restrict__ qkv, const u16* __restrict__ Vt,
                 u16* __restrict__ y) {
  constexpr int T = 2048, D = 64, C = 1024, QS = 3072;
  __shared__ alignas(16) u16 Ktile[2][64 * 64];
  __shared__ alignas(16) u16 Vtile[2][64 * 64];
  __shared__ alignas(16) u16 Pw[4][16 * PSTR];

  const int tid = threadIdx.x, wave = tid >> 6, lane = tid & 63;
  const int fr = lane & 15, fg = lane >> 4;
  const int bh = blockIdx.y, b = bh >> 4, h = bh & 15;
  const int ta = blockIdx.x, tb = 31 - ta;
  const u16* qkvb = qkv + (size_t)b * T * QS + h * 64;  // Q base
  const u16* Kg = qkvb + 1024;                          // K base
  const u16* Vh = Vt + (size_t)bh * D * T;
  u16* pw = &Pw[wave][0];

  const int rowA = ta * 64 + wave * 16;
  const int rowB = tb * 64 + wave * 16;

  v8s qfA[2], qfB[2];
#pragma unroll
  for (int dh = 0; dh < 2; ++dh) {
    qfA[dh] = *(const v8s*)&qkvb[(size_t)(rowA + fr) * QS + dh * 32 + fg * 8];
    qfB[dh] = *(const v8s*)&qkvb[(size_t)(rowB + fr) * QS + dh * 32 + fg * 8];
  }

  const v4f vz = {0.f, 0.f, 0.f, 0.f};
  v4f otA[4], otB[4];
#pragma unroll
  for (int ds = 0; ds < 4; ++ds) { otA[ds] = vz; otB[ds] = vz; }
  float mA = -1e30f, lA = 0.f, mB = -1e30f, lB = 0.f;

  const int srow = lane >> 3;
  const int sg0 = lane & 7;

  const int nt = tb + 1;
  {
#pragma unroll
    for (int cc = 0; cc < 2; ++cc) {
      const int r0 = wave * 16 + cc * 8;
      const int rr = r0 + srow;
      const int gg = sg0 ^ (rr & 7);
      __builtin_amdgcn_global_load_lds(
          (GAS const u32*)(Kg + (size_t)rr * QS + gg * 8),
          (LAS u32*)(Ktile[0] + r0 * 64), 16, 0, 0);
      __builtin_amdgcn_global_load_lds(
          (GAS const u32*)(Vh + (size_t)rr * T + gg * 8),
          (LAS u32*)(Vtile[0] + r0 * 64), 16, 0, 0);
    }
  }
  for (int kt = 0; kt < nt; ++kt) {
    __syncthreads();
    if (kt + 1 < nt) {
      const int kb1 = (kt + 1) << 6;
      const int nb = (kt + 1) & 1;
#pragma unroll
      for (int cc = 0; cc < 2; ++cc) {
        const int r0 = wave * 16 + cc * 8;
        const int rr = r0 + srow;
        const int gg = sg0 ^ (rr & 7);
        __builtin_amdgcn_global_load_lds(
            (GAS const u32*)(Kg + (size_t)(kb1 + rr) * QS + gg * 8),
            (LAS u32*)(Ktile[nb] + r0 * 64), 16, 0, 0);
        __builtin_amdgcn_global_load_lds(
            (GAS const u32*)(Vh + (size_t)rr * T + kb1 + gg * 8),
            (LAS u32*)(Vtile[nb] + r0 * 64), 16, 0, 0);
      }
    }
    const u16* Kt = Ktile[kt & 1];
    const u16* Vi = Vtile[kt & 1];
    const int kb = kt << 6;
    const int swz = fr & 7;
    v8s kf[4][2], vfr[4][2];
#pragma unroll
    for (int ks = 0; ks < 4; ++ks) {
      const int rr = ks * 16 + fr;
      kf[ks][0] = *(const v8s*)&Kt[rr * 64 + ((0 + fg) ^ swz) * 8];
      kf[ks][1] = *(const v8s*)&Kt[rr * 64 + ((4 + fg) ^ swz) * 8];
      vfr[ks][0] = *(const v8s*)&Vi[rr * 64 + ((0 + fg) ^ swz) * 8];
      vfr[ks][1] = *(const v8s*)&Vi[rr * 64 + ((4 + fg) ^ swz) * 8];
    }
    if (kt < ta) {
      attn_sub<false>(kf, vfr, qfA, otA, mA, lA, pw, kb, rowA, fr, fg);
      attn_sub<false>(kf, vfr, qfB, otB, mB, lB, pw, kb, rowB, fr, fg);
    } else if (kt == ta) {
      attn_sub<true>(kf, vfr, qfA, otA, mA, lA, pw, kb, rowA, fr, fg);
      attn_sub<false>(kf, vfr, qfB, otB, mB, lB, pw, kb, rowB, fr, fg);
    } else if (kt < tb) {
      attn_sub<false>(kf, vfr, qfB, otB, mB, lB, pw, kb, rowB, fr, fg);
    } else {
      attn_sub<true>(kf, vfr, qfB, otB, mB, lB, pw, kb, rowB, fr, fg);
    }
  }

  const float invA = 1.f / lA, invB = 1.f / lB;
#pragma unroll
  for (int ds = 0; ds < 4; ++ds) {
    ushort4 a4, b4;
    a4.x = f2bf(otA[ds][0] * invA);
    a4.y = f2bf(otA[ds][1] * invA);
    a4.z = f2bf(otA[ds][2] * invA);
    a4.w = f2bf(otA[ds][3] * invA);
    b4.x = f2bf(otB[ds][0] * invB);
    b4.y = f2bf(otB[ds][1] * invB);
    b4.z = f2bf(otB[ds][2] * invB);
    b4.w = f2bf(otB[ds][3] * invB);
    *(ushort4*)&y[(size_t)(b * T + rowA + fr) * C + h * D + ds * 16 + fg * 4] = a4;
    *(ushort4*)&y[(size_t)(b * T + rowB + fr) * C + h * D + ds * 16 + fg * 4] = b4;
  }
}

// ------------------------------- launch ----------------------------------
extern "C" void kernel_launch(void* const* d_in, const int* in_sizes, int n_in,
                              void* d_out, int out_size, void* d_ws, size_t ws_size,
                              hipStream_t stream) {
  const float* x      = (const float*)d_in[0];
  const float* ln1_g  = (const float*)d_in[1];
  const float* ln1_b  = (const float*)d_in[2];
  const float* W_attn = (const float*)d_in[3];
  const float* b_attn = (const float*)d_in[4];
  const float* W_o    = (const float*)d_in[5];
  const float* b_o    = (const float*)d_in[6];
  const float* ln2_g  = (const float*)d_in[7];
  const float* ln2_b  = (const float*)d_in[8];
  const float* W_fc   = (const float*)d_in[9];
  const float* b_fc   = (const float*)d_in[10];
  const float* W_fc2  = (const float*)d_in[11];
  const float* b_fc2  = (const float*)d_in[12];
  float* out = (float*)d_out;
  char* ws = (char*)d_ws;

  const size_t MB = 1u << 20;
  u16* Wattn_t = (u16*)(ws + 0 * MB);   // 6MB
  u16* Wo_t    = (u16*)(ws + 6 * MB);   // 2MB
  u16* Wfc_t   = (u16*)(ws + 8 * MB);   // 8MB
  u16* Wfc2_t  = (u16*)(ws + 16 * MB);  // 8MB
  float* x1    = (float*)(ws + 24 * MB); // 16MB
  u16* h1      = (u16*)(ws + 40 * MB);  // 8MB
  u16* qkv     = (u16*)(ws + 48 * MB);  // 24MB (alive through attn)
  u16* Vt      = (u16*)(ws + 88 * MB);  // 8MB
  u16* yb      = (u16*)(ws + 40 * MB);  // reuse h1 (dead after qkv GEMM)
  u16* h2      = (u16*)(ws + 48 * MB);  // reuse qkv (dead after attn)
  u16* ab      = (u16*)(ws + 56 * MB);  // 32MB (56..88)

  wtrans<<<dim3(3072 / 32, 1024 / 32), 256, 0, stream>>>(W_attn, Wattn_t, 1024, 3072);
  wtrans<<<dim3(1024 / 32, 1024 / 32), 256, 0, stream>>>(W_o, Wo_t, 1024, 1024);
  wtrans<<<dim3(4096 / 32, 1024 / 32), 256, 0, stream>>>(W_fc, Wfc_t, 1024, 4096);
  wtrans<<<dim3(1024 / 32, 4096 / 32), 256, 0, stream>>>(W_fc2, Wfc2_t, 4096, 1024);

  ln_bf16<<<4096, 256, 0, stream>>>(x, ln1_g, ln1_b, h1);
  gemm_bt<0><<<dim3(3072 / 128, 4096 / 128), 256, 0, stream>>>(
      h1, Wattn_t, b_attn, nullptr, qkv, 4096, 3072, 1024);
  transpose_v<<<dim3(2048 / 64, 32), 256, 0, stream>>>(qkv, Vt);
  attn_kernel<<<dim3(16, 32), 256, 0, stream>>>(qkv, Vt, yb);
  gemm_bt_n64<2><<<dim3(1024 / 64, 4096 / 128), 256, 0, stream>>>(
      yb, Wo_t, b_o, x, x1, 4096, 1024, 1024);
  ln_bf16<<<4096, 256, 0, stream>>>(x1, ln2_g, ln2_b, h2);
  gemm_bt<1><<<dim3(4096 / 128, 4096 / 128), 256, 0, stream>>>(
      h2, Wfc_t, b_fc, nullptr, ab, 4096, 4096, 1024);
  gemm_bt_n64<2><<<dim3(1024 / 64, 4096 / 128), 256, 0, stream>>>(
      ab, Wfc2_t, b_fc2, x1, out, 4096, 1024, 4096);
}

// Round 8
// 364.828 us; speedup vs baseline: 2.3417x; 1.0232x over previous
//
#include <hip/hip_runtime.h>

// Transformer block on MI355X (gfx950).
// B=2, T=2048, C=1024, H=16, D=64. All GEMMs in bf16 MFMA (16x16x32).
// R1: acc array in scratch -> unroll + inline tanh.
// R2: attention latency-bound -> LDS-staged K/V, S^T/O^T register layouts.
// R3/R4: N=1024 GEMMs occupancy-bound -> BN=64 kernel (2 blocks/CU).
// R5: attention causal pairing (block j does q-tiles j and 31-j).
// R6: manual vmcnt NEUTRAL (compiler re-inserted vmcnt(0) before visible
//     ds_reads). R7: asm-opaque ds_read_b128 + vmcnt(6) pipeline -> WIN,
//     fc2/proj off the critical list.
// R8: same pipeline ported to the 128x128 kernel (gemm_bt_p): depth-3 over
//     4 LDS buffer pairs (64KB, 2 blocks/CU), vmcnt(8) steady state, asm
//     ds_read fragments. Used for qkv + fc1 (the R7 leaders, ~500 TF on the
//     old 2-barrier structure).

typedef unsigned short u16;
typedef unsigned int u32;
typedef __attribute__((ext_vector_type(8))) short v8s;   // 8 x bf16 (4 VGPR)
typedef __attribute__((ext_vector_type(4))) float v4f;   // MFMA acc

#define GAS __attribute__((address_space(1)))
#define LAS __attribute__((address_space(3)))

__device__ __forceinline__ u16 f2bf(float f) {
  u32 u = __float_as_uint(f);
  u = (u + 0x7FFF + ((u >> 16) & 1)) >> 16;  // RNE
  return (u16)u;
}
__device__ __forceinline__ float bf2f(u16 h) {
  return __uint_as_float(((u32)h) << 16);
}
__device__ __forceinline__ float fast_tanh(float x) {
  return 1.f - 2.f / (1.f + __expf(2.f * x));
}

// ---------------- weight transpose + fp32->bf16 convert ----------------
__global__ __launch_bounds__(256)
void wtrans(const float* __restrict__ W, u16* __restrict__ Wt, int K, int N) {
  __shared__ float tile[32][33];
  const int n0 = blockIdx.x << 5, k0 = blockIdx.y << 5;
  const int r = threadIdx.x >> 5, c = threadIdx.x & 31;
#pragma unroll
  for (int i = 0; i < 4; ++i)
    tile[r + 8 * i][c] = W[(size_t)(k0 + r + 8 * i) * N + n0 + c];
  __syncthreads();
#pragma unroll
  for (int i = 0; i < 4; ++i)
    Wt[(size_t)(n0 + r + 8 * i) * K + k0 + c] = f2bf(tile[c][r + 8 * i]);
}

// ---------------- LayerNorm (f32 in -> bf16 out), C=1024 ----------------
__global__ __launch_bounds__(256)
void ln_bf16(const float* __restrict__ x, const float* __restrict__ g,
             const float* __restrict__ be, u16* __restrict__ out) {
  constexpr int C = 1024;
  const int row = blockIdx.x, t = threadIdx.x;
  const float4 v = ((const float4*)(x + (size_t)row * C))[t];
  float s = v.x + v.y + v.z + v.w;
#pragma unroll
  for (int m = 32; m >= 1; m >>= 1) s += __shfl_xor(s, m);
  __shared__ float red[4], red2[4];
  if ((t & 63) == 0) red[t >> 6] = s;
  __syncthreads();
  const float mu = (red[0] + red[1] + red[2] + red[3]) * (1.f / C);
  const float dx = v.x - mu, dy = v.y - mu, dz = v.z - mu, dw = v.w - mu;
  float s2 = dx * dx + dy * dy + dz * dz + dw * dw;
#pragma unroll
  for (int m = 32; m >= 1; m >>= 1) s2 += __shfl_xor(s2, m);
  if ((t & 63) == 0) red2[t >> 6] = s2;
  __syncthreads();
  const float var = (red2[0] + red2[1] + red2[2] + red2[3]) * (1.f / C);
  const float rs = rsqrtf(var + 1e-5f);
  const int c = t << 2;
  u16 o0 = f2bf(dx * rs * g[c + 0] + be[c + 0]);
  u16 o1 = f2bf(dy * rs * g[c + 1] + be[c + 1]);
  u16 o2 = f2bf(dz * rs * g[c + 2] + be[c + 2]);
  u16 o3 = f2bf(dw * rs * g[c + 3] + be[c + 3]);
  uint2 pk;
  pk.x = (u32)o0 | ((u32)o1 << 16);
  pk.y = (u32)o2 | ((u32)o3 << 16);
  *(uint2*)(out + (size_t)row * C + c) = pk;
}

// ------- GEMM 128x128, depth-3 asm pipeline (qkv, fc1) -------------------
// 4 LDS buffer pairs (64KB). Per iter: vmcnt(8) waits only tile kt's 4
// loads; kt+1/kt+2 stay in flight across the raw s_barrier. Fragment loads
// are asm ds_read_b128 (opaque to compiler dep tracking) + lgkmcnt(0) tying
// all 8 fragments.
template <int EPI>
__global__ __launch_bounds__(256)
void gemm_bt_p(const u16* __restrict__ A, const u16* __restrict__ Bt,
               const float* __restrict__ bias, const float* __restrict__ res,
               void* __restrict__ outp, int M, int N, int K) {
  __shared__ u16 As[4][128 * 32];
  __shared__ u16 Bs[4][128 * 32];
  const int tid = threadIdx.x;
  const int wave = tid >> 6, lane = tid & 63;
  const int m0 = blockIdx.y << 7, n0 = blockIdx.x << 7;

  v4f acc[4][4];
  const v4f vz = {0.f, 0.f, 0.f, 0.f};
#pragma unroll
  for (int i = 0; i < 4; ++i)
#pragma unroll
    for (int j = 0; j < 4; ++j) acc[i][j] = vz;

  const int wm = (wave >> 1) << 6, wn = (wave & 1) << 6;
  const int sr = lane >> 2;
  const int sc = (lane & 3) << 3;
  const int fr = lane & 15;
  const int fk = (lane >> 4) << 3;
  const int c0 = wave << 1;

  const u16* gA0 = A + (size_t)(m0 + c0 * 16 + sr) * K + sc;
  const u16* gA1 = A + (size_t)(m0 + c0 * 16 + 16 + sr) * K + sc;
  const u16* gB0 = Bt + (size_t)(n0 + c0 * 16 + sr) * K + sc;
  const u16* gB1 = Bt + (size_t)(n0 + c0 * 16 + 16 + sr) * K + sc;
  const int aoff = c0 * 512;  // elements within a buffer

  const u32 asb = (u32)(size_t)(LAS const u16*)&As[0][0];
  const u32 bsb = (u32)(size_t)(LAS const u16*)&Bs[0][0];
  const u32 afrag = (u32)(((wm + fr) << 6) + (fk << 1));  // bytes
  const u32 bfrag = (u32)(((wn + fr) << 6) + (fk << 1));

  const int nk = K >> 5;  // >= 4

#define P128_ISSUE(t, bf)                                                        \
  do {                                                                           \
    const int k0_ = (t) << 5;                                                    \
    __builtin_amdgcn_global_load_lds((GAS const u32*)(gA0 + k0_),                \
                                     (LAS u32*)(As[bf] + aoff), 16, 0, 0);       \
    __builtin_amdgcn_global_load_lds((GAS const u32*)(gA1 + k0_),                \
                                     (LAS u32*)(As[bf] + aoff + 512), 16, 0, 0); \
    __builtin_amdgcn_global_load_lds((GAS const u32*)(gB0 + k0_),                \
                                     (LAS u32*)(Bs[bf] + aoff), 16, 0, 0);       \
    __builtin_amdgcn_global_load_lds((GAS const u32*)(gB1 + k0_),                \
                                     (LAS u32*)(Bs[bf] + aoff + 512), 16, 0, 0); \
  } while (0)

  P128_ISSUE(0, 0);
  P128_ISSUE(1, 1);
  P128_ISSUE(2, 2);

  auto compute = [&](int kt) __attribute__((always_inline)) {
    const u32 ab = asb + ((u32)(kt & 3) << 13) + afrag;  // buf stride 8 KB
    const u32 bb = bsb + ((u32)(kt & 3) << 13) + bfrag;
    v8s a0, a1, a2, a3, b0, b1, b2, b3;
    asm volatile("ds_read_b128 %0, %1 offset:0"    : "=v"(a0) : "v"(ab));
    asm volatile("ds_read_b128 %0, %1 offset:1024" : "=v"(a1) : "v"(ab));
    asm volatile("ds_read_b128 %0, %1 offset:2048" : "=v"(a2) : "v"(ab));
    asm volatile("ds_read_b128 %0, %1 offset:3072" : "=v"(a3) : "v"(ab));
    asm volatile("ds_read_b128 %0, %1 offset:0"    : "=v"(b0) : "v"(bb));
    asm volatile("ds_read_b128 %0, %1 offset:1024" : "=v"(b1) : "v"(bb));
    asm volatile("ds_read_b128 %0, %1 offset:2048" : "=v"(b2) : "v"(bb));
    asm volatile("ds_read_b128 %0, %1 offset:3072" : "=v"(b3) : "v"(bb));
    asm volatile("s_waitcnt lgkmcnt(0)"
                 : "+v"(a0), "+v"(a1), "+v"(a2), "+v"(a3),
                   "+v"(b0), "+v"(b1), "+v"(b2), "+v"(b3)
                 :
                 : "memory");
    acc[0][0] = __builtin_amdgcn_mfma_f32_16x16x32_bf16(a0, b0, acc[0][0], 0, 0, 0);
    acc[0][1] = __builtin_amdgcn_mfma_f32_16x16x32_bf16(a0, b1, acc[0][1], 0, 0, 0);
    acc[0][2] = __builtin_amdgcn_mfma_f32_16x16x32_bf16(a0, b2, acc[0][2], 0, 0, 0);
    acc[0][3] = __builtin_amdgcn_mfma_f32_16x16x32_bf16(a0, b3, acc[0][3], 0, 0, 0);
    acc[1][0] = __builtin_amdgcn_mfma_f32_16x16x32_bf16(a1, b0, acc[1][0], 0, 0, 0);
    acc[1][1] = __builtin_amdgcn_mfma_f32_16x16x32_bf16(a1, b1, acc[1][1], 0, 0, 0);
    acc[1][2] = __builtin_amdgcn_mfma_f32_16x16x32_bf16(a1, b2, acc[1][2], 0, 0, 0);
    acc[1][3] = __builtin_amdgcn_mfma_f32_16x16x32_bf16(a1, b3, acc[1][3], 0, 0, 0);
    acc[2][0] = __builtin_amdgcn_mfma_f32_16x16x32_bf16(a2, b0, acc[2][0], 0, 0, 0);
    acc[2][1] = __builtin_amdgcn_mfma_f32_16x16x32_bf16(a2, b1, acc[2][1], 0, 0, 0);
    acc[2][2] = __builtin_amdgcn_mfma_f32_16x16x32_bf16(a2, b2, acc[2][2], 0, 0, 0);
    acc[2][3] = __builtin_amdgcn_mfma_f32_16x16x32_bf16(a2, b3, acc[2][3], 0, 0, 0);
    acc[3][0] = __builtin_amdgcn_mfma_f32_16x16x32_bf16(a3, b0, acc[3][0], 0, 0, 0);
    acc[3][1] = __builtin_amdgcn_mfma_f32_16x16x32_bf16(a3, b1, acc[3][1], 0, 0, 0);
    acc[3][2] = __builtin_amdgcn_mfma_f32_16x16x32_bf16(a3, b2, acc[3][2], 0, 0, 0);
    acc[3][3] = __builtin_amdgcn_mfma_f32_16x16x32_bf16(a3, b3, acc[3][3], 0, 0, 0);
  };

  for (int kt = 0; kt < nk - 3; ++kt) {
    asm volatile("s_waitcnt vmcnt(8)" ::: "memory");
    __builtin_amdgcn_s_barrier();
    P128_ISSUE(kt + 3, (kt + 3) & 3);
    compute(kt);
  }
  asm volatile("s_waitcnt vmcnt(8)" ::: "memory");
  __builtin_amdgcn_s_barrier();
  compute(nk - 3);
  asm volatile("s_waitcnt vmcnt(4)" ::: "memory");
  __builtin_amdgcn_s_barrier();
  compute(nk - 2);
  asm volatile("s_waitcnt vmcnt(0)" ::: "memory");
  __builtin_amdgcn_s_barrier();
  compute(nk - 1);
#undef P128_ISSUE

  const int er = (lane >> 4) << 2;
#pragma unroll
  for (int mi = 0; mi < 4; ++mi) {
#pragma unroll
    for (int ni = 0; ni < 4; ++ni) {
      const int col = n0 + wn + ni * 16 + fr;
      const float bcol = bias[col];
#pragma unroll
      for (int r = 0; r < 4; ++r) {
        const int row = m0 + wm + mi * 16 + er + r;
        float v = acc[mi][ni][r] + bcol;
        if constexpr (EPI == 1) {
          const float t = fast_tanh(0.7978845608028654f * (v + 0.044715f * v * v * v));
          v = 0.5f * v * (1.f + t);
        }
        if constexpr (EPI == 2) {
          v += res[(size_t)row * N + col];
          ((float*)outp)[(size_t)row * N + col] = v;
        } else {
          ((u16*)outp)[(size_t)row * N + col] = f2bf(v);
        }
      }
    }
  }
}

// ------- GEMM 128x64, depth-3 prefetch, asm ds_read (proj, fc2) ----------
template <int EPI>
__global__ __launch_bounds__(256)
void gemm_bt_n64(const u16* __restrict__ A, const u16* __restrict__ Bt,
                 const float* __restrict__ bias, const float* __restrict__ res,
                 void* __restrict__ outp, int M, int N, int K) {
  __shared__ u16 As[4][128 * 32];
  __shared__ u16 Bs[4][64 * 32];
  const int tid = threadIdx.x;
  const int wave = tid >> 6, lane = tid & 63;
  const int m0 = blockIdx.y << 7, n0 = blockIdx.x << 6;

  v4f acc[4][2];
  const v4f vz = {0.f, 0.f, 0.f, 0.f};
#pragma unroll
  for (int i = 0; i < 4; ++i)
#pragma unroll
    for (int j = 0; j < 2; ++j) acc[i][j] = vz;

  const int wm = (wave >> 1) << 6, wn = (wave & 1) << 5;
  const int sr = lane >> 2;
  const int sc = (lane & 3) << 3;
  const int fr = lane & 15;
  const int fk = (lane >> 4) << 3;

  const u16* gA0 = A + (size_t)(m0 + wave * 32 + sr) * K + sc;
  const u16* gA1 = A + (size_t)(m0 + wave * 32 + 16 + sr) * K + sc;
  const u16* gB0 = Bt + (size_t)(n0 + wave * 16 + sr) * K + sc;
  const int aoff = wave * 1024;
  const int boff = wave * 512;

  const u32 asb = (u32)(size_t)(LAS const u16*)&As[0][0];
  const u32 bsb = (u32)(size_t)(LAS const u16*)&Bs[0][0];
  const u32 afrag = (u32)(((wm + fr) << 6) + (fk << 1));
  const u32 bfrag = (u32)(((wn + fr) << 6) + (fk << 1));

  const int nk = K >> 5;

#define N64_ISSUE(t, bf)                                                      \
  do {                                                                        \
    const int k0_ = (t) << 5;                                                 \
    __builtin_amdgcn_global_load_lds((GAS const u32*)(gA0 + k0_),             \
                                     (LAS u32*)(As[bf] + aoff), 16, 0, 0);    \
    __builtin_amdgcn_global_load_lds((GAS const u32*)(gA1 + k0_),             \
                                     (LAS u32*)(As[bf] + aoff + 512), 16, 0, 0); \
    __builtin_amdgcn_global_load_lds((GAS const u32*)(gB0 + k0_),             \
                                     (LAS u32*)(Bs[bf] + boff), 16, 0, 0);    \
  } while (0)

  N64_ISSUE(0, 0);
  N64_ISSUE(1, 1);
  N64_ISSUE(2, 2);

  auto compute = [&](int kt) __attribute__((always_inline)) {
    const u32 ab = asb + ((u32)(kt & 3) << 13) + afrag;  // A buf stride 8 KB
    const u32 bb = bsb + ((u32)(kt & 3) << 12) + bfrag;  // B buf stride 4 KB
    v8s a0, a1, a2, a3, b0, b1;
    asm volatile("ds_read_b128 %0, %1 offset:0"    : "=v"(a0) : "v"(ab));
    asm volatile("ds_read_b128 %0, %1 offset:1024" : "=v"(a1) : "v"(ab));
    asm volatile("ds_read_b128 %0, %1 offset:2048" : "=v"(a2) : "v"(ab));
    asm volatile("ds_read_b128 %0, %1 offset:3072" : "=v"(a3) : "v"(ab));
    asm volatile("ds_read_b128 %0, %1 offset:0"    : "=v"(b0) : "v"(bb));
    asm volatile("ds_read_b128 %0, %1 offset:1024" : "=v"(b1) : "v"(bb));
    asm volatile("s_waitcnt lgkmcnt(0)"
                 : "+v"(a0), "+v"(a1), "+v"(a2), "+v"(a3), "+v"(b0), "+v"(b1)
                 :
                 : "memory");
    acc[0][0] = __builtin_amdgcn_mfma_f32_16x16x32_bf16(a0, b0, acc[0][0], 0, 0, 0);
    acc[0][1] = __builtin_amdgcn_mfma_f32_16x16x32_bf16(a0, b1, acc[0][1], 0, 0, 0);
    acc[1][0] = __builtin_amdgcn_mfma_f32_16x16x32_bf16(a1, b0, acc[1][0], 0, 0, 0);
    acc[1][1] = __builtin_amdgcn_mfma_f32_16x16x32_bf16(a1, b1, acc[1][1], 0, 0, 0);
    acc[2][0] = __builtin_amdgcn_mfma_f32_16x16x32_bf16(a2, b0, acc[2][0], 0, 0, 0);
    acc[2][1] = __builtin_amdgcn_mfma_f32_16x16x32_bf16(a2, b1, acc[2][1], 0, 0, 0);
    acc[3][0] = __builtin_amdgcn_mfma_f32_16x16x32_bf16(a3, b0, acc[3][0], 0, 0, 0);
    acc[3][1] = __builtin_amdgcn_mfma_f32_16x16x32_bf16(a3, b1, acc[3][1], 0, 0, 0);
  };

  for (int kt = 0; kt < nk - 2; ++kt) {
    asm volatile("s_waitcnt vmcnt(6)" ::: "memory");
    __builtin_amdgcn_s_barrier();
    if (kt + 3 < nk) N64_ISSUE(kt + 3, (kt + 3) & 3);
    compute(kt);
  }
  asm volatile("s_waitcnt vmcnt(3)" ::: "memory");
  __builtin_amdgcn_s_barrier();
  compute(nk - 2);
  asm volatile("s_waitcnt vmcnt(0)" ::: "memory");
  __builtin_amdgcn_s_barrier();
  compute(nk - 1);
#undef N64_ISSUE

  const int er = (lane >> 4) << 2;
#pragma unroll
  for (int mi = 0; mi < 4; ++mi) {
#pragma unroll
    for (int ni = 0; ni < 2; ++ni) {
      const int col = n0 + wn + ni * 16 + fr;
      const float bcol = bias[col];
#pragma unroll
      for (int r = 0; r < 4; ++r) {
        const int row = m0 + wm + mi * 16 + er + r;
        float v = acc[mi][ni][r] + bcol;
        if constexpr (EPI == 1) {
          const float t = fast_tanh(0.7978845608028654f * (v + 0.044715f * v * v * v));
          v = 0.5f * v * (1.f + t);
        }
        if constexpr (EPI == 2) {
          v += res[(size_t)row * N + col];
          ((float*)outp)[(size_t)row * N + col] = v;
        } else {
          ((u16*)outp)[(size_t)row * N + col] = f2bf(v);
        }
      }
    }
  }
}

// ---------------- V -> Vt [B,H,D,T] bf16 (transpose via LDS) -------------
__global__ __launch_bounds__(256)
void transpose_v(const u16* __restrict__ qkv, u16* __restrict__ Vt) {
  __shared__ u16 tile[64][65];
  const int t0 = blockIdx.x << 6;
  const int bh = blockIdx.y;
  const int b = bh >> 4, h = bh & 15;
  const int r4 = threadIdx.x >> 6, c = threadIdx.x & 63;
#pragma unroll
  for (int i = 0; i < 16; ++i) {
    const int r = r4 * 16 + i;
    tile[r][c] = qkv[(size_t)(b * 2048 + t0 + r) * 3072 + 2048 + h * 64 + c];
  }
  __syncthreads();
#pragma unroll
  for (int i = 0; i < 16; ++i) {
    const int d = r4 * 16 + i;
    Vt[(size_t)bh * 64 * 2048 + (size_t)d * 2048 + t0 + c] = tile[c][d];
  }
}

// ---------------- flash attention (causal, balanced pairing) -------------
constexpr int PSTR = 88;  // P row stride (u16): 176B = 16B-mult, 2-way banks

template <bool MASKED>
__device__ __forceinline__ void attn_sub(
    const v8s (&kf)[4][2], const v8s (&vfr)[4][2], const v8s (&qf)[2],
    v4f (&ot)[4], float& m_i, float& l_i, u16* __restrict__ pw,
    const int kb, const int qrow, const int fr, const int fg) {
  const v4f vz = {0.f, 0.f, 0.f, 0.f};
  v4f st[4];
#pragma unroll
  for (int ks = 0; ks < 4; ++ks) {
    st[ks] = vz;
    st[ks] = __builtin_amdgcn_mfma_f32_16x16x32_bf16(kf[ks][0], qf[0], st[ks], 0, 0, 0);
    st[ks] = __builtin_amdgcn_mfma_f32_16x16x32_bf16(kf[ks][1], qf[1], st[ks], 0, 0, 0);
  }
  const int q = qrow + fr;
  float e[4][4];
  float mt = -1e30f;
#pragma unroll
  for (int ks = 0; ks < 4; ++ks)
#pragma unroll
    for (int r = 0; r < 4; ++r) {
      float v = st[ks][r] * 0.125f;  // fold 1/sqrt(64)
      if (MASKED) v = (kb + ks * 16 + fg * 4 + r <= q) ? v : -1e30f;
      e[ks][r] = v;
      mt = fmaxf(mt, v);
    }
  mt = fmaxf(mt, __shfl_xor(mt, 16));
  mt = fmaxf(mt, __shfl_xor(mt, 32));
  const float m_new = fmaxf(m_i, mt);
  const float alpha = __expf(m_i - m_new);
  m_i = m_new;
  float ls = 0.f;
#pragma unroll
  for (int ks = 0; ks < 4; ++ks)
#pragma unroll
    for (int r = 0; r < 4; ++r) {
      e[ks][r] = __expf(e[ks][r] - m_new);
      ls += e[ks][r];
    }
  ls += __shfl_xor(ls, 16);
  ls += __shfl_xor(ls, 32);
  l_i = l_i * alpha + ls;
#pragma unroll
  for (int ds = 0; ds < 4; ++ds) ot[ds] *= alpha;
#pragma unroll
  for (int ks = 0; ks < 4; ++ks) {
    ushort4 pk4;
    pk4.x = f2bf(e[ks][0]);
    pk4.y = f2bf(e[ks][1]);
    pk4.z = f2bf(e[ks][2]);
    pk4.w = f2bf(e[ks][3]);
    *(ushort4*)&pw[fr * PSTR + ks * 16 + fg * 4] = pk4;
  }
  const v8s pf0 = *(const v8s*)&pw[fr * PSTR + fg * 8];
  const v8s pf1 = *(const v8s*)&pw[fr * PSTR + 32 + fg * 8];
#pragma unroll
  for (int ds = 0; ds < 4; ++ds) {
    ot[ds] = __builtin_amdgcn_mfma_f32_16x16x32_bf16(vfr[ds][0], pf0, ot[ds], 0, 0, 0);
    ot[ds] = __builtin_amdgcn_mfma_f32_16x16x32_bf16(vfr[ds][1], pf1, ot[ds], 0, 0, 0);
  }
}

__global__ __launch_bounds__(256)
void attn_kernel(const u16* __restrict__ qkv, const u16* __restrict__ Vt,
                 u16* __restrict__ y) {
  constexpr int T = 2048, D = 64, C = 1024, QS = 3072;
  __shared__ alignas(16) u16 Ktile[2][64 * 64];
  __shared__ alignas(16) u16 Vtile[2][64 * 64];
  __shared__ alignas(16) u16 Pw[4][16 * PSTR];

  const int tid = threadIdx.x, wave = tid >> 6, lane = tid & 63;
  const int fr = lane & 15, fg = lane >> 4;
  const int bh = blockIdx.y, b = bh >> 4, h = bh & 15;
  const int ta = blockIdx.x, tb = 31 - ta;
  const u16* qkvb = qkv + (size_t)b * T * QS + h * 64;  // Q base
  const u16* Kg = qkvb + 1024;                          // K base
  const u16* Vh = Vt + (size_t)bh * D * T;
  u16* pw = &Pw[wave][0];

  const int rowA = ta * 64 + wave * 16;
  const int rowB = tb * 64 + wave * 16;

  v8s qfA[2], qfB[2];
#pragma unroll
  for (int dh = 0; dh < 2; ++dh) {
    qfA[dh] = *(const v8s*)&qkvb[(size_t)(rowA + fr) * QS + dh * 32 + fg * 8];
    qfB[dh] = *(const v8s*)&qkvb[(size_t)(rowB + fr) * QS + dh * 32 + fg * 8];
  }

  const v4f vz = {0.f, 0.f, 0.f, 0.f};
  v4f otA[4], otB[4];
#pragma unroll
  for (int ds = 0; ds < 4; ++ds) { otA[ds] = vz; otB[ds] = vz; }
  float mA = -1e30f, lA = 0.f, mB = -1e30f, lB = 0.f;

  const int srow = lane >> 3;
  const int sg0 = lane & 7;

  const int nt = tb + 1;
  {
#pragma unroll
    for (int cc = 0; cc < 2; ++cc) {
      const int r0 = wave * 16 + cc * 8;
      const int rr = r0 + srow;
      const int gg = sg0 ^ (rr & 7);
      __builtin_amdgcn_global_load_lds(
          (GAS const u32*)(Kg + (size_t)rr * QS + gg * 8),
          (LAS u32*)(Ktile[0] + r0 * 64), 16, 0, 0);
      __builtin_amdgcn_global_load_lds(
          (GAS const u32*)(Vh + (size_t)rr * T + gg * 8),
          (LAS u32*)(Vtile[0] + r0 * 64), 16, 0, 0);
    }
  }
  for (int kt = 0; kt < nt; ++kt) {
    __syncthreads();
    if (kt + 1 < nt) {
      const int kb1 = (kt + 1) << 6;
      const int nb = (kt + 1) & 1;
#pragma unroll
      for (int cc = 0; cc < 2; ++cc) {
        const int r0 = wave * 16 + cc * 8;
        const int rr = r0 + srow;
        const int gg = sg0 ^ (rr & 7);
        __builtin_amdgcn_global_load_lds(
            (GAS const u32*)(Kg + (size_t)(kb1 + rr) * QS + gg * 8),
            (LAS u32*)(Ktile[nb] + r0 * 64), 16, 0, 0);
        __builtin_amdgcn_global_load_lds(
            (GAS const u32*)(Vh + (size_t)rr * T + kb1 + gg * 8),
            (LAS u32*)(Vtile[nb] + r0 * 64), 16, 0, 0);
      }
    }
    const u16* Kt = Ktile[kt & 1];
    const u16* Vi = Vtile[kt & 1];
    const int kb = kt << 6;
    const int swz = fr & 7;
    v8s kf[4][2], vfr[4][2];
#pragma unroll
    for (int ks = 0; ks < 4; ++ks) {
      const int rr = ks * 16 + fr;
      kf[ks][0] = *(const v8s*)&Kt[rr * 64 + ((0 + fg) ^ swz) * 8];
      kf[ks][1] = *(const v8s*)&Kt[rr * 64 + ((4 + fg) ^ swz) * 8];
      vfr[ks][0] = *(const v8s*)&Vi[rr * 64 + ((0 + fg) ^ swz) * 8];
      vfr[ks][1] = *(const v8s*)&Vi[rr * 64 + ((4 + fg) ^ swz) * 8];
    }
    if (kt < ta) {
      attn_sub<false>(kf, vfr, qfA, otA, mA, lA, pw, kb, rowA, fr, fg);
      attn_sub<false>(kf, vfr, qfB, otB, mB, lB, pw, kb, rowB, fr, fg);
    } else if (kt == ta) {
      attn_sub<true>(kf, vfr, qfA, otA, mA, lA, pw, kb, rowA, fr, fg);
      attn_sub<false>(kf, vfr, qfB, otB, mB, lB, pw, kb, rowB, fr, fg);
    } else if (kt < tb) {
      attn_sub<false>(kf, vfr, qfB, otB, mB, lB, pw, kb, rowB, fr, fg);
    } else {
      attn_sub<true>(kf, vfr, qfB, otB, mB, lB, pw, kb, rowB, fr, fg);
    }
  }

  const float invA = 1.f / lA, invB = 1.f / lB;
#pragma unroll
  for (int ds = 0; ds < 4; ++ds) {
    ushort4 a4, b4;
    a4.x = f2bf(otA[ds][0] * invA);
    a4.y = f2bf(otA[ds][1] * invA);
    a4.z = f2bf(otA[ds][2] * invA);
    a4.w = f2bf(otA[ds][3] * invA);
    b4.x = f2bf(otB[ds][0] * invB);
    b4.y = f2bf(otB[ds][1] * invB);
    b4.z = f2bf(otB[ds][2] * invB);
    b4.w = f2bf(otB[ds][3] * invB);
    *(ushort4*)&y[(size_t)(b * T + rowA + fr) * C + h * D + ds * 16 + fg * 4] = a4;
    *(ushort4*)&y[(size_t)(b * T + rowB + fr) * C + h * D + ds * 16 + fg * 4] = b4;
  }
}

// ------------------------------- launch ----------------------------------
extern "C" void kernel_launch(void* const* d_in, const int* in_sizes, int n_in,
                              void* d_out, int out_size, void* d_ws, size_t ws_size,
                              hipStream_t stream) {
  const float* x      = (const float*)d_in[0];
  const float* ln1_g  = (const float*)d_in[1];
  const float* ln1_b  = (const float*)d_in[2];
  const float* W_attn = (const float*)d_in[3];
  const float* b_attn = (const float*)d_in[4];
  const float* W_o    = (const float*)d_in[5];
  const float* b_o    = (const float*)d_in[6];
  const float* ln2_g  = (const float*)d_in[7];
  const float* ln2_b  = (const float*)d_in[8];
  const float* W_fc   = (const float*)d_in[9];
  const float* b_fc   = (const float*)d_in[10];
  const float* W_fc2  = (const float*)d_in[11];
  const float* b_fc2  = (const float*)d_in[12];
  float* out = (float*)d_out;
  char* ws = (char*)d_ws;

  const size_t MB = 1u << 20;
  u16* Wattn_t = (u16*)(ws + 0 * MB);   // 6MB
  u16* Wo_t    = (u16*)(ws + 6 * MB);   // 2MB
  u16* Wfc_t   = (u16*)(ws + 8 * MB);   // 8MB
  u16* Wfc2_t  = (u16*)(ws + 16 * MB);  // 8MB
  float* x1    = (float*)(ws + 24 * MB); // 16MB
  u16* h1      = (u16*)(ws + 40 * MB);  // 8MB
  u16* qkv     = (u16*)(ws + 48 * MB);  // 24MB (alive through attn)
  u16* Vt      = (u16*)(ws + 88 * MB);  // 8MB
  u16* yb      = (u16*)(ws + 40 * MB);  // reuse h1 (dead after qkv GEMM)
  u16* h2      = (u16*)(ws + 48 * MB);  // reuse qkv (dead after attn)
  u16* ab      = (u16*)(ws + 56 * MB);  // 32MB (56..88)

  wtrans<<<dim3(3072 / 32, 1024 / 32), 256, 0, stream>>>(W_attn, Wattn_t, 1024, 3072);
  wtrans<<<dim3(1024 / 32, 1024 / 32), 256, 0, stream>>>(W_o, Wo_t, 1024, 1024);
  wtrans<<<dim3(4096 / 32, 1024 / 32), 256, 0, stream>>>(W_fc, Wfc_t, 1024, 4096);
  wtrans<<<dim3(1024 / 32, 4096 / 32), 256, 0, stream>>>(W_fc2, Wfc2_t, 4096, 1024);

  ln_bf16<<<4096, 256, 0, stream>>>(x, ln1_g, ln1_b, h1);
  gemm_bt_p<0><<<dim3(3072 / 128, 4096 / 128), 256, 0, stream>>>(
      h1, Wattn_t, b_attn, nullptr, qkv, 4096, 3072, 1024);
  transpose_v<<<dim3(2048 / 64, 32), 256, 0, stream>>>(qkv, Vt);
  attn_kernel<<<dim3(16, 32), 256, 0, stream>>>(qkv, Vt, yb);
  gemm_bt_n64<2><<<dim3(1024 / 64, 4096 / 128), 256, 0, stream>>>(
      yb, Wo_t, b_o, x, x1, 4096, 1024, 1024);
  ln_bf16<<<4096, 256, 0, stream>>>(x1, ln2_g, ln2_b, h2);
  gemm_bt_p<1><<<dim3(4096 / 128, 4096 / 128), 256, 0, stream>>>(
      h2, Wfc_t, b_fc, nullptr, ab, 4096, 4096, 1024);
  gemm_bt_n64<2><<<dim3(1024 / 64, 4096 / 128), 256, 0, stream>>>(
      ab, Wfc2_t, b_fc2, x1, out, 4096, 1024, 4096);
}